// Round 2
// baseline (5734.931 us; speedup 1.0000x reference)
//
#include <hip/hip_runtime.h>
#include <hip/hip_bf16.h>

typedef __hip_bfloat16 bf16;
using bf16x8 = __attribute__((ext_vector_type(8))) short;
using f32x4  = __attribute__((ext_vector_type(4))) float;

#define kNEG 1.0e9f

__device__ __forceinline__ float b2f(bf16 x){ return __bfloat162float(x); }
__device__ __forceinline__ bf16  f2b(float x){ return __float2bfloat16(x); }

__device__ __forceinline__ void unpack8(uint4 u, float* f){
  f[0]=__uint_as_float(u.x<<16); f[1]=__uint_as_float(u.x&0xffff0000u);
  f[2]=__uint_as_float(u.y<<16); f[3]=__uint_as_float(u.y&0xffff0000u);
  f[4]=__uint_as_float(u.z<<16); f[5]=__uint_as_float(u.z&0xffff0000u);
  f[6]=__uint_as_float(u.w<<16); f[7]=__uint_as_float(u.w&0xffff0000u);
}

// ---------------- embedding + LN (all f32 in/out, bf16 shadow) ----------------
__global__ __launch_bounds__(256)
void embed_ln(const int* __restrict__ ids, const float* __restrict__ wemb,
              const float* __restrict__ pemb, const float* __restrict__ lns,
              const float* __restrict__ lnb, float* __restrict__ hout,
              bf16* __restrict__ hbout)
{
  const int row = blockIdx.x;
  const int tid = threadIdx.x;
  const int wave = tid >> 6, lane = tid & 63;
  const int id = ids[row];
  float x[3];
  #pragma unroll
  for (int p=0;p<3;p++){
    int i = tid + p*256;
    x[p] = wemb[(size_t)id*768 + i] + pemb[(size_t)row*768 + i];
  }
  float s1 = x[0]+x[1]+x[2];
  float s2 = x[0]*x[0]+x[1]*x[1]+x[2]*x[2];
  #pragma unroll
  for (int m=32;m>=1;m>>=1){ s1 += __shfl_xor(s1,m); s2 += __shfl_xor(s2,m); }
  __shared__ float red[8];
  if (lane==0){ red[wave]=s1; red[4+wave]=s2; }
  __syncthreads();
  s1 = red[0]+red[1]+red[2]+red[3];
  s2 = red[4]+red[5]+red[6]+red[7];
  float mu = s1*(1.0f/768.0f);
  float var = s2*(1.0f/768.0f) - mu*mu;
  float rs = rsqrtf(var + 1e-5f);
  #pragma unroll
  for (int p=0;p<3;p++){
    int i = tid + p*256;
    float y = (x[p]-mu)*rs*lns[i] + lnb[i];
    hout[(size_t)row*768+i] = y;
    hbout[(size_t)row*768+i] = f2b(y);
  }
}

// ---------------- residual add + LN ----------------
__global__ __launch_bounds__(256)
void add_ln(const float* __restrict__ res, const float* __restrict__ delta,
            const float* __restrict__ lns, const float* __restrict__ lnb,
            float* __restrict__ hout, bf16* __restrict__ hbout)
{
  const int row = blockIdx.x;
  const int tid = threadIdx.x;
  const int wave = tid >> 6, lane = tid & 63;
  float x[3];
  #pragma unroll
  for (int p=0;p<3;p++){
    int i = tid + p*256;
    x[p] = res[(size_t)row*768+i] + delta[(size_t)row*768+i];
  }
  float s1 = x[0]+x[1]+x[2];
  float s2 = x[0]*x[0]+x[1]*x[1]+x[2]*x[2];
  #pragma unroll
  for (int m=32;m>=1;m>>=1){ s1 += __shfl_xor(s1,m); s2 += __shfl_xor(s2,m); }
  __shared__ float red[8];
  if (lane==0){ red[wave]=s1; red[4+wave]=s2; }
  __syncthreads();
  s1 = red[0]+red[1]+red[2]+red[3];
  s2 = red[4]+red[5]+red[6]+red[7];
  float mu = s1*(1.0f/768.0f);
  float var = s2*(1.0f/768.0f) - mu*mu;
  float rs = rsqrtf(var + 1e-5f);
  #pragma unroll
  for (int p=0;p<3;p++){
    int i = tid + p*256;
    float y = (x[p]-mu)*rs*lns[i] + lnb[i];
    hout[(size_t)row*768+i] = y;
    hbout[(size_t)row*768+i] = f2b(y);
  }
}

// ---------------- per-layer weight transpose (f32 -> bf16) + bias concat ----------------
// blocks [0,720): Wq..Wvg -> WcatT, [720,864): Wo, [864,1440): Wf1, [1440,2016): Wf2
// blocks [2016,2031): bcat (f32)
__global__ __launch_bounds__(256)
void prep_layer(const float* __restrict__ Wq, const float* __restrict__ Wk,
                const float* __restrict__ Wv, const float* __restrict__ Wkg,
                const float* __restrict__ Wvg, const float* __restrict__ Wo,
                const float* __restrict__ Wf1, const float* __restrict__ Wf2,
                const float* __restrict__ bq, const float* __restrict__ bk,
                const float* __restrict__ bv, const float* __restrict__ bkg,
                const float* __restrict__ bvg,
                bf16* __restrict__ WcatT, bf16* __restrict__ WoT,
                bf16* __restrict__ Wf1T, bf16* __restrict__ Wf2T,
                float* __restrict__ bcat)
{
  const int b = blockIdx.x;
  const int tid = threadIdx.x;
  if (b >= 2016) {
    int i = (b-2016)*256 + tid;   // 0..3839
    int which = i / 768, j = i - which*768;
    float v;
    if      (which==0) v = bq[j] * 0.125f;
    else if (which==1) v = bk[j];
    else if (which==2) v = bv[j];
    else if (which==3) v = bkg[j];
    else               v = bvg[j];
    bcat[i] = v;
    return;
  }
  const float* src; bf16* dst; int K, N; float scale = 1.0f; int tile;
  if (b < 720) {
    int wsel = b / 144; tile = b - wsel*144;
    if      (wsel==0){ src=Wq;  scale=0.125f; }
    else if (wsel==1){ src=Wk; }
    else if (wsel==2){ src=Wv; }
    else if (wsel==3){ src=Wkg; }
    else             { src=Wvg; }
    dst = WcatT + (size_t)wsel*768*768; K=768; N=768;
  } else if (b < 864) { tile = b-720;  src=Wo;  dst=WoT;  K=768;  N=768;  }
  else if (b < 1440)  { tile = b-864;  src=Wf1; dst=Wf1T; K=768;  N=3072; }
  else                { tile = b-1440; src=Wf2; dst=Wf2T; K=3072; N=768;  }
  const int ntn = N/64;
  const int tk = tile / ntn, tn = tile - tk*ntn;
  const int k0 = tk*64, n0 = tn*64;

  __shared__ float t[64][68];
  const int r  = tid >> 3;
  const int c8 = (tid & 7) << 3;
  #pragma unroll
  for (int p=0;p<2;p++){
    int kk = r + p*32;
    const float* s = &src[(size_t)(k0+kk)*N + n0 + c8];
    float4 v0 = *(const float4*)(s);
    float4 v1 = *(const float4*)(s+4);
    *(float4*)&t[kk][c8]   = v0;
    *(float4*)&t[kk][c8+4] = v1;
  }
  __syncthreads();
  #pragma unroll
  for (int p=0;p<2;p++){
    int nn = r + p*32;
    union { uint4 u; bf16 h[8]; } tmp;
    #pragma unroll
    for (int e=0;e<8;e++){
      tmp.h[e] = f2b(t[c8+e][nn]*scale);
    }
    *(uint4*)&dst[(size_t)(n0+nn)*K + k0 + c8] = tmp.u;
  }
}

// ---------------- MFMA GEMM: C[M][N] = A[M][K] @ Bt[N][K]^T + bias ----------------
template<int OUTF, int OUTB, int GELU>
__global__ __launch_bounds__(256)
void gemm_bt(const bf16* __restrict__ A, const bf16* __restrict__ Bt,
             const float* __restrict__ bias,
             float* __restrict__ outf, bf16* __restrict__ outb,
             int M, int N, int K)
{
  __shared__ bf16 As[128*32];
  __shared__ bf16 Bs[128*32];
  const int tid  = threadIdx.x;
  const int lane = tid & 63;
  const int wave = tid >> 6;
  const int wm = wave >> 1, wn = wave & 1;
  const int bm = blockIdx.x, bn = blockIdx.y;
  const int fr = lane & 15;
  const int fk = lane >> 4;

  const int srow = tid >> 2;
  const int scol = (tid & 3) << 3;
  const bf16* pa0 = A  + (size_t)(bm*128 + srow)*K      + scol;
  const bf16* pa1 = A  + (size_t)(bm*128 + srow + 64)*K + scol;
  const bf16* pb0 = Bt + (size_t)(bn*128 + srow)*K      + scol;
  const bf16* pb1 = Bt + (size_t)(bn*128 + srow + 64)*K + scol;

  f32x4 acc[4][4];
  const f32x4 zero = {0.f,0.f,0.f,0.f};
  #pragma unroll
  for (int i=0;i<4;i++)
    #pragma unroll
    for (int j=0;j<4;j++) acc[i][j] = zero;

  for (int k0 = 0; k0 < K; k0 += 32) {
    __syncthreads();
    uint4 a0 = *(const uint4*)(pa0 + k0);
    uint4 a1 = *(const uint4*)(pa1 + k0);
    uint4 b0 = *(const uint4*)(pb0 + k0);
    uint4 b1 = *(const uint4*)(pb1 + k0);
    *(uint4*)&As[srow*32 + scol]      = a0;
    *(uint4*)&As[(srow+64)*32 + scol] = a1;
    *(uint4*)&Bs[srow*32 + scol]      = b0;
    *(uint4*)&Bs[(srow+64)*32 + scol] = b1;
    __syncthreads();
    bf16x8 af[4], bfr[4];
    #pragma unroll
    for (int m=0;m<4;m++)
      af[m] = *reinterpret_cast<const bf16x8*>(&As[(wm*64 + m*16 + fr)*32 + fk*8]);
    #pragma unroll
    for (int n=0;n<4;n++)
      bfr[n] = *reinterpret_cast<const bf16x8*>(&Bs[(wn*64 + n*16 + fr)*32 + fk*8]);
    #pragma unroll
    for (int m=0;m<4;m++)
      #pragma unroll
      for (int n=0;n<4;n++)
        acc[m][n] = __builtin_amdgcn_mfma_f32_16x16x32_bf16(af[m], bfr[n], acc[m][n], 0,0,0);
  }

  const int row0 = bm*128 + wm*64 + (lane>>4)*4;
  const int col0 = bn*128 + wn*64 + fr;
  #pragma unroll
  for (int n=0;n<4;n++){
    const int col = col0 + n*16;
    const float bv = bias[col];
    #pragma unroll
    for (int m=0;m<4;m++){
      const int r0 = row0 + m*16;
      #pragma unroll
      for (int r=0;r<4;r++){
        float x = acc[m][n][r] + bv;
        if (GELU) x = 0.5f*x*(1.0f + erff(x*0.70710678118f));
        size_t idx = (size_t)(r0+r)*N + col;
        if (OUTF) outf[idx] = x;
        if (OUTB) outb[idx] = f2b(x);
      }
    }
  }
}

// ---------------- qg = (h0 @ Wqg + bqg)*SCALE  (all f32) ----------------
__global__ __launch_bounds__(256)
void qg_kernel(const float* __restrict__ h0, const float* __restrict__ Wqg,
               const float* __restrict__ bqg, float* __restrict__ qg)
{
  const int col = blockIdx.x*256 + threadIdx.x;  // 768 total
  float acc = 0.f;
  #pragma unroll 8
  for (int k=0;k<768;k++) acc += h0[k] * Wqg[(size_t)k*768 + col];
  qg[col] = (acc + bqg[col])*0.125f;
}

// ---------------- band (sliding window + global col) attention ----------------
__global__ __launch_bounds__(256)
void band_attn(const bf16* __restrict__ qkv, const int* __restrict__ amask,
               const int* __restrict__ gmask, bf16* __restrict__ attn)
{
  const int c = blockIdx.x, n = blockIdx.y, rg = blockIdx.z;
  const int tid = threadIdx.x, wave = tid>>6, lane = tid&63;

  __shared__ float q_lds[64][68];
  __shared__ float k_lds[64][68];
  __shared__ float v_lds[64][68];
  __shared__ float p_lds[4][2][64];
  __shared__ float kv0[2][64];

  // stage q rows (block rows rg*64 .. +63), f32
  {
    const int j = tid >> 2, d0 = (tid & 3) * 16;
    const bf16* src = qkv + (size_t)(c*256 + rg*64 + j)*3840 + n*64 + d0;
    const uint4* s4 = (const uint4*)src;
    float f[8];
    unpack8(s4[0], f);
    *(float4*)&q_lds[j][d0+0]  = make_float4(f[0],f[1],f[2],f[3]);
    *(float4*)&q_lds[j][d0+4]  = make_float4(f[4],f[5],f[6],f[7]);
    unpack8(s4[1], f);
    *(float4*)&q_lds[j][d0+8]  = make_float4(f[0],f[1],f[2],f[3]);
    *(float4*)&q_lds[j][d0+12] = make_float4(f[4],f[5],f[6],f[7]);
  }
  if (wave==0)      kv0[0][lane] = b2f(qkv[768  + n*64 + lane]);
  else if (wave==1) kv0[1][lane] = b2f(qkv[1536 + n*64 + lane]);

  float m[16], l[16], acc[16];
  #pragma unroll
  for (int r=0;r<16;r++){ m[r] = -kNEG; l[r] = 0.f; acc[r] = 0.f; }

  const int kt1 = (rg+8 < 11) ? rg+8 : 11;
  for (int kt = rg; kt <= kt1; kt++) {
    __syncthreads();
    {
      const int j = tid >> 2, d0 = (tid & 3) * 16;
      int kpos = c*256 + kt*64 + j - 256;
      int kq = kpos < 0 ? 0 : (kpos > 2047 ? 2047 : kpos);
      const uint4* ks = (const uint4*)(qkv + (size_t)kq*3840 + 768  + n*64 + d0);
      const uint4* vs = (const uint4*)(qkv + (size_t)kq*3840 + 1536 + n*64 + d0);
      float f[8];
      unpack8(ks[0], f);
      *(float4*)&k_lds[j][d0+0]  = make_float4(f[0],f[1],f[2],f[3]);
      *(float4*)&k_lds[j][d0+4]  = make_float4(f[4],f[5],f[6],f[7]);
      unpack8(ks[1], f);
      *(float4*)&k_lds[j][d0+8]  = make_float4(f[0],f[1],f[2],f[3]);
      *(float4*)&k_lds[j][d0+12] = make_float4(f[4],f[5],f[6],f[7]);
      unpack8(vs[0], f);
      *(float4*)&v_lds[j][d0+0]  = make_float4(f[0],f[1],f[2],f[3]);
      *(float4*)&v_lds[j][d0+4]  = make_float4(f[4],f[5],f[6],f[7]);
      unpack8(vs[1], f);
      *(float4*)&v_lds[j][d0+8]  = make_float4(f[0],f[1],f[2],f[3]);
      *(float4*)&v_lds[j][d0+12] = make_float4(f[4],f[5],f[6],f[7]);
    }
    __syncthreads();

    const int jg = kt*64 + lane;
    const int kpos = c*256 + jg - 256;
    bool okk = (kpos >= 0) && (kpos < 2048);
    if (okk) okk = (amask[kpos] != 0) && (gmask[kpos] == 0);

    #pragma unroll
    for (int rp=0; rp<8; rp++) {
      const int rr0 = rp*2, rr1 = rp*2+1;
      const int qi0 = rg*64 + wave*16 + rr0;
      float sa = 0.f, sb = 0.f;
      #pragma unroll 4
      for (int d4=0; d4<16; d4++) {
        float4 kk4 = *(const float4*)&k_lds[lane][d4*4];
        float4 qa4 = *(const float4*)&q_lds[wave*16+rr0][d4*4];
        float4 qb4 = *(const float4*)&q_lds[wave*16+rr1][d4*4];
        sa += kk4.x*qa4.x + kk4.y*qa4.y + kk4.z*qa4.z + kk4.w*qa4.w;
        sb += kk4.x*qb4.x + kk4.y*qb4.y + kk4.z*qb4.z + kk4.w*qb4.w;
      }
      unsigned rela = (unsigned)(jg - qi0);
      unsigned relb = (unsigned)(jg - qi0 - 1);
      float SA = (okk && rela <= 512u) ? sa : -kNEG;
      float SB = (okk && relb <= 512u) ? sb : -kNEG;

      float tma = SA, tmb = SB;
      #pragma unroll
      for (int mk=32; mk>=1; mk>>=1){
        tma = fmaxf(tma, __shfl_xor(tma, mk));
        tmb = fmaxf(tmb, __shfl_xor(tmb, mk));
      }
      float mna = fmaxf(m[rr0], tma), mnb = fmaxf(m[rr1], tmb);
      float faca = __expf(m[rr0]-mna), facb = __expf(m[rr1]-mnb);
      float pa = __expf(SA - mna), pb = __expf(SB - mnb);
      float tsa = pa, tsb = pb;
      #pragma unroll
      for (int mk=32; mk>=1; mk>>=1){
        tsa += __shfl_xor(tsa, mk);
        tsb += __shfl_xor(tsb, mk);
      }
      l[rr0] = l[rr0]*faca + tsa;  m[rr0] = mna;
      l[rr1] = l[rr1]*facb + tsb;  m[rr1] = mnb;
      p_lds[wave][0][lane] = pa;
      p_lds[wave][1][lane] = pb;
      float accA = acc[rr0]*faca;
      float accB = acc[rr1]*facb;
      #pragma unroll 4
      for (int j4=0; j4<16; j4++) {
        float4 pa4 = *(const float4*)&p_lds[wave][0][j4*4];
        float4 pb4 = *(const float4*)&p_lds[wave][1][j4*4];
        float v0 = v_lds[j4*4+0][lane];
        float v1 = v_lds[j4*4+1][lane];
        float v2 = v_lds[j4*4+2][lane];
        float v3 = v_lds[j4*4+3][lane];
        accA += pa4.x*v0 + pa4.y*v1 + pa4.z*v2 + pa4.w*v3;
        accB += pb4.x*v0 + pb4.y*v1 + pb4.z*v2 + pb4.w*v3;
      }
      acc[rr0] = accA; acc[rr1] = accB;
    }
  }

  // finalize: global column (key/value = band k,v at position 0)
  const bool okg = (amask[0] != 0);
  #pragma unroll
  for (int r=0; r<16; r++) {
    float pr = q_lds[wave*16+r][lane]*kv0[0][lane];
    #pragma unroll
    for (int mk=32; mk>=1; mk>>=1) pr += __shfl_xor(pr, mk);
    float sg = okg ? pr : -kNEG;
    float mn = fmaxf(m[r], sg);
    float fac = __expf(m[r]-mn);
    float pg = __expf(sg - mn);
    float lf = l[r]*fac + pg;
    float o = (acc[r]*fac + pg*kv0[1][lane]) / lf;
    int srow = c*256 + rg*64 + wave*16 + r;
    attn[(size_t)srow*768 + n*64 + lane] = f2b(o);
  }
}

// ---------------- global-token (row 0) full attention ----------------
__global__ __launch_bounds__(256)
void global_attn(const bf16* __restrict__ qkv, const float* __restrict__ qg,
                 const int* __restrict__ amask, bf16* __restrict__ attn)
{
  const int n = blockIdx.x;
  const int tid = threadIdx.x, wave = tid>>6, lane = tid&63;
  __shared__ float sg[2048];
  __shared__ float qh[64];
  __shared__ float red[8];
  __shared__ float part[4][64];
  if (tid < 64) qh[tid] = qg[n*64+tid];
  __syncthreads();

  float smax = -3.0e38f;
  for (int p=0;p<8;p++){
    int s = p*256 + tid;
    const uint4* kr = (const uint4*)(qkv + (size_t)s*3840 + 2304 + n*64);
    float acc = 0.f;
    #pragma unroll
    for (int d8=0; d8<8; d8++){
      float f[8]; unpack8(kr[d8], f);
      #pragma unroll
      for (int e=0;e<8;e++) acc += f[e]*qh[d8*8+e];
    }
    if (amask[s] == 0) acc = -kNEG;
    sg[s] = acc;
    smax = fmaxf(smax, acc);
  }
  #pragma unroll
  for (int mk=32; mk>=1; mk>>=1) smax = fmaxf(smax, __shfl_xor(smax, mk));
  if (lane==0) red[wave] = smax;
  __syncthreads();
  smax = fmaxf(fmaxf(red[0],red[1]),fmaxf(red[2],red[3]));
  float ssum = 0.f;
  for (int p=0;p<8;p++){
    int s = p*256 + tid;
    float e = __expf(sg[s]-smax);
    sg[s] = e;
    ssum += e;
  }
  #pragma unroll
  for (int mk=32; mk>=1; mk>>=1) ssum += __shfl_xor(ssum, mk);
  if (lane==0) red[4+wave] = ssum;
  __syncthreads();
  float total = red[4]+red[5]+red[6]+red[7];

  float o = 0.f;
  const int base = wave*512;
  for (int s = base; s < base+512; s++)
    o += sg[s] * b2f(qkv[(size_t)s*3840 + 3072 + n*64 + lane]);
  part[wave][lane] = o;
  __syncthreads();
  if (tid < 64) {
    float oo = (part[0][tid]+part[1][tid]+part[2][tid]+part[3][tid]) / total;
    attn[n*64+tid] = f2b(oo);   // sequence row 0
  }
}

// ---------------- head (all f32) ----------------
__global__ void head_dense(const float* __restrict__ h0, const float* __restrict__ dw,
                           const float* __restrict__ db, float* __restrict__ y)
{
  const int col = blockIdx.x*64 + threadIdx.x; // 768
  float acc = 0.f;
  #pragma unroll 8
  for (int k=0;k<768;k++) acc += h0[k]*dw[(size_t)k*768 + col];
  y[col] = tanhf(acc + db[col]);
}

__global__ void head_out(const float* __restrict__ y, const float* __restrict__ ow,
                         const float* __restrict__ ob, float* __restrict__ out)
{
  const int col = blockIdx.x*64 + threadIdx.x; // 256
  float acc = 0.f;
  #pragma unroll 8
  for (int k=0;k<768;k++) acc += y[k]*ow[(size_t)k*256 + col];
  out[col] = acc + ob[col];
}

// ---------------- host ----------------
extern "C" void kernel_launch(void* const* d_in, const int* in_sizes, int n_in,
                              void* d_out, int out_size, void* d_ws, size_t ws_size,
                              hipStream_t stream)
{
  const int*   ids   = (const int*)d_in[0];
  const int*   amask = (const int*)d_in[1];
  const int*   gmask = (const int*)d_in[2];
  const float* wemb  = (const float*)d_in[3];
  const float* pemb  = (const float*)d_in[4];
  const float* elns  = (const float*)d_in[5];
  const float* elnb  = (const float*)d_in[6];
  const float* Wq    = (const float*)d_in[7];
  const float* bq    = (const float*)d_in[8];
  const float* Wk    = (const float*)d_in[9];
  const float* bk    = (const float*)d_in[10];
  const float* Wv    = (const float*)d_in[11];
  const float* bv    = (const float*)d_in[12];
  const float* Wqg   = (const float*)d_in[13];
  const float* bqg   = (const float*)d_in[14];
  const float* Wkg   = (const float*)d_in[15];
  const float* bkg   = (const float*)d_in[16];
  const float* Wvg   = (const float*)d_in[17];
  const float* bvg   = (const float*)d_in[18];
  const float* Wo    = (const float*)d_in[19];
  const float* bo    = (const float*)d_in[20];
  const float* ln1s  = (const float*)d_in[21];
  const float* ln1b  = (const float*)d_in[22];
  const float* Wf1   = (const float*)d_in[23];
  const float* bf1   = (const float*)d_in[24];
  const float* Wf2   = (const float*)d_in[25];
  const float* bf2   = (const float*)d_in[26];
  const float* ln2s  = (const float*)d_in[27];
  const float* ln2b  = (const float*)d_in[28];
  const float* dw    = (const float*)d_in[29];
  const float* db    = (const float*)d_in[30];
  const float* ow    = (const float*)d_in[31];
  const float* ob    = (const float*)d_in[32];

  char* ws = (char*)d_ws;
  size_t off = 0;
  auto alloc = [&](size_t bytes)->char*{
    char* p = ws + off; off += (bytes + 255) & ~(size_t)255; return p;
  };
  float* h    = (float*)alloc((size_t)2048*768*4);
  bf16*  hb   = (bf16*) alloc((size_t)2048*768*2);
  float* h2   = (float*)alloc((size_t)2048*768*4);
  bf16*  h2b  = (bf16*) alloc((size_t)2048*768*2);
  bf16*  qkv  = (bf16*) alloc((size_t)2048*3840*2);
  bf16*  att  = (bf16*) alloc((size_t)2048*768*2);
  float* proj = (float*)alloc((size_t)2048*768*4);
  bf16*  f1   = (bf16*) alloc((size_t)2048*3072*2);
  float* ffb  = (float*)alloc((size_t)2048*768*4);
  bf16*  WcatT= (bf16*) alloc((size_t)3840*768*2);
  bf16*  WoT  = (bf16*) alloc((size_t)768*768*2);
  bf16*  Wf1T = (bf16*) alloc((size_t)3072*768*2);
  bf16*  Wf2T = (bf16*) alloc((size_t)768*3072*2);
  float* bcat = (float*)alloc((size_t)3840*4);
  float* qg   = (float*)alloc(768*4);
  float* y    = (float*)alloc(768*4);

  embed_ln<<<2048,256,0,stream>>>(ids, wemb, pemb, elns, elnb, h, hb);

  for (int l=0; l<12; l++) {
    const size_t oHH = (size_t)l*768*768;
    const size_t oH  = (size_t)l*768;
    const size_t oHF = (size_t)l*768*3072;
    const size_t oF  = (size_t)l*3072;
    prep_layer<<<2031,256,0,stream>>>(Wq+oHH, Wk+oHH, Wv+oHH, Wkg+oHH, Wvg+oHH,
                                      Wo+oHH, Wf1+oHF, Wf2+oHF,
                                      bq+oH, bk+oH, bv+oH, bkg+oH, bvg+oH,
                                      WcatT, WoT, Wf1T, Wf2T, bcat);
    gemm_bt<0,1,0><<<dim3(16,30),256,0,stream>>>(hb, WcatT, bcat, nullptr, qkv,
                                                 2048, 3840, 768);
    qg_kernel<<<3,256,0,stream>>>(h, Wqg+oHH, bqg+oH, qg);
    band_attn<<<dim3(8,12,4),256,0,stream>>>(qkv, amask, gmask, att);
    global_attn<<<12,256,0,stream>>>(qkv, qg, amask, att);
    gemm_bt<1,0,0><<<dim3(16,6),256,0,stream>>>(att, WoT, bo+oH, proj, nullptr,
                                                2048, 768, 768);
    add_ln<<<2048,256,0,stream>>>(h, proj, ln1s+oH, ln1b+oH, h2, h2b);
    gemm_bt<0,1,1><<<dim3(16,24),256,0,stream>>>(h2b, Wf1T, bf1+oF, nullptr, f1,
                                                 2048, 3072, 768);
    gemm_bt<1,0,0><<<dim3(16,6),256,0,stream>>>(f1, Wf2T, bf2+oH, ffb, nullptr,
                                                2048, 768, 3072);
    add_ln<<<2048,256,0,stream>>>(h2, ffb, ln2s+oH, ln2b+oH, h, hb);
  }

  head_dense<<<12,64,0,stream>>>(h, dw, db, y);
  head_out<<<4,64,0,stream>>>(y, ow, ob, (float*)d_out);
}

// Round 3
// 3766.962 us; speedup vs baseline: 1.5224x; 1.5224x over previous
//
#include <hip/hip_runtime.h>
#include <hip/hip_bf16.h>

typedef __hip_bfloat16 bf16;
using bf16x8 = __attribute__((ext_vector_type(8))) short;
using f32x4  = __attribute__((ext_vector_type(4))) float;

#define kNEG 1.0e9f

__device__ __forceinline__ float b2f(bf16 x){ return __bfloat162float(x); }
__device__ __forceinline__ bf16  f2b(float x){ return __float2bfloat16(x); }

__device__ __forceinline__ void unpack8(uint4 u, float* f){
  f[0]=__uint_as_float(u.x<<16); f[1]=__uint_as_float(u.x&0xffff0000u);
  f[2]=__uint_as_float(u.y<<16); f[3]=__uint_as_float(u.y&0xffff0000u);
  f[4]=__uint_as_float(u.z<<16); f[5]=__uint_as_float(u.z&0xffff0000u);
  f[6]=__uint_as_float(u.w<<16); f[7]=__uint_as_float(u.w&0xffff0000u);
}

// ---------------- embedding + LN (all f32 in/out, bf16 shadow) ----------------
__global__ __launch_bounds__(256)
void embed_ln(const int* __restrict__ ids, const float* __restrict__ wemb,
              const float* __restrict__ pemb, const float* __restrict__ lns,
              const float* __restrict__ lnb, float* __restrict__ hout,
              bf16* __restrict__ hbout)
{
  const int row = blockIdx.x;
  const int tid = threadIdx.x;
  const int wave = tid >> 6, lane = tid & 63;
  const int id = ids[row];
  float x[3];
  #pragma unroll
  for (int p=0;p<3;p++){
    int i = tid + p*256;
    x[p] = wemb[(size_t)id*768 + i] + pemb[(size_t)row*768 + i];
  }
  float s1 = x[0]+x[1]+x[2];
  float s2 = x[0]*x[0]+x[1]*x[1]+x[2]*x[2];
  #pragma unroll
  for (int m=32;m>=1;m>>=1){ s1 += __shfl_xor(s1,m); s2 += __shfl_xor(s2,m); }
  __shared__ float red[8];
  if (lane==0){ red[wave]=s1; red[4+wave]=s2; }
  __syncthreads();
  s1 = red[0]+red[1]+red[2]+red[3];
  s2 = red[4]+red[5]+red[6]+red[7];
  float mu = s1*(1.0f/768.0f);
  float var = s2*(1.0f/768.0f) - mu*mu;
  float rs = rsqrtf(var + 1e-5f);
  #pragma unroll
  for (int p=0;p<3;p++){
    int i = tid + p*256;
    float y = (x[p]-mu)*rs*lns[i] + lnb[i];
    hout[(size_t)row*768+i] = y;
    hbout[(size_t)row*768+i] = f2b(y);
  }
}

// ---------------- residual add + LN ----------------
__global__ __launch_bounds__(256)
void add_ln(const float* __restrict__ res, const float* __restrict__ delta,
            const float* __restrict__ lns, const float* __restrict__ lnb,
            float* __restrict__ hout, bf16* __restrict__ hbout)
{
  const int row = blockIdx.x;
  const int tid = threadIdx.x;
  const int wave = tid >> 6, lane = tid & 63;
  float x[3];
  #pragma unroll
  for (int p=0;p<3;p++){
    int i = tid + p*256;
    x[p] = res[(size_t)row*768+i] + delta[(size_t)row*768+i];
  }
  float s1 = x[0]+x[1]+x[2];
  float s2 = x[0]*x[0]+x[1]*x[1]+x[2]*x[2];
  #pragma unroll
  for (int m=32;m>=1;m>>=1){ s1 += __shfl_xor(s1,m); s2 += __shfl_xor(s2,m); }
  __shared__ float red[8];
  if (lane==0){ red[wave]=s1; red[4+wave]=s2; }
  __syncthreads();
  s1 = red[0]+red[1]+red[2]+red[3];
  s2 = red[4]+red[5]+red[6]+red[7];
  float mu = s1*(1.0f/768.0f);
  float var = s2*(1.0f/768.0f) - mu*mu;
  float rs = rsqrtf(var + 1e-5f);
  #pragma unroll
  for (int p=0;p<3;p++){
    int i = tid + p*256;
    float y = (x[p]-mu)*rs*lns[i] + lnb[i];
    hout[(size_t)row*768+i] = y;
    hbout[(size_t)row*768+i] = f2b(y);
  }
}

// ---------------- per-layer weight transpose (f32 -> bf16) + bias concat ----------------
__global__ __launch_bounds__(256)
void prep_layer(const float* __restrict__ Wq, const float* __restrict__ Wk,
                const float* __restrict__ Wv, const float* __restrict__ Wkg,
                const float* __restrict__ Wvg, const float* __restrict__ Wo,
                const float* __restrict__ Wf1, const float* __restrict__ Wf2,
                const float* __restrict__ bq, const float* __restrict__ bk,
                const float* __restrict__ bv, const float* __restrict__ bkg,
                const float* __restrict__ bvg,
                bf16* __restrict__ WcatT, bf16* __restrict__ WoT,
                bf16* __restrict__ Wf1T, bf16* __restrict__ Wf2T,
                float* __restrict__ bcat)
{
  const int b = blockIdx.x;
  const int tid = threadIdx.x;
  if (b >= 2016) {
    int i = (b-2016)*256 + tid;   // 0..3839
    int which = i / 768, j = i - which*768;
    float v;
    if      (which==0) v = bq[j] * 0.125f;
    else if (which==1) v = bk[j];
    else if (which==2) v = bv[j];
    else if (which==3) v = bkg[j];
    else               v = bvg[j];
    bcat[i] = v;
    return;
  }
  const float* src; bf16* dst; int K, N; float scale = 1.0f; int tile;
  if (b < 720) {
    int wsel = b / 144; tile = b - wsel*144;
    if      (wsel==0){ src=Wq;  scale=0.125f; }
    else if (wsel==1){ src=Wk; }
    else if (wsel==2){ src=Wv; }
    else if (wsel==3){ src=Wkg; }
    else             { src=Wvg; }
    dst = WcatT + (size_t)wsel*768*768; K=768; N=768;
  } else if (b < 864) { tile = b-720;  src=Wo;  dst=WoT;  K=768;  N=768;  }
  else if (b < 1440)  { tile = b-864;  src=Wf1; dst=Wf1T; K=768;  N=3072; }
  else                { tile = b-1440; src=Wf2; dst=Wf2T; K=3072; N=768;  }
  const int ntn = N/64;
  const int tk = tile / ntn, tn = tile - tk*ntn;
  const int k0 = tk*64, n0 = tn*64;

  __shared__ float t[64][68];
  const int r  = tid >> 3;
  const int c8 = (tid & 7) << 3;
  #pragma unroll
  for (int p=0;p<2;p++){
    int kk = r + p*32;
    const float* s = &src[(size_t)(k0+kk)*N + n0 + c8];
    float4 v0 = *(const float4*)(s);
    float4 v1 = *(const float4*)(s+4);
    *(float4*)&t[kk][c8]   = v0;
    *(float4*)&t[kk][c8+4] = v1;
  }
  __syncthreads();
  #pragma unroll
  for (int p=0;p<2;p++){
    int nn = r + p*32;
    union { uint4 u; bf16 h[8]; } tmp;
    #pragma unroll
    for (int e=0;e<8;e++){
      tmp.h[e] = f2b(t[c8+e][nn]*scale);
    }
    *(uint4*)&dst[(size_t)(n0+nn)*K + k0 + c8] = tmp.u;
  }
}

// ---------------- MFMA GEMM: C[M][N] = A[M][K] @ Bt[N][K]^T + bias ----------------
template<int OUTF, int OUTB, int GELU>
__global__ __launch_bounds__(256)
void gemm_bt(const bf16* __restrict__ A, const bf16* __restrict__ Bt,
             const float* __restrict__ bias,
             float* __restrict__ outf, bf16* __restrict__ outb,
             int M, int N, int K)
{
  __shared__ bf16 As[128*32];
  __shared__ bf16 Bs[128*32];
  const int tid  = threadIdx.x;
  const int lane = tid & 63;
  const int wave = tid >> 6;
  const int wm = wave >> 1, wn = wave & 1;
  const int bm = blockIdx.x, bn = blockIdx.y;
  const int fr = lane & 15;
  const int fk = lane >> 4;

  const int srow = tid >> 2;
  const int scol = (tid & 3) << 3;
  const bf16* pa0 = A  + (size_t)(bm*128 + srow)*K      + scol;
  const bf16* pa1 = A  + (size_t)(bm*128 + srow + 64)*K + scol;
  const bf16* pb0 = Bt + (size_t)(bn*128 + srow)*K      + scol;
  const bf16* pb1 = Bt + (size_t)(bn*128 + srow + 64)*K + scol;

  f32x4 acc[4][4];
  const f32x4 zero = {0.f,0.f,0.f,0.f};
  #pragma unroll
  for (int i=0;i<4;i++)
    #pragma unroll
    for (int j=0;j<4;j++) acc[i][j] = zero;

  for (int k0 = 0; k0 < K; k0 += 32) {
    __syncthreads();
    uint4 a0 = *(const uint4*)(pa0 + k0);
    uint4 a1 = *(const uint4*)(pa1 + k0);
    uint4 b0 = *(const uint4*)(pb0 + k0);
    uint4 b1 = *(const uint4*)(pb1 + k0);
    *(uint4*)&As[srow*32 + scol]      = a0;
    *(uint4*)&As[(srow+64)*32 + scol] = a1;
    *(uint4*)&Bs[srow*32 + scol]      = b0;
    *(uint4*)&Bs[(srow+64)*32 + scol] = b1;
    __syncthreads();
    bf16x8 af[4], bfr[4];
    #pragma unroll
    for (int m=0;m<4;m++)
      af[m] = *reinterpret_cast<const bf16x8*>(&As[(wm*64 + m*16 + fr)*32 + fk*8]);
    #pragma unroll
    for (int n=0;n<4;n++)
      bfr[n] = *reinterpret_cast<const bf16x8*>(&Bs[(wn*64 + n*16 + fr)*32 + fk*8]);
    #pragma unroll
    for (int m=0;m<4;m++)
      #pragma unroll
      for (int n=0;n<4;n++)
        acc[m][n] = __builtin_amdgcn_mfma_f32_16x16x32_bf16(af[m], bfr[n], acc[m][n], 0,0,0);
  }

  const int row0 = bm*128 + wm*64 + (lane>>4)*4;
  const int col0 = bn*128 + wn*64 + fr;
  #pragma unroll
  for (int n=0;n<4;n++){
    const int col = col0 + n*16;
    const float bv = bias[col];
    #pragma unroll
    for (int m=0;m<4;m++){
      const int r0 = row0 + m*16;
      #pragma unroll
      for (int r=0;r<4;r++){
        float x = acc[m][n][r] + bv;
        if (GELU) x = 0.5f*x*(1.0f + erff(x*0.70710678118f));
        size_t idx = (size_t)(r0+r)*N + col;
        if (OUTF) outf[idx] = x;
        if (OUTB) outb[idx] = f2b(x);
      }
    }
  }
}

// ---------------- qg = (h0 @ Wqg + bqg)*SCALE  (all f32) ----------------
__global__ __launch_bounds__(256)
void qg_kernel(const float* __restrict__ h0, const float* __restrict__ Wqg,
               const float* __restrict__ bqg, float* __restrict__ qg)
{
  const int col = blockIdx.x*256 + threadIdx.x;  // 768 total
  float acc = 0.f;
  #pragma unroll 8
  for (int k=0;k<768;k++) acc += h0[k] * Wqg[(size_t)k*768 + col];
  qg[col] = (acc + bqg[col])*0.125f;
}

// ---------------- band (sliding window + global col) attention, MFMA ----------------
// grid (c=8, n=12, rg=4); block 256 = 4 waves; wave handles 16 q-rows.
__global__ __launch_bounds__(256)
void band_attn(const bf16* __restrict__ qkv, const int* __restrict__ amask,
               const int* __restrict__ gmask, bf16* __restrict__ attn)
{
  const int c = blockIdx.x, n = blockIdx.y, rg = blockIdx.z;
  const int tid = threadIdx.x, wave = tid>>6, lane = tid&63;
  const int fr = lane & 15, fk = lane >> 4;

  __shared__ __attribute__((aligned(16))) bf16 q_s[64][72];
  __shared__ __attribute__((aligned(16))) bf16 k_s[64][72];
  __shared__ __attribute__((aligned(16))) bf16 vt_s[64][72];
  __shared__ __attribute__((aligned(16))) bf16 p_s[4][16][72];
  __shared__ int  okk_s[768];
  __shared__ float kv0[2][64];

  // stage Q (64 rows x 64 dims, bf16) : rows c*256 + rg*64 + j, head n (pre-scaled)
  {
    const int j = tid >> 2, d0 = (tid & 3) * 16;
    const uint4* src = (const uint4*)(qkv + (size_t)(c*256 + rg*64 + j)*3840 + n*64 + d0);
    *(uint4*)&q_s[j][d0]   = src[0];
    *(uint4*)&q_s[j][d0+8] = src[1];
  }
  // key-validity flags over the 768-wide window
  #pragma unroll
  for (int p=0;p<3;p++){
    int j = tid + p*256;
    int kpos = c*256 + j - 256;
    int ok = 0;
    if (kpos >= 0 && kpos < 2048) ok = (amask[kpos] != 0) && (gmask[kpos] == 0);
    okk_s[j] = ok;
  }
  if (tid < 64)       kv0[0][tid]    = b2f(qkv[768  + n*64 + tid]);
  else if (tid < 128) kv0[1][tid-64] = b2f(qkv[1536 + n*64 + (tid-64)]);

  float m[4], l[4];
  f32x4 out[4];
  const f32x4 zero = {0.f,0.f,0.f,0.f};
  #pragma unroll
  for (int r=0;r<4;r++){ m[r] = -kNEG; l[r] = 0.f; }
  #pragma unroll
  for (int dt=0;dt<4;dt++) out[dt] = zero;

  const int kt1 = (rg+8 < 11) ? rg+8 : 11;
  for (int kt = rg; kt <= kt1; kt++) {
    __syncthreads();
    // stage K tile [key][d] and V^T tile [d][key]
    {
      const int jj = tid >> 2, d0 = (tid & 3) * 16;
      int kpos = c*256 + kt*64 + jj - 256;
      int kq = kpos < 0 ? 0 : (kpos > 2047 ? 2047 : kpos);
      const uint4* ks = (const uint4*)(qkv + (size_t)kq*3840 + 768  + n*64 + d0);
      *(uint4*)&k_s[jj][d0]   = ks[0];
      *(uint4*)&k_s[jj][d0+8] = ks[1];
      const uint4* vs = (const uint4*)(qkv + (size_t)kq*3840 + 1536 + n*64 + d0);
      uint4 v0 = vs[0], v1 = vs[1];
      const bf16* ve0 = (const bf16*)&v0;
      const bf16* ve1 = (const bf16*)&v1;
      #pragma unroll
      for (int e=0;e<8;e++) vt_s[d0+e][jj]   = ve0[e];
      #pragma unroll
      for (int e=0;e<8;e++) vt_s[d0+8+e][jj] = ve1[e];
    }
    __syncthreads();

    // S = Q @ K^T : wave's 16 rows x 64 keys (4 col-tiles, K=64 as 2 slices)
    f32x4 s[4];
    #pragma unroll
    for (int ct=0;ct<4;ct++) s[ct] = zero;
    #pragma unroll
    for (int ks=0;ks<2;ks++){
      bf16x8 aq = *reinterpret_cast<const bf16x8*>(&q_s[wave*16 + fr][ks*32 + fk*8]);
      #pragma unroll
      for (int ct=0;ct<4;ct++){
        bf16x8 bk = *reinterpret_cast<const bf16x8*>(&k_s[ct*16 + fr][ks*32 + fk*8]);
        s[ct] = __builtin_amdgcn_mfma_f32_16x16x32_bf16(aq, bk, s[ct], 0,0,0);
      }
    }
    // mask: C layout row=(fk*4+r), col=fr
    const int qbase = rg*64 + wave*16 + fk*4;
    #pragma unroll
    for (int ct=0;ct<4;ct++){
      int j = kt*64 + ct*16 + fr;
      int okj = okk_s[j];
      #pragma unroll
      for (int r=0;r<4;r++){
        unsigned rel = (unsigned)(j - (qbase + r));
        s[ct][r] = (okj && rel <= 512u) ? s[ct][r] : -kNEG;
      }
    }
    // online softmax over this 64-key tile
    float fac[4], psum[4];
    #pragma unroll
    for (int r=0;r<4;r++){
      float mm = fmaxf(fmaxf(s[0][r], s[1][r]), fmaxf(s[2][r], s[3][r]));
      #pragma unroll
      for (int mk=8; mk>=1; mk>>=1) mm = fmaxf(mm, __shfl_xor(mm, mk));
      float mn = fmaxf(m[r], mm);
      fac[r] = __expf(m[r] - mn);
      m[r] = mn;
      psum[r] = 0.f;
    }
    #pragma unroll
    for (int ct=0;ct<4;ct++){
      #pragma unroll
      for (int r=0;r<4;r++){
        float p = __expf(s[ct][r] - m[r]);
        psum[r] += p;
        p_s[wave][fk*4 + r][ct*16 + fr] = f2b(p);
      }
    }
    #pragma unroll
    for (int r=0;r<4;r++){
      float ts = psum[r];
      #pragma unroll
      for (int mk=8; mk>=1; mk>>=1) ts += __shfl_xor(ts, mk);
      l[r] = l[r]*fac[r] + ts;
    }
    #pragma unroll
    for (int dt=0;dt<4;dt++)
      #pragma unroll
      for (int r=0;r<4;r++) out[dt][r] *= fac[r];
    // out += P @ V  (A = P rows, Bt = V^T rows)
    #pragma unroll
    for (int ks=0;ks<2;ks++){
      bf16x8 ap = *reinterpret_cast<const bf16x8*>(&p_s[wave][fr][ks*32 + fk*8]);
      #pragma unroll
      for (int dt=0;dt<4;dt++){
        bf16x8 bv = *reinterpret_cast<const bf16x8*>(&vt_s[dt*16 + fr][ks*32 + fk*8]);
        out[dt] = __builtin_amdgcn_mfma_f32_16x16x32_bf16(ap, bv, out[dt], 0,0,0);
      }
    }
  }

  // global column (key/value = band k,v at sequence position 0) + finalize
  const bool okg = (amask[0] != 0);
  #pragma unroll
  for (int r=0;r<4;r++){
    const int row16 = fk*4 + r;
    float sp = 0.f;
    #pragma unroll
    for (int e=0;e<4;e++){
      int d = fr*4 + e;
      sp += b2f(q_s[wave*16 + row16][d]) * kv0[0][d];
    }
    #pragma unroll
    for (int mk=8; mk>=1; mk>>=1) sp += __shfl_xor(sp, mk);
    float sg = okg ? sp : -kNEG;
    float mn = fmaxf(m[r], sg);
    float fc = __expf(m[r]-mn);
    float pg = __expf(sg-mn);
    float lf = l[r]*fc + pg;
    const int srow = c*256 + rg*64 + wave*16 + row16;
    #pragma unroll
    for (int dt=0;dt<4;dt++){
      int d = dt*16 + fr;
      float o = (out[dt][r]*fc + pg*kv0[1][d]) / lf;
      attn[(size_t)srow*768 + n*64 + d] = f2b(o);
    }
  }
}

// ---------------- global-token (row 0) full attention ----------------
__global__ __launch_bounds__(256)
void global_attn(const bf16* __restrict__ qkv, const float* __restrict__ qg,
                 const int* __restrict__ amask, bf16* __restrict__ attn)
{
  const int n = blockIdx.x;
  const int tid = threadIdx.x, wave = tid>>6, lane = tid&63;
  __shared__ float sg[2048];
  __shared__ float qh[64];
  __shared__ float red[8];
  __shared__ float part[4][64];
  if (tid < 64) qh[tid] = qg[n*64+tid];
  __syncthreads();

  float smax = -3.0e38f;
  for (int p=0;p<8;p++){
    int s = p*256 + tid;
    const uint4* kr = (const uint4*)(qkv + (size_t)s*3840 + 2304 + n*64);
    float acc = 0.f;
    #pragma unroll
    for (int d8=0; d8<8; d8++){
      float f[8]; unpack8(kr[d8], f);
      #pragma unroll
      for (int e=0;e<8;e++) acc += f[e]*qh[d8*8+e];
    }
    if (amask[s] == 0) acc = -kNEG;
    sg[s] = acc;
    smax = fmaxf(smax, acc);
  }
  #pragma unroll
  for (int mk=32; mk>=1; mk>>=1) smax = fmaxf(smax, __shfl_xor(smax, mk));
  if (lane==0) red[wave] = smax;
  __syncthreads();
  smax = fmaxf(fmaxf(red[0],red[1]),fmaxf(red[2],red[3]));
  float ssum = 0.f;
  for (int p=0;p<8;p++){
    int s = p*256 + tid;
    float e = __expf(sg[s]-smax);
    sg[s] = e;
    ssum += e;
  }
  #pragma unroll
  for (int mk=32; mk>=1; mk>>=1) ssum += __shfl_xor(ssum, mk);
  if (lane==0) red[4+wave] = ssum;
  __syncthreads();
  float total = red[4]+red[5]+red[6]+red[7];

  float o0=0.f,o1=0.f,o2=0.f,o3=0.f;
  const int base = wave*512;
  for (int s = base; s < base+512; s+=4){
    o0 += sg[s]   * b2f(qkv[(size_t)s*3840     + 3072 + n*64 + lane]);
    o1 += sg[s+1] * b2f(qkv[(size_t)(s+1)*3840 + 3072 + n*64 + lane]);
    o2 += sg[s+2] * b2f(qkv[(size_t)(s+2)*3840 + 3072 + n*64 + lane]);
    o3 += sg[s+3] * b2f(qkv[(size_t)(s+3)*3840 + 3072 + n*64 + lane]);
  }
  part[wave][lane] = (o0+o1)+(o2+o3);
  __syncthreads();
  if (tid < 64) {
    float oo = (part[0][tid]+part[1][tid]+part[2][tid]+part[3][tid]) / total;
    attn[n*64+tid] = f2b(oo);   // sequence row 0
  }
}

// ---------------- head (all f32) ----------------
__global__ void head_dense(const float* __restrict__ h0, const float* __restrict__ dw,
                           const float* __restrict__ db, float* __restrict__ y)
{
  const int col = blockIdx.x*64 + threadIdx.x; // 768
  float acc = 0.f;
  #pragma unroll 8
  for (int k=0;k<768;k++) acc += h0[k]*dw[(size_t)k*768 + col];
  y[col] = tanhf(acc + db[col]);
}

__global__ void head_out(const float* __restrict__ y, const float* __restrict__ ow,
                         const float* __restrict__ ob, float* __restrict__ out)
{
  const int col = blockIdx.x*64 + threadIdx.x; // 256
  float acc = 0.f;
  #pragma unroll 8
  for (int k=0;k<768;k++) acc += y[k]*ow[(size_t)k*256 + col];
  out[col] = acc + ob[col];
}

// ---------------- host ----------------
extern "C" void kernel_launch(void* const* d_in, const int* in_sizes, int n_in,
                              void* d_out, int out_size, void* d_ws, size_t ws_size,
                              hipStream_t stream)
{
  const int*   ids   = (const int*)d_in[0];
  const int*   amask = (const int*)d_in[1];
  const int*   gmask = (const int*)d_in[2];
  const float* wemb  = (const float*)d_in[3];
  const float* pemb  = (const float*)d_in[4];
  const float* elns  = (const float*)d_in[5];
  const float* elnb  = (const float*)d_in[6];
  const float* Wq    = (const float*)d_in[7];
  const float* bq    = (const float*)d_in[8];
  const float* Wk    = (const float*)d_in[9];
  const float* bk    = (const float*)d_in[10];
  const float* Wv    = (const float*)d_in[11];
  const float* bv    = (const float*)d_in[12];
  const float* Wqg   = (const float*)d_in[13];
  const float* bqg   = (const float*)d_in[14];
  const float* Wkg   = (const float*)d_in[15];
  const float* bkg   = (const float*)d_in[16];
  const float* Wvg   = (const float*)d_in[17];
  const float* bvg   = (const float*)d_in[18];
  const float* Wo    = (const float*)d_in[19];
  const float* bo    = (const float*)d_in[20];
  const float* ln1s  = (const float*)d_in[21];
  const float* ln1b  = (const float*)d_in[22];
  const float* Wf1   = (const float*)d_in[23];
  const float* bf1   = (const float*)d_in[24];
  const float* Wf2   = (const float*)d_in[25];
  const float* bf2   = (const float*)d_in[26];
  const float* ln2s  = (const float*)d_in[27];
  const float* ln2b  = (const float*)d_in[28];
  const float* dw    = (const float*)d_in[29];
  const float* db    = (const float*)d_in[30];
  const float* ow    = (const float*)d_in[31];
  const float* ob    = (const float*)d_in[32];

  char* ws = (char*)d_ws;
  size_t off = 0;
  auto alloc = [&](size_t bytes)->char*{
    char* p = ws + off; off += (bytes + 255) & ~(size_t)255; return p;
  };
  float* h    = (float*)alloc((size_t)2048*768*4);
  bf16*  hb   = (bf16*) alloc((size_t)2048*768*2);
  float* h2   = (float*)alloc((size_t)2048*768*4);
  bf16*  h2b  = (bf16*) alloc((size_t)2048*768*2);
  bf16*  qkv  = (bf16*) alloc((size_t)2048*3840*2);
  bf16*  att  = (bf16*) alloc((size_t)2048*768*2);
  float* proj = (float*)alloc((size_t)2048*768*4);
  bf16*  f1   = (bf16*) alloc((size_t)2048*3072*2);
  float* ffb  = (float*)alloc((size_t)2048*768*4);
  bf16*  WcatT= (bf16*) alloc((size_t)3840*768*2);
  bf16*  WoT  = (bf16*) alloc((size_t)768*768*2);
  bf16*  Wf1T = (bf16*) alloc((size_t)3072*768*2);
  bf16*  Wf2T = (bf16*) alloc((size_t)768*3072*2);
  float* bcat = (float*)alloc((size_t)3840*4);
  float* qg   = (float*)alloc(768*4);
  float* y    = (float*)alloc(768*4);

  embed_ln<<<2048,256,0,stream>>>(ids, wemb, pemb, elns, elnb, h, hb);

  for (int l=0; l<12; l++) {
    const size_t oHH = (size_t)l*768*768;
    const size_t oH  = (size_t)l*768;
    const size_t oHF = (size_t)l*768*3072;
    const size_t oF  = (size_t)l*3072;
    prep_layer<<<2031,256,0,stream>>>(Wq+oHH, Wk+oHH, Wv+oHH, Wkg+oHH, Wvg+oHH,
                                      Wo+oHH, Wf1+oHF, Wf2+oHF,
                                      bq+oH, bk+oH, bv+oH, bkg+oH, bvg+oH,
                                      WcatT, WoT, Wf1T, Wf2T, bcat);
    gemm_bt<0,1,0><<<dim3(16,30),256,0,stream>>>(hb, WcatT, bcat, nullptr, qkv,
                                                 2048, 3840, 768);
    qg_kernel<<<3,256,0,stream>>>(h, Wqg+oHH, bqg+oH, qg);
    band_attn<<<dim3(8,12,4),256,0,stream>>>(qkv, amask, gmask, att);
    global_attn<<<12,256,0,stream>>>(qkv, qg, amask, att);
    gemm_bt<1,0,0><<<dim3(16,6),256,0,stream>>>(att, WoT, bo+oH, proj, nullptr,
                                                2048, 768, 768);
    add_ln<<<2048,256,0,stream>>>(h, proj, ln1s+oH, ln1b+oH, h2, h2b);
    gemm_bt<0,1,1><<<dim3(16,24),256,0,stream>>>(h2b, Wf1T, bf1+oF, nullptr, f1,
                                                 2048, 3072, 768);
    gemm_bt<1,0,0><<<dim3(16,6),256,0,stream>>>(f1, Wf2T, bf2+oH, ffb, nullptr,
                                                2048, 768, 3072);
    add_ln<<<2048,256,0,stream>>>(h2, ffb, ln2s+oH, ln2b+oH, h, hb);
  }

  head_dense<<<12,64,0,stream>>>(h, dw, db, y);
  head_out<<<4,64,0,stream>>>(y, ow, ob, (float*)d_out);
}

// Round 4
// 3084.030 us; speedup vs baseline: 1.8596x; 1.2214x over previous
//
#include <hip/hip_runtime.h>
#include <hip/hip_bf16.h>

typedef __hip_bfloat16 bf16;
using bf16x8 = __attribute__((ext_vector_type(8))) short;
using f32x4  = __attribute__((ext_vector_type(4))) float;

#define kNEG 1.0e9f

__device__ __forceinline__ float b2f(bf16 x){ return __bfloat162float(x); }
__device__ __forceinline__ bf16  f2b(float x){ return __float2bfloat16(x); }

#define GLDS16(gp, lp) __builtin_amdgcn_global_load_lds( \
    (const __attribute__((address_space(1))) void*)(gp), \
    (__attribute__((address_space(3))) void*)(lp), 16, 0, 0)

__device__ __forceinline__ void unpack8(uint4 u, float* f){
  f[0]=__uint_as_float(u.x<<16); f[1]=__uint_as_float(u.x&0xffff0000u);
  f[2]=__uint_as_float(u.y<<16); f[3]=__uint_as_float(u.y&0xffff0000u);
  f[4]=__uint_as_float(u.z<<16); f[5]=__uint_as_float(u.z&0xffff0000u);
  f[6]=__uint_as_float(u.w<<16); f[7]=__uint_as_float(u.w&0xffff0000u);
}

// ---------------- embedding + LN ----------------
__global__ __launch_bounds__(256)
void embed_ln(const int* __restrict__ ids, const float* __restrict__ wemb,
              const float* __restrict__ pemb, const float* __restrict__ lns,
              const float* __restrict__ lnb, float* __restrict__ hout,
              bf16* __restrict__ hbout)
{
  const int row = blockIdx.x;
  const int tid = threadIdx.x;
  const int wave = tid >> 6, lane = tid & 63;
  const int id = ids[row];
  float x[3];
  #pragma unroll
  for (int p=0;p<3;p++){
    int i = tid + p*256;
    x[p] = wemb[(size_t)id*768 + i] + pemb[(size_t)row*768 + i];
  }
  float s1 = x[0]+x[1]+x[2];
  float s2 = x[0]*x[0]+x[1]*x[1]+x[2]*x[2];
  #pragma unroll
  for (int m=32;m>=1;m>>=1){ s1 += __shfl_xor(s1,m); s2 += __shfl_xor(s2,m); }
  __shared__ float red[8];
  if (lane==0){ red[wave]=s1; red[4+wave]=s2; }
  __syncthreads();
  s1 = red[0]+red[1]+red[2]+red[3];
  s2 = red[4]+red[5]+red[6]+red[7];
  float mu = s1*(1.0f/768.0f);
  float var = s2*(1.0f/768.0f) - mu*mu;
  float rs = rsqrtf(var + 1e-5f);
  #pragma unroll
  for (int p=0;p<3;p++){
    int i = tid + p*256;
    float y = (x[p]-mu)*rs*lns[i] + lnb[i];
    hout[(size_t)row*768+i] = y;
    hbout[(size_t)row*768+i] = f2b(y);
  }
}

// ---------------- residual add (two deltas) + LN ----------------
__global__ __launch_bounds__(256)
void add_ln(const float* __restrict__ res, const float* __restrict__ d0,
            const float* __restrict__ d1,
            const float* __restrict__ lns, const float* __restrict__ lnb,
            float* __restrict__ hout, bf16* __restrict__ hbout)
{
  const int row = blockIdx.x;
  const int tid = threadIdx.x;
  const int wave = tid >> 6, lane = tid & 63;
  float x[3];
  #pragma unroll
  for (int p=0;p<3;p++){
    int i = tid + p*256;
    size_t idx = (size_t)row*768+i;
    x[p] = res[idx] + d0[idx] + d1[idx];
  }
  float s1 = x[0]+x[1]+x[2];
  float s2 = x[0]*x[0]+x[1]*x[1]+x[2]*x[2];
  #pragma unroll
  for (int m=32;m>=1;m>>=1){ s1 += __shfl_xor(s1,m); s2 += __shfl_xor(s2,m); }
  __shared__ float red[8];
  if (lane==0){ red[wave]=s1; red[4+wave]=s2; }
  __syncthreads();
  s1 = red[0]+red[1]+red[2]+red[3];
  s2 = red[4]+red[5]+red[6]+red[7];
  float mu = s1*(1.0f/768.0f);
  float var = s2*(1.0f/768.0f) - mu*mu;
  float rs = rsqrtf(var + 1e-5f);
  #pragma unroll
  for (int p=0;p<3;p++){
    int i = tid + p*256;
    float y = (x[p]-mu)*rs*lns[i] + lnb[i];
    hout[(size_t)row*768+i] = y;
    hbout[(size_t)row*768+i] = f2b(y);
  }
}

// ---------------- ALL-layer weight transpose (f32 -> bf16) + bias concat ----------------
// grid.x: [0,720) Wq..Wvg -> WcatT, [720,864) Wo, [864,1440) Wf1, [1440,2016) Wf2,
//         [2016,2031) bcat ; grid.y = layer
__global__ __launch_bounds__(256)
void prep_all(const float* __restrict__ Wq, const float* __restrict__ Wk,
              const float* __restrict__ Wv, const float* __restrict__ Wkg,
              const float* __restrict__ Wvg, const float* __restrict__ Wo,
              const float* __restrict__ Wf1, const float* __restrict__ Wf2,
              const float* __restrict__ bq, const float* __restrict__ bk,
              const float* __restrict__ bv, const float* __restrict__ bkg,
              const float* __restrict__ bvg,
              bf16* __restrict__ WcatT, bf16* __restrict__ WoT,
              bf16* __restrict__ Wf1T, bf16* __restrict__ Wf2T,
              float* __restrict__ bcat)
{
  const int b = blockIdx.x;
  const int l = blockIdx.y;
  const int tid = threadIdx.x;
  const size_t oHH = (size_t)l*768*768;
  const size_t oHF = (size_t)l*768*3072;
  const size_t oH  = (size_t)l*768;
  if (b >= 2016) {
    int i = (b-2016)*256 + tid;   // 0..3839
    int which = i / 768, j = i - which*768;
    float v;
    if      (which==0) v = bq[oH+j] * 0.125f;
    else if (which==1) v = bk[oH+j];
    else if (which==2) v = bv[oH+j];
    else if (which==3) v = bkg[oH+j];
    else               v = bvg[oH+j];
    bcat[(size_t)l*3840 + i] = v;
    return;
  }
  const float* src; bf16* dst; int K, N; float scale = 1.0f; int tile;
  if (b < 720) {
    int wsel = b / 144; tile = b - wsel*144;
    if      (wsel==0){ src=Wq+oHH;  scale=0.125f; }
    else if (wsel==1){ src=Wk+oHH; }
    else if (wsel==2){ src=Wv+oHH; }
    else if (wsel==3){ src=Wkg+oHH; }
    else             { src=Wvg+oHH; }
    dst = WcatT + (size_t)l*5*768*768 + (size_t)wsel*768*768; K=768; N=768;
  } else if (b < 864) { tile = b-720;  src=Wo+oHH;  dst=WoT +(size_t)l*768*768;  K=768;  N=768;  }
  else if (b < 1440)  { tile = b-864;  src=Wf1+oHF; dst=Wf1T+(size_t)l*768*3072; K=768;  N=3072; }
  else                { tile = b-1440; src=Wf2+oHF; dst=Wf2T+(size_t)l*768*3072; K=3072; N=768;  }
  const int ntn = N/64;
  const int tk = tile / ntn, tn = tile - tk*ntn;
  const int k0 = tk*64, n0 = tn*64;

  __shared__ float t[64][69];
  const int r  = tid >> 3;
  const int c8 = (tid & 7) << 3;
  #pragma unroll
  for (int p=0;p<2;p++){
    int kk = r + p*32;
    const float* s = &src[(size_t)(k0+kk)*N + n0 + c8];
    float4 v0 = *(const float4*)(s);
    float4 v1 = *(const float4*)(s+4);
    *(float4*)&t[kk][c8]   = v0;
    *(float4*)&t[kk][c8+4] = v1;
  }
  __syncthreads();
  #pragma unroll
  for (int p=0;p<2;p++){
    int nn = r + p*32;
    union { uint4 u; bf16 h[8]; } tmp;
    #pragma unroll
    for (int e=0;e<8;e++){
      tmp.h[e] = f2b(t[c8+e][nn]*scale);
    }
    *(uint4*)&dst[(size_t)(n0+nn)*K + k0 + c8] = tmp.u;
  }
}

// ---------------- MFMA GEMM: C[M][N] = A[M][K] @ Bt[N][K]^T + bias ----------------
// KSPLIT>1: blockIdx.z picks K-slice, partial written to outf + z*M*N (bias on z==0 only)
template<int OUTF, int OUTB, int GELU, int KSPLIT>
__global__ __launch_bounds__(256)
void gemm_bt(const bf16* __restrict__ A, const bf16* __restrict__ Bt,
             const float* __restrict__ bias,
             float* __restrict__ outf, bf16* __restrict__ outb,
             int M, int N, int K)
{
  __shared__ bf16 As[128*32];
  __shared__ bf16 Bs[128*32];
  const int tid  = threadIdx.x;
  const int lane = tid & 63;
  const int wave = tid >> 6;
  const int wm = wave >> 1, wn = wave & 1;
  const int bm = blockIdx.x, bn = blockIdx.y, bz = (KSPLIT>1) ? blockIdx.z : 0;
  const int fr = lane & 15;
  const int fk = lane >> 4;
  const int Ks = K / KSPLIT;
  const int kbeg = bz * Ks;

  const int srow = tid >> 2;
  const int scol = (tid & 3) << 3;
  const bf16* pa0 = A  + (size_t)(bm*128 + srow)*K      + kbeg + scol;
  const bf16* pa1 = A  + (size_t)(bm*128 + srow + 64)*K + kbeg + scol;
  const bf16* pb0 = Bt + (size_t)(bn*128 + srow)*K      + kbeg + scol;
  const bf16* pb1 = Bt + (size_t)(bn*128 + srow + 64)*K + kbeg + scol;
  bf16* lA0 = &As[srow*32 + scol];
  bf16* lA1 = &As[(srow+64)*32 + scol];
  bf16* lB0 = &Bs[srow*32 + scol];
  bf16* lB1 = &Bs[(srow+64)*32 + scol];

  f32x4 acc[4][4];
  const f32x4 zero = {0.f,0.f,0.f,0.f};
  #pragma unroll
  for (int i=0;i<4;i++)
    #pragma unroll
    for (int j=0;j<4;j++) acc[i][j] = zero;

  for (int k0 = 0; k0 < Ks; k0 += 32) {
    __syncthreads();
    GLDS16(pa0 + k0, lA0);
    GLDS16(pa1 + k0, lA1);
    GLDS16(pb0 + k0, lB0);
    GLDS16(pb1 + k0, lB1);
    __syncthreads();
    bf16x8 af[4], bfr[4];
    #pragma unroll
    for (int m=0;m<4;m++)
      af[m] = *reinterpret_cast<const bf16x8*>(&As[(wm*64 + m*16 + fr)*32 + fk*8]);
    #pragma unroll
    for (int n=0;n<4;n++)
      bfr[n] = *reinterpret_cast<const bf16x8*>(&Bs[(wn*64 + n*16 + fr)*32 + fk*8]);
    #pragma unroll
    for (int m=0;m<4;m++)
      #pragma unroll
      for (int n=0;n<4;n++)
        acc[m][n] = __builtin_amdgcn_mfma_f32_16x16x32_bf16(af[m], bfr[n], acc[m][n], 0,0,0);
  }

  const int row0 = bm*128 + wm*64 + (lane>>4)*4;
  const int col0 = bn*128 + wn*64 + fr;
  float* outfz = OUTF ? (outf + (size_t)bz*M*N) : nullptr;
  #pragma unroll
  for (int n=0;n<4;n++){
    const int col = col0 + n*16;
    const float bv = (bz==0) ? bias[col] : 0.f;
    #pragma unroll
    for (int m=0;m<4;m++){
      const int r0 = row0 + m*16;
      #pragma unroll
      for (int r=0;r<4;r++){
        float x = acc[m][n][r] + bv;
        if (GELU) x = 0.5f*x*(1.0f + erff(x*0.70710678118f));
        size_t idx = (size_t)(r0+r)*N + col;
        if (OUTF) outfz[idx] = x;
        if (OUTB) outb[idx] = f2b(x);
      }
    }
  }
}

// ---------------- band (sliding window + global col) attention, MFMA ----------------
// grid (c=8, n=12, rg=4); block 256 = 4 waves; wave handles 16 q-rows.
__global__ __launch_bounds__(256)
void band_attn(const bf16* __restrict__ qkv, const int* __restrict__ amask,
               const int* __restrict__ gmask, bf16* __restrict__ attn)
{
  const int c = blockIdx.x, n = blockIdx.y, rg = blockIdx.z;
  const int tid = threadIdx.x, wave = tid>>6, lane = tid&63;
  const int fr = lane & 15, fk = lane >> 4;

  __shared__ __attribute__((aligned(16))) bf16 q_s[64][72];
  __shared__ __attribute__((aligned(16))) bf16 k_s[64][72];
  __shared__ __attribute__((aligned(16))) bf16 vt_s[64][72];
  __shared__ __attribute__((aligned(16))) bf16 p_s[4][16][72];
  __shared__ int  okk_s[768];
  __shared__ float kv0[2][64];

  {
    const int j = tid >> 2, d0 = (tid & 3) * 16;
    const uint4* src = (const uint4*)(qkv + (size_t)(c*256 + rg*64 + j)*3840 + n*64 + d0);
    *(uint4*)&q_s[j][d0]   = src[0];
    *(uint4*)&q_s[j][d0+8] = src[1];
  }
  #pragma unroll
  for (int p=0;p<3;p++){
    int j = tid + p*256;
    int kpos = c*256 + j - 256;
    int ok = 0;
    if (kpos >= 0 && kpos < 2048) ok = (amask[kpos] != 0) && (gmask[kpos] == 0);
    okk_s[j] = ok;
  }
  if (tid < 64)       kv0[0][tid]    = b2f(qkv[768  + n*64 + tid]);
  else if (tid < 128) kv0[1][tid-64] = b2f(qkv[1536 + n*64 + (tid-64)]);

  float m[4], l[4];
  f32x4 out[4];
  const f32x4 zero = {0.f,0.f,0.f,0.f};
  #pragma unroll
  for (int r=0;r<4;r++){ m[r] = -kNEG; l[r] = 0.f; }
  #pragma unroll
  for (int dt=0;dt<4;dt++) out[dt] = zero;

  const int kt1 = (rg+8 < 11) ? rg+8 : 11;
  for (int kt = rg; kt <= kt1; kt++) {
    __syncthreads();
    {
      const int jj = tid >> 2, d0 = (tid & 3) * 16;
      int kpos = c*256 + kt*64 + jj - 256;
      int kq = kpos < 0 ? 0 : (kpos > 2047 ? 2047 : kpos);
      const uint4* ks = (const uint4*)(qkv + (size_t)kq*3840 + 768  + n*64 + d0);
      *(uint4*)&k_s[jj][d0]   = ks[0];
      *(uint4*)&k_s[jj][d0+8] = ks[1];
      const uint4* vs = (const uint4*)(qkv + (size_t)kq*3840 + 1536 + n*64 + d0);
      uint4 v0 = vs[0], v1 = vs[1];
      const bf16* ve0 = (const bf16*)&v0;
      const bf16* ve1 = (const bf16*)&v1;
      #pragma unroll
      for (int e=0;e<8;e++) vt_s[d0+e][jj]   = ve0[e];
      #pragma unroll
      for (int e=0;e<8;e++) vt_s[d0+8+e][jj] = ve1[e];
    }
    __syncthreads();

    f32x4 s[4];
    #pragma unroll
    for (int ct=0;ct<4;ct++) s[ct] = zero;
    #pragma unroll
    for (int ks=0;ks<2;ks++){
      bf16x8 aq = *reinterpret_cast<const bf16x8*>(&q_s[wave*16 + fr][ks*32 + fk*8]);
      #pragma unroll
      for (int ct=0;ct<4;ct++){
        bf16x8 bk = *reinterpret_cast<const bf16x8*>(&k_s[ct*16 + fr][ks*32 + fk*8]);
        s[ct] = __builtin_amdgcn_mfma_f32_16x16x32_bf16(aq, bk, s[ct], 0,0,0);
      }
    }
    const int qbase = rg*64 + wave*16 + fk*4;
    #pragma unroll
    for (int ct=0;ct<4;ct++){
      int j = kt*64 + ct*16 + fr;
      int okj = okk_s[j];
      #pragma unroll
      for (int r=0;r<4;r++){
        unsigned rel = (unsigned)(j - (qbase + r));
        s[ct][r] = (okj && rel <= 512u) ? s[ct][r] : -kNEG;
      }
    }
    float fac[4], psum[4];
    #pragma unroll
    for (int r=0;r<4;r++){
      float mm = fmaxf(fmaxf(s[0][r], s[1][r]), fmaxf(s[2][r], s[3][r]));
      #pragma unroll
      for (int mk=8; mk>=1; mk>>=1) mm = fmaxf(mm, __shfl_xor(mm, mk));
      float mn = fmaxf(m[r], mm);
      fac[r] = __expf(m[r] - mn);
      m[r] = mn;
      psum[r] = 0.f;
    }
    #pragma unroll
    for (int ct=0;ct<4;ct++){
      #pragma unroll
      for (int r=0;r<4;r++){
        float p = __expf(s[ct][r] - m[r]);
        psum[r] += p;
        p_s[wave][fk*4 + r][ct*16 + fr] = f2b(p);
      }
    }
    #pragma unroll
    for (int r=0;r<4;r++){
      float ts = psum[r];
      #pragma unroll
      for (int mk=8; mk>=1; mk>>=1) ts += __shfl_xor(ts, mk);
      l[r] = l[r]*fac[r] + ts;
    }
    #pragma unroll
    for (int dt=0;dt<4;dt++)
      #pragma unroll
      for (int r=0;r<4;r++) out[dt][r] *= fac[r];
    #pragma unroll
    for (int ks=0;ks<2;ks++){
      bf16x8 ap = *reinterpret_cast<const bf16x8*>(&p_s[wave][fr][ks*32 + fk*8]);
      #pragma unroll
      for (int dt=0;dt<4;dt++){
        bf16x8 bv = *reinterpret_cast<const bf16x8*>(&vt_s[dt*16 + fr][ks*32 + fk*8]);
        out[dt] = __builtin_amdgcn_mfma_f32_16x16x32_bf16(ap, bv, out[dt], 0,0,0);
      }
    }
  }

  const bool okg = (amask[0] != 0);
  #pragma unroll
  for (int r=0;r<4;r++){
    const int row16 = fk*4 + r;
    float sp = 0.f;
    #pragma unroll
    for (int e=0;e<4;e++){
      int d = fr*4 + e;
      sp += b2f(q_s[wave*16 + row16][d]) * kv0[0][d];
    }
    #pragma unroll
    for (int mk=8; mk>=1; mk>>=1) sp += __shfl_xor(sp, mk);
    float sg = okg ? sp : -kNEG;
    float mn = fmaxf(m[r], sg);
    float fc = __expf(m[r]-mn);
    float pg = __expf(sg-mn);
    float lf = l[r]*fc + pg;
    const int srow = c*256 + rg*64 + wave*16 + row16;
    #pragma unroll
    for (int dt=0;dt<4;dt++){
      int d = dt*16 + fr;
      float o = (out[dt][r]*fc + pg*kv0[1][d]) / lf;
      attn[(size_t)srow*768 + n*64 + d] = f2b(o);
    }
  }
}

// ---------------- global-token (row 0) full attention, qg fused ----------------
__global__ __launch_bounds__(256)
void global_attn(const bf16* __restrict__ qkv, const float* __restrict__ h0,
                 const float* __restrict__ Wqg, const float* __restrict__ bqg,
                 const int* __restrict__ amask, bf16* __restrict__ attn)
{
  const int n = blockIdx.x;
  const int tid = threadIdx.x, wave = tid>>6, lane = tid&63;
  __shared__ float sg[2048];
  __shared__ float qh[64];
  __shared__ float red[8];
  __shared__ float part[4][64];

  // qg slice for this head: col = n*64 + d
  {
    const int d = tid & 63;
    const int w = tid >> 6;
    const float* wp = Wqg + (size_t)(w*192)*768 + n*64 + d;
    float a = 0.f;
    #pragma unroll 8
    for (int k=0;k<192;k++) a += h0[w*192+k] * wp[(size_t)k*768];
    part[w][d] = a;
  }
  __syncthreads();
  if (tid < 64)
    qh[tid] = (part[0][tid]+part[1][tid]+part[2][tid]+part[3][tid] + bqg[n*64+tid]) * 0.125f;
  __syncthreads();

  float smax = -3.0e38f;
  for (int p=0;p<8;p++){
    int s = p*256 + tid;
    const uint4* kr = (const uint4*)(qkv + (size_t)s*3840 + 2304 + n*64);
    float acc = 0.f;
    #pragma unroll
    for (int d8=0; d8<8; d8++){
      float f[8]; unpack8(kr[d8], f);
      #pragma unroll
      for (int e=0;e<8;e++) acc += f[e]*qh[d8*8+e];
    }
    if (amask[s] == 0) acc = -kNEG;
    sg[s] = acc;
    smax = fmaxf(smax, acc);
  }
  #pragma unroll
  for (int mk=32; mk>=1; mk>>=1) smax = fmaxf(smax, __shfl_xor(smax, mk));
  if (lane==0) red[wave] = smax;
  __syncthreads();
  smax = fmaxf(fmaxf(red[0],red[1]),fmaxf(red[2],red[3]));
  float ssum = 0.f;
  for (int p=0;p<8;p++){
    int s = p*256 + tid;
    float e = __expf(sg[s]-smax);
    sg[s] = e;
    ssum += e;
  }
  #pragma unroll
  for (int mk=32; mk>=1; mk>>=1) ssum += __shfl_xor(ssum, mk);
  if (lane==0) red[4+wave] = ssum;
  __syncthreads();
  float total = red[4]+red[5]+red[6]+red[7];
  __syncthreads();

  float o0=0.f,o1=0.f,o2=0.f,o3=0.f;
  const int base = wave*512;
  for (int s = base; s < base+512; s+=4){
    o0 += sg[s]   * b2f(qkv[(size_t)s*3840     + 3072 + n*64 + lane]);
    o1 += sg[s+1] * b2f(qkv[(size_t)(s+1)*3840 + 3072 + n*64 + lane]);
    o2 += sg[s+2] * b2f(qkv[(size_t)(s+2)*3840 + 3072 + n*64 + lane]);
    o3 += sg[s+3] * b2f(qkv[(size_t)(s+3)*3840 + 3072 + n*64 + lane]);
  }
  part[wave][lane] = (o0+o1)+(o2+o3);
  __syncthreads();
  if (tid < 64) {
    float oo = (part[0][tid]+part[1][tid]+part[2][tid]+part[3][tid]) / total;
    attn[n*64+tid] = f2b(oo);   // sequence row 0
  }
}

// ---------------- head: tanh(h0 @ dw + db) @ ow + ob  (single block) ----------------
__global__ __launch_bounds__(768)
void head(const float* __restrict__ h0, const float* __restrict__ dw,
          const float* __restrict__ db, const float* __restrict__ ow,
          const float* __restrict__ ob, float* __restrict__ out)
{
  __shared__ float y[768];
  const int tid = threadIdx.x;
  float acc = 0.f;
  #pragma unroll 8
  for (int k=0;k<768;k++) acc += h0[k]*dw[(size_t)k*768 + tid];
  y[tid] = tanhf(acc + db[tid]);
  __syncthreads();
  if (tid < 256) {
    float a = 0.f;
    #pragma unroll 8
    for (int k=0;k<768;k++) a += y[k]*ow[(size_t)k*256 + tid];
    out[tid] = a + ob[tid];
  }
}

// ---------------- host ----------------
extern "C" void kernel_launch(void* const* d_in, const int* in_sizes, int n_in,
                              void* d_out, int out_size, void* d_ws, size_t ws_size,
                              hipStream_t stream)
{
  const int*   ids   = (const int*)d_in[0];
  const int*   amask = (const int*)d_in[1];
  const int*   gmask = (const int*)d_in[2];
  const float* wemb  = (const float*)d_in[3];
  const float* pemb  = (const float*)d_in[4];
  const float* elns  = (const float*)d_in[5];
  const float* elnb  = (const float*)d_in[6];
  const float* Wq    = (const float*)d_in[7];
  const float* bq    = (const float*)d_in[8];
  const float* Wk    = (const float*)d_in[9];
  const float* bk    = (const float*)d_in[10];
  const float* Wv    = (const float*)d_in[11];
  const float* bv    = (const float*)d_in[12];
  const float* Wqg   = (const float*)d_in[13];
  const float* bqg   = (const float*)d_in[14];
  const float* Wkg   = (const float*)d_in[15];
  const float* bkg   = (const float*)d_in[16];
  const float* Wvg   = (const float*)d_in[17];
  const float* bvg   = (const float*)d_in[18];
  const float* Wo    = (const float*)d_in[19];
  const float* bo    = (const float*)d_in[20];
  const float* ln1s  = (const float*)d_in[21];
  const float* ln1b  = (const float*)d_in[22];
  const float* Wf1   = (const float*)d_in[23];
  const float* bf1   = (const float*)d_in[24];
  const float* Wf2   = (const float*)d_in[25];
  const float* bf2   = (const float*)d_in[26];
  const float* ln2s  = (const float*)d_in[27];
  const float* ln2b  = (const float*)d_in[28];
  const float* dw    = (const float*)d_in[29];
  const float* db    = (const float*)d_in[30];
  const float* ow    = (const float*)d_in[31];
  const float* ob    = (const float*)d_in[32];

  char* ws = (char*)d_ws;
  size_t off = 0;
  auto alloc = [&](size_t bytes)->char*{
    char* p = ws + off; off += (bytes + 255) & ~(size_t)255; return p;
  };
  float* h     = (float*)alloc((size_t)2048*768*4);
  bf16*  hb    = (bf16*) alloc((size_t)2048*768*2);
  float* h2    = (float*)alloc((size_t)2048*768*4);
  bf16*  h2b   = (bf16*) alloc((size_t)2048*768*2);
  bf16*  qkv   = (bf16*) alloc((size_t)2048*3840*2);   // also reused as f32 split-K partials
  bf16*  att   = (bf16*) alloc((size_t)2048*768*2);
  bf16*  f1    = (bf16*) alloc((size_t)2048*3072*2);
  bf16*  WcatT = (bf16*) alloc((size_t)12*5*768*768*2);
  bf16*  WoT   = (bf16*) alloc((size_t)12*768*768*2);
  bf16*  Wf1T  = (bf16*) alloc((size_t)12*768*3072*2);
  bf16*  Wf2T  = (bf16*) alloc((size_t)12*768*3072*2);
  float* bcat  = (float*)alloc((size_t)12*3840*4);
  float* pf    = (float*)qkv;                          // 2 x 2048*768 f32 fits in qkv
  const size_t MN = (size_t)2048*768;

  prep_all<<<dim3(2031,12),256,0,stream>>>(Wq, Wk, Wv, Wkg, Wvg, Wo, Wf1, Wf2,
                                           bq, bk, bv, bkg, bvg,
                                           WcatT, WoT, Wf1T, Wf2T, bcat);
  embed_ln<<<2048,256,0,stream>>>(ids, wemb, pemb, elns, elnb, h, hb);

  for (int l=0; l<12; l++) {
    const size_t oHH = (size_t)l*768*768;
    const size_t oH  = (size_t)l*768;
    const size_t oF  = (size_t)l*3072;
    const bf16* WcatT_l = WcatT + (size_t)l*5*768*768;
    const bf16* WoT_l   = WoT   + (size_t)l*768*768;
    const bf16* Wf1T_l  = Wf1T  + (size_t)l*768*3072;
    const bf16* Wf2T_l  = Wf2T  + (size_t)l*768*3072;
    const float* bcat_l = bcat  + (size_t)l*3840;

    gemm_bt<0,1,0,1><<<dim3(16,30),256,0,stream>>>(hb, WcatT_l, bcat_l, nullptr, qkv,
                                                   2048, 3840, 768);
    band_attn<<<dim3(8,12,4),256,0,stream>>>(qkv, amask, gmask, att);
    global_attn<<<12,256,0,stream>>>(qkv, h, Wqg+oHH, bqg+oH, amask, att);
    gemm_bt<1,0,0,2><<<dim3(16,6,2),256,0,stream>>>(att, WoT_l, bo+oH, pf, nullptr,
                                                    2048, 768, 768);
    add_ln<<<2048,256,0,stream>>>(h, pf, pf+MN, ln1s+oH, ln1b+oH, h2, h2b);
    gemm_bt<0,1,1,1><<<dim3(16,24),256,0,stream>>>(h2b, Wf1T_l, bf1+oF, nullptr, f1,
                                                   2048, 3072, 768);
    gemm_bt<1,0,0,2><<<dim3(16,6,2),256,0,stream>>>(f1, Wf2T_l, bf2+oH, pf, nullptr,
                                                    2048, 768, 3072);
    add_ln<<<2048,256,0,stream>>>(h2, pf, pf+MN, ln2s+oH, ln2b+oH, h, hb);
  }

  head<<<1,768,0,stream>>>(h, dw, db, ow, ob, (float*)d_out);
}

// Round 5
// 2912.804 us; speedup vs baseline: 1.9689x; 1.0588x over previous
//
#include <hip/hip_runtime.h>
#include <hip/hip_bf16.h>

typedef __hip_bfloat16 bf16;
using bf16x8 = __attribute__((ext_vector_type(8))) short;
using f32x4  = __attribute__((ext_vector_type(4))) float;

#define kNEG 1.0e9f

__device__ __forceinline__ float b2f(bf16 x){ return __bfloat162float(x); }
__device__ __forceinline__ bf16  f2b(float x){ return __float2bfloat16(x); }

#define GLDS16(gp, lp) __builtin_amdgcn_global_load_lds( \
    (const __attribute__((address_space(1))) void*)(gp), \
    (__attribute__((address_space(3))) void*)(lp), 16, 0, 0)

__device__ __forceinline__ void unpack8(uint4 u, float* f){
  f[0]=__uint_as_float(u.x<<16); f[1]=__uint_as_float(u.x&0xffff0000u);
  f[2]=__uint_as_float(u.y<<16); f[3]=__uint_as_float(u.y&0xffff0000u);
  f[4]=__uint_as_float(u.z<<16); f[5]=__uint_as_float(u.z&0xffff0000u);
  f[6]=__uint_as_float(u.w<<16); f[7]=__uint_as_float(u.w&0xffff0000u);
}

// ---------------- embedding + LN ----------------
__global__ __launch_bounds__(256)
void embed_ln(const int* __restrict__ ids, const float* __restrict__ wemb,
              const float* __restrict__ pemb, const float* __restrict__ lns,
              const float* __restrict__ lnb, float* __restrict__ hout,
              bf16* __restrict__ hbout)
{
  const int row = blockIdx.x;
  const int tid = threadIdx.x;
  const int wave = tid >> 6, lane = tid & 63;
  const int id = ids[row];
  float x[3];
  #pragma unroll
  for (int p=0;p<3;p++){
    int i = tid + p*256;
    x[p] = wemb[(size_t)id*768 + i] + pemb[(size_t)row*768 + i];
  }
  float s1 = x[0]+x[1]+x[2];
  float s2 = x[0]*x[0]+x[1]*x[1]+x[2]*x[2];
  #pragma unroll
  for (int m=32;m>=1;m>>=1){ s1 += __shfl_xor(s1,m); s2 += __shfl_xor(s2,m); }
  __shared__ float red[8];
  if (lane==0){ red[wave]=s1; red[4+wave]=s2; }
  __syncthreads();
  s1 = red[0]+red[1]+red[2]+red[3];
  s2 = red[4]+red[5]+red[6]+red[7];
  float mu = s1*(1.0f/768.0f);
  float var = s2*(1.0f/768.0f) - mu*mu;
  float rs = rsqrtf(var + 1e-5f);
  #pragma unroll
  for (int p=0;p<3;p++){
    int i = tid + p*256;
    float y = (x[p]-mu)*rs*lns[i] + lnb[i];
    hout[(size_t)row*768+i] = y;
    hbout[(size_t)row*768+i] = f2b(y);
  }
}

// ---------------- residual add (two deltas) + LN ----------------
__global__ __launch_bounds__(256)
void add_ln(const float* __restrict__ res, const float* __restrict__ d0,
            const float* __restrict__ d1,
            const float* __restrict__ lns, const float* __restrict__ lnb,
            float* __restrict__ hout, bf16* __restrict__ hbout)
{
  const int row = blockIdx.x;
  const int tid = threadIdx.x;
  const int wave = tid >> 6, lane = tid & 63;
  float x[3];
  #pragma unroll
  for (int p=0;p<3;p++){
    int i = tid + p*256;
    size_t idx = (size_t)row*768+i;
    x[p] = res[idx] + d0[idx] + d1[idx];
  }
  float s1 = x[0]+x[1]+x[2];
  float s2 = x[0]*x[0]+x[1]*x[1]+x[2]*x[2];
  #pragma unroll
  for (int m=32;m>=1;m>>=1){ s1 += __shfl_xor(s1,m); s2 += __shfl_xor(s2,m); }
  __shared__ float red[8];
  if (lane==0){ red[wave]=s1; red[4+wave]=s2; }
  __syncthreads();
  s1 = red[0]+red[1]+red[2]+red[3];
  s2 = red[4]+red[5]+red[6]+red[7];
  float mu = s1*(1.0f/768.0f);
  float var = s2*(1.0f/768.0f) - mu*mu;
  float rs = rsqrtf(var + 1e-5f);
  #pragma unroll
  for (int p=0;p<3;p++){
    int i = tid + p*256;
    float y = (x[p]-mu)*rs*lns[i] + lnb[i];
    hout[(size_t)row*768+i] = y;
    hbout[(size_t)row*768+i] = f2b(y);
  }
}

// ---------------- ALL-layer weight transpose (f32 -> bf16) + bias concat ----------------
__global__ __launch_bounds__(256)
void prep_all(const float* __restrict__ Wq, const float* __restrict__ Wk,
              const float* __restrict__ Wv, const float* __restrict__ Wkg,
              const float* __restrict__ Wvg, const float* __restrict__ Wo,
              const float* __restrict__ Wf1, const float* __restrict__ Wf2,
              const float* __restrict__ bq, const float* __restrict__ bk,
              const float* __restrict__ bv, const float* __restrict__ bkg,
              const float* __restrict__ bvg,
              bf16* __restrict__ WcatT, bf16* __restrict__ WoT,
              bf16* __restrict__ Wf1T, bf16* __restrict__ Wf2T,
              float* __restrict__ bcat)
{
  const int b = blockIdx.x;
  const int l = blockIdx.y;
  const int tid = threadIdx.x;
  const size_t oHH = (size_t)l*768*768;
  const size_t oHF = (size_t)l*768*3072;
  const size_t oH  = (size_t)l*768;
  if (b >= 2016) {
    int i = (b-2016)*256 + tid;   // 0..3839
    int which = i / 768, j = i - which*768;
    float v;
    if      (which==0) v = bq[oH+j] * 0.125f;
    else if (which==1) v = bk[oH+j];
    else if (which==2) v = bv[oH+j];
    else if (which==3) v = bkg[oH+j];
    else               v = bvg[oH+j];
    bcat[(size_t)l*3840 + i] = v;
    return;
  }
  const float* src; bf16* dst; int K, N; float scale = 1.0f; int tile;
  if (b < 720) {
    int wsel = b / 144; tile = b - wsel*144;
    if      (wsel==0){ src=Wq+oHH;  scale=0.125f; }
    else if (wsel==1){ src=Wk+oHH; }
    else if (wsel==2){ src=Wv+oHH; }
    else if (wsel==3){ src=Wkg+oHH; }
    else             { src=Wvg+oHH; }
    dst = WcatT + (size_t)l*5*768*768 + (size_t)wsel*768*768; K=768; N=768;
  } else if (b < 864) { tile = b-720;  src=Wo+oHH;  dst=WoT +(size_t)l*768*768;  K=768;  N=768;  }
  else if (b < 1440)  { tile = b-864;  src=Wf1+oHF; dst=Wf1T+(size_t)l*768*3072; K=768;  N=3072; }
  else                { tile = b-1440; src=Wf2+oHF; dst=Wf2T+(size_t)l*768*3072; K=3072; N=768;  }
  const int ntn = N/64;
  const int tk = tile / ntn, tn = tile - tk*ntn;
  const int k0 = tk*64, n0 = tn*64;

  __shared__ float t[64][69];
  const int r  = tid >> 3;
  const int c8 = (tid & 7) << 3;
  #pragma unroll
  for (int p=0;p<2;p++){
    int kk = r + p*32;
    const float* s = &src[(size_t)(k0+kk)*N + n0 + c8];
    float4 v0 = *(const float4*)(s);
    float4 v1 = *(const float4*)(s+4);
    *(float4*)&t[kk][c8]   = v0;
    *(float4*)&t[kk][c8+4] = v1;
  }
  __syncthreads();
  #pragma unroll
  for (int p=0;p<2;p++){
    int nn = r + p*32;
    union { uint4 u; bf16 h[8]; } tmp;
    #pragma unroll
    for (int e=0;e<8;e++){
      tmp.h[e] = f2b(t[c8+e][nn]*scale);
    }
    *(uint4*)&dst[(size_t)(n0+nn)*K + k0 + c8] = tmp.u;
  }
}

// ---------------- MFMA GEMM (2-phase prefetch, dbuf LDS) ----------------
// C[M][N] = A[M][K] @ Bt[N][K]^T + bias
// KSPLIT>1: blockIdx.z picks K-slice, partial -> outf + z*M*N (bias on z==0)
// VT: also scatter V-region cols (1536..2304) transposed into vt[(col-1536)][row]
template<int OUTF, int OUTB, int GELU, int KSPLIT, int VT>
__global__ __launch_bounds__(256)
void gemm_bt(const bf16* __restrict__ A, const bf16* __restrict__ Bt,
             const float* __restrict__ bias,
             float* __restrict__ outf, bf16* __restrict__ outb,
             bf16* __restrict__ vt,
             int M, int N, int K)
{
  __shared__ bf16 As[2][128*32];
  __shared__ bf16 Bs[2][128*32];
  const int tid  = threadIdx.x;
  const int lane = tid & 63;
  const int wave = tid >> 6;
  const int wm = wave >> 1, wn = wave & 1;
  const int bm = blockIdx.x, bn = blockIdx.y, bz = (KSPLIT>1) ? blockIdx.z : 0;
  const int fr = lane & 15;
  const int fk = lane >> 4;
  const int Ks = K / KSPLIT;
  const int nt = Ks / 32;
  const int kbeg = bz * Ks;

  const int srow = tid >> 2;
  const int scol = (tid & 3) << 3;
  const bf16* pa0 = A  + (size_t)(bm*128 + srow)*K      + kbeg + scol;
  const bf16* pa1 = A  + (size_t)(bm*128 + srow + 64)*K + kbeg + scol;
  const bf16* pb0 = Bt + (size_t)(bn*128 + srow)*K      + kbeg + scol;
  const bf16* pb1 = Bt + (size_t)(bn*128 + srow + 64)*K + kbeg + scol;
  const int l0 = srow*32 + scol;
  const int l1 = (srow+64)*32 + scol;

  f32x4 acc[4][4];
  const f32x4 zero = {0.f,0.f,0.f,0.f};
  #pragma unroll
  for (int i=0;i<4;i++)
    #pragma unroll
    for (int j=0;j<4;j++) acc[i][j] = zero;

  // prologue: stage tile 0 into buf 0
  GLDS16(pa0, &As[0][l0]);
  GLDS16(pa1, &As[0][l1]);
  GLDS16(pb0, &Bs[0][l0]);
  GLDS16(pb1, &Bs[0][l1]);
  __syncthreads();          // drains vmcnt(0) + barrier

  int cur = 0;
  for (int t = 0; t < nt; ++t) {
    if (t+1 < nt) {         // stage next tile into buf cur^1 (overlaps compute)
      const int ko = (t+1)*32;
      GLDS16(pa0 + ko, &As[cur^1][l0]);
      GLDS16(pa1 + ko, &As[cur^1][l1]);
      GLDS16(pb0 + ko, &Bs[cur^1][l0]);
      GLDS16(pb1 + ko, &Bs[cur^1][l1]);
    }
    bf16x8 af[4], bfr[4];
    #pragma unroll
    for (int m=0;m<4;m++)
      af[m] = *reinterpret_cast<const bf16x8*>(&As[cur][(wm*64 + m*16 + fr)*32 + fk*8]);
    #pragma unroll
    for (int n=0;n<4;n++)
      bfr[n] = *reinterpret_cast<const bf16x8*>(&Bs[cur][(wn*64 + n*16 + fr)*32 + fk*8]);
    #pragma unroll
    for (int m=0;m<4;m++)
      #pragma unroll
      for (int n=0;n<4;n++)
        acc[m][n] = __builtin_amdgcn_mfma_f32_16x16x32_bf16(af[m], bfr[n], acc[m][n], 0,0,0);
    __syncthreads();        // drains next-tile staging + all lgkm; flips buffers
    cur ^= 1;
  }

  const int row0 = bm*128 + wm*64 + (lane>>4)*4;
  const int col0 = bn*128 + wn*64 + fr;
  float* outfz = OUTF ? (outf + (size_t)bz*M*N) : nullptr;
  #pragma unroll
  for (int n=0;n<4;n++){
    const int col = col0 + n*16;
    const float bv = (bz==0) ? bias[col] : 0.f;
    #pragma unroll
    for (int m=0;m<4;m++){
      const int r0 = row0 + m*16;
      union { ushort4 u; bf16 h[4]; } pk;
      #pragma unroll
      for (int r=0;r<4;r++){
        float x = acc[m][n][r] + bv;
        if (GELU) x = 0.5f*x*(1.0f + erff(x*0.70710678118f));
        size_t idx = (size_t)(r0+r)*N + col;
        pk.h[r] = f2b(x);
        if (OUTF) outfz[idx] = x;
        if (OUTB) outb[idx] = pk.h[r];
      }
      if (VT) {
        if (col >= 1536 && col < 2304)
          *(ushort4*)&vt[(size_t)(col-1536)*2048 + r0] = pk.u;
      }
    }
  }
}

// ---------------- band (sliding window + global col) attention, MFMA ----------------
// grid (c=8, n=12, rg=4); block 256 = 4 waves; wave handles 16 q-rows.
// double-buffered K/V^T tiles, register prefetch, 1 barrier per tile.
__global__ __launch_bounds__(256)
void band_attn(const bf16* __restrict__ qkv, const bf16* __restrict__ Vt,
               const int* __restrict__ amask, const int* __restrict__ gmask,
               bf16* __restrict__ attn)
{
  const int c = blockIdx.x, n = blockIdx.y, rg = blockIdx.z;
  const int tid = threadIdx.x, wave = tid>>6, lane = tid&63;
  const int fr = lane & 15, fk = lane >> 4;
  const int jj = tid >> 2, seg = tid & 3;

  __shared__ __attribute__((aligned(16))) bf16 q_s[64][72];
  __shared__ __attribute__((aligned(16))) bf16 k_s[2][64][72];
  __shared__ __attribute__((aligned(16))) bf16 vt_s[2][64][72];
  __shared__ __attribute__((aligned(16))) bf16 p_s[4][16][72];
  __shared__ int  okk_s[768];
  __shared__ float kv0[2][64];

  // stage Q (64 rows x 64 d)
  {
    const uint4* src = (const uint4*)(qkv + (size_t)(c*256 + rg*64 + jj)*3840 + n*64 + seg*16);
    *(uint4*)&q_s[jj][seg*16]   = src[0];
    *(uint4*)&q_s[jj][seg*16+8] = src[1];
  }
  #pragma unroll
  for (int p=0;p<3;p++){
    int j = tid + p*256;
    int kpos = c*256 + j - 256;
    int ok = 0;
    if (kpos >= 0 && kpos < 2048) ok = (amask[kpos] != 0) && (gmask[kpos] == 0);
    okk_s[j] = ok;
  }
  if (tid < 64)       kv0[0][tid]    = b2f(qkv[768  + n*64 + tid]);
  else if (tid < 128) kv0[1][tid-64] = b2f(qkv[1536 + n*64 + (tid-64)]);

  auto loadK = [&](int kt, uint4& a, uint4& b){
    int kpos = c*256 + kt*64 + jj - 256;
    int kq = kpos < 0 ? 0 : (kpos > 2047 ? 2047 : kpos);
    const uint4* ks = (const uint4*)(qkv + (size_t)kq*3840 + 768 + n*64 + seg*16);
    a = ks[0]; b = ks[1];
  };
  auto loadV = [&](int kt, uint4& a, uint4& b){
    int base = c*256 + kt*64 - 256;              // tiles are fully in- or out-of-range
    int sb = (base < 0 || base > 2048-64) ? 0 : base;
    const uint4* vs = (const uint4*)(Vt + (size_t)(n*64 + jj)*2048 + sb + seg*8);
    a = vs[0]; b = vs[4];
  };

  uint4 ka,kb,va,vb;
  loadK(rg,ka,kb); loadV(rg,va,vb);
  *(uint4*)&k_s[0][jj][seg*16]    = ka;
  *(uint4*)&k_s[0][jj][seg*16+8]  = kb;
  *(uint4*)&vt_s[0][jj][seg*8]    = va;
  *(uint4*)&vt_s[0][jj][seg*8+32] = vb;

  float m[4], l[4];
  f32x4 out[4];
  const f32x4 zero = {0.f,0.f,0.f,0.f};
  #pragma unroll
  for (int r=0;r<4;r++){ m[r] = -kNEG; l[r] = 0.f; }
  #pragma unroll
  for (int dt=0;dt<4;dt++) out[dt] = zero;

  const int kt1 = (rg+8 < 11) ? rg+8 : 11;
  int cur = 0;
  for (int kt = rg; kt <= kt1; kt++) {
    const bool pf = (kt < kt1);
    if (pf){ loadK(kt+1,ka,kb); loadV(kt+1,va,vb); }
    __syncthreads();   // buf[cur] writes visible; prefetch loads in flight

    f32x4 s[4];
    #pragma unroll
    for (int ct=0;ct<4;ct++) s[ct] = zero;
    #pragma unroll
    for (int ks=0;ks<2;ks++){
      bf16x8 aq = *reinterpret_cast<const bf16x8*>(&q_s[wave*16 + fr][ks*32 + fk*8]);
      #pragma unroll
      for (int ct=0;ct<4;ct++){
        bf16x8 bk = *reinterpret_cast<const bf16x8*>(&k_s[cur][ct*16 + fr][ks*32 + fk*8]);
        s[ct] = __builtin_amdgcn_mfma_f32_16x16x32_bf16(aq, bk, s[ct], 0,0,0);
      }
    }
    const int qbase = rg*64 + wave*16 + fk*4;
    #pragma unroll
    for (int ct=0;ct<4;ct++){
      int j = kt*64 + ct*16 + fr;
      int okj = okk_s[j];
      #pragma unroll
      for (int r=0;r<4;r++){
        unsigned rel = (unsigned)(j - (qbase + r));
        s[ct][r] = (okj && rel <= 512u) ? s[ct][r] : -kNEG;
      }
    }
    float fac[4], psum[4];
    #pragma unroll
    for (int r=0;r<4;r++){
      float mm = fmaxf(fmaxf(s[0][r], s[1][r]), fmaxf(s[2][r], s[3][r]));
      #pragma unroll
      for (int mk=8; mk>=1; mk>>=1) mm = fmaxf(mm, __shfl_xor(mm, mk));
      float mn = fmaxf(m[r], mm);
      fac[r] = __expf(m[r] - mn);
      m[r] = mn;
      psum[r] = 0.f;
    }
    #pragma unroll
    for (int ct=0;ct<4;ct++){
      #pragma unroll
      for (int r=0;r<4;r++){
        float p = __expf(s[ct][r] - m[r]);
        psum[r] += p;
        p_s[wave][fk*4 + r][ct*16 + fr] = f2b(p);
      }
    }
    #pragma unroll
    for (int r=0;r<4;r++){
      float ts = psum[r];
      #pragma unroll
      for (int mk=8; mk>=1; mk>>=1) ts += __shfl_xor(ts, mk);
      l[r] = l[r]*fac[r] + ts;
    }
    #pragma unroll
    for (int dt=0;dt<4;dt++)
      #pragma unroll
      for (int r=0;r<4;r++) out[dt][r] *= fac[r];
    #pragma unroll
    for (int ks=0;ks<2;ks++){
      bf16x8 ap = *reinterpret_cast<const bf16x8*>(&p_s[wave][fr][ks*32 + fk*8]);
      #pragma unroll
      for (int dt=0;dt<4;dt++){
        bf16x8 bv = *reinterpret_cast<const bf16x8*>(&vt_s[cur][dt*16 + fr][ks*32 + fk*8]);
        out[dt] = __builtin_amdgcn_mfma_f32_16x16x32_bf16(ap, bv, out[dt], 0,0,0);
      }
    }

    if (pf){   // write prefetched tile into buf cur^1 (its old readers passed the barrier)
      *(uint4*)&k_s[cur^1][jj][seg*16]    = ka;
      *(uint4*)&k_s[cur^1][jj][seg*16+8]  = kb;
      *(uint4*)&vt_s[cur^1][jj][seg*8]    = va;
      *(uint4*)&vt_s[cur^1][jj][seg*8+32] = vb;
      cur ^= 1;
    }
  }

  // global column (key/value = band k,v at sequence position 0) + finalize
  const bool okg = (amask[0] != 0);
  #pragma unroll
  for (int r=0;r<4;r++){
    const int row16 = fk*4 + r;
    float sp = 0.f;
    #pragma unroll
    for (int e=0;e<4;e++){
      int d = fr*4 + e;
      sp += b2f(q_s[wave*16 + row16][d]) * kv0[0][d];
    }
    #pragma unroll
    for (int mk=8; mk>=1; mk>>=1) sp += __shfl_xor(sp, mk);
    float sg = okg ? sp : -kNEG;
    float mn = fmaxf(m[r], sg);
    float fc = __expf(m[r]-mn);
    float pg = __expf(sg-mn);
    float lf = l[r]*fc + pg;
    const int srow = c*256 + rg*64 + wave*16 + row16;
    #pragma unroll
    for (int dt=0;dt<4;dt++){
      int d = dt*16 + fr;
      float o = (out[dt][r]*fc + pg*kv0[1][d]) / lf;
      attn[(size_t)srow*768 + n*64 + d] = f2b(o);
    }
  }
}

// ---------------- global-token (row 0) full attention, qg fused ----------------
__global__ __launch_bounds__(256)
void global_attn(const bf16* __restrict__ qkv, const float* __restrict__ h0,
                 const float* __restrict__ Wqg, const float* __restrict__ bqg,
                 const int* __restrict__ amask, bf16* __restrict__ attn)
{
  const int n = blockIdx.x;
  const int tid = threadIdx.x, wave = tid>>6, lane = tid&63;
  __shared__ float sg[2048];
  __shared__ float qh[64];
  __shared__ float red[8];
  __shared__ float part[4][64];

  {
    const int d = tid & 63;
    const int w = tid >> 6;
    const float* wp = Wqg + (size_t)(w*192)*768 + n*64 + d;
    float a = 0.f;
    #pragma unroll 8
    for (int k=0;k<192;k++) a += h0[w*192+k] * wp[(size_t)k*768];
    part[w][d] = a;
  }
  __syncthreads();
  if (tid < 64)
    qh[tid] = (part[0][tid]+part[1][tid]+part[2][tid]+part[3][tid] + bqg[n*64+tid]) * 0.125f;
  __syncthreads();

  float smax = -3.0e38f;
  for (int p=0;p<8;p++){
    int s = p*256 + tid;
    const uint4* kr = (const uint4*)(qkv + (size_t)s*3840 + 2304 + n*64);
    float acc = 0.f;
    #pragma unroll
    for (int d8=0; d8<8; d8++){
      float f[8]; unpack8(kr[d8], f);
      #pragma unroll
      for (int e=0;e<8;e++) acc += f[e]*qh[d8*8+e];
    }
    if (amask[s] == 0) acc = -kNEG;
    sg[s] = acc;
    smax = fmaxf(smax, acc);
  }
  #pragma unroll
  for (int mk=32; mk>=1; mk>>=1) smax = fmaxf(smax, __shfl_xor(smax, mk));
  if (lane==0) red[wave] = smax;
  __syncthreads();
  smax = fmaxf(fmaxf(red[0],red[1]),fmaxf(red[2],red[3]));
  float ssum = 0.f;
  for (int p=0;p<8;p++){
    int s = p*256 + tid;
    float e = __expf(sg[s]-smax);
    sg[s] = e;
    ssum += e;
  }
  #pragma unroll
  for (int mk=32; mk>=1; mk>>=1) ssum += __shfl_xor(ssum, mk);
  if (lane==0) red[4+wave] = ssum;
  __syncthreads();
  float total = red[4]+red[5]+red[6]+red[7];
  __syncthreads();

  float o0=0.f,o1=0.f,o2=0.f,o3=0.f;
  const int base = wave*512;
  for (int s = base; s < base+512; s+=4){
    o0 += sg[s]   * b2f(qkv[(size_t)s*3840     + 3072 + n*64 + lane]);
    o1 += sg[s+1] * b2f(qkv[(size_t)(s+1)*3840 + 3072 + n*64 + lane]);
    o2 += sg[s+2] * b2f(qkv[(size_t)(s+2)*3840 + 3072 + n*64 + lane]);
    o3 += sg[s+3] * b2f(qkv[(size_t)(s+3)*3840 + 3072 + n*64 + lane]);
  }
  part[wave][lane] = (o0+o1)+(o2+o3);
  __syncthreads();
  if (tid < 64) {
    float oo = (part[0][tid]+part[1][tid]+part[2][tid]+part[3][tid]) / total;
    attn[n*64+tid] = f2b(oo);   // sequence row 0
  }
}

// ---------------- head: tanh(h0 @ dw + db) @ ow + ob ----------------
__global__ __launch_bounds__(768)
void head(const float* __restrict__ h0, const float* __restrict__ dw,
          const float* __restrict__ db, const float* __restrict__ ow,
          const float* __restrict__ ob, float* __restrict__ out)
{
  __shared__ float y[768];
  const int tid = threadIdx.x;
  float acc = 0.f;
  #pragma unroll 8
  for (int k=0;k<768;k++) acc += h0[k]*dw[(size_t)k*768 + tid];
  y[tid] = tanhf(acc + db[tid]);
  __syncthreads();
  if (tid < 256) {
    float a = 0.f;
    #pragma unroll 8
    for (int k=0;k<768;k++) a += y[k]*ow[(size_t)k*256 + tid];
    out[tid] = a + ob[tid];
  }
}

// ---------------- host ----------------
extern "C" void kernel_launch(void* const* d_in, const int* in_sizes, int n_in,
                              void* d_out, int out_size, void* d_ws, size_t ws_size,
                              hipStream_t stream)
{
  const int*   ids   = (const int*)d_in[0];
  const int*   amask = (const int*)d_in[1];
  const int*   gmask = (const int*)d_in[2];
  const float* wemb  = (const float*)d_in[3];
  const float* pemb  = (const float*)d_in[4];
  const float* elns  = (const float*)d_in[5];
  const float* elnb  = (const float*)d_in[6];
  const float* Wq    = (const float*)d_in[7];
  const float* bq    = (const float*)d_in[8];
  const float* Wk    = (const float*)d_in[9];
  const float* bk    = (const float*)d_in[10];
  const float* Wv    = (const float*)d_in[11];
  const float* bv    = (const float*)d_in[12];
  const float* Wqg   = (const float*)d_in[13];
  const float* bqg   = (const float*)d_in[14];
  const float* Wkg   = (const float*)d_in[15];
  const float* bkg   = (const float*)d_in[16];
  const float* Wvg   = (const float*)d_in[17];
  const float* bvg   = (const float*)d_in[18];
  const float* Wo    = (const float*)d_in[19];
  const float* bo    = (const float*)d_in[20];
  const float* ln1s  = (const float*)d_in[21];
  const float* ln1b  = (const float*)d_in[22];
  const float* Wf1   = (const float*)d_in[23];
  const float* bf1   = (const float*)d_in[24];
  const float* Wf2   = (const float*)d_in[25];
  const float* bf2   = (const float*)d_in[26];
  const float* ln2s  = (const float*)d_in[27];
  const float* ln2b  = (const float*)d_in[28];
  const float* dw    = (const float*)d_in[29];
  const float* db    = (const float*)d_in[30];
  const float* ow    = (const float*)d_in[31];
  const float* ob    = (const float*)d_in[32];

  char* ws = (char*)d_ws;
  size_t off = 0;
  auto alloc = [&](size_t bytes)->char*{
    char* p = ws + off; off += (bytes + 255) & ~(size_t)255; return p;
  };
  float* h     = (float*)alloc((size_t)2048*768*4);
  bf16*  hb    = (bf16*) alloc((size_t)2048*768*2);
  float* h2    = (float*)alloc((size_t)2048*768*4);
  bf16*  h2b   = (bf16*) alloc((size_t)2048*768*2);
  bf16*  qkv   = (bf16*) alloc((size_t)2048*3840*2);   // reused as f32 split-K partials
  bf16*  att   = (bf16*) alloc((size_t)2048*768*2);
  bf16*  f1    = (bf16*) alloc((size_t)2048*3072*2);
  bf16*  Vtb   = (bf16*) alloc((size_t)768*2048*2);    // V^T per layer [head*64+d][s]
  bf16*  WcatT = (bf16*) alloc((size_t)12*5*768*768*2);
  bf16*  WoT   = (bf16*) alloc((size_t)12*768*768*2);
  bf16*  Wf1T  = (bf16*) alloc((size_t)12*768*3072*2);
  bf16*  Wf2T  = (bf16*) alloc((size_t)12*768*3072*2);
  float* bcat  = (float*)alloc((size_t)12*3840*4);
  float* pf    = (float*)qkv;                          // 2 x 2048*768 f32 fits in qkv
  const size_t MN = (size_t)2048*768;

  prep_all<<<dim3(2031,12),256,0,stream>>>(Wq, Wk, Wv, Wkg, Wvg, Wo, Wf1, Wf2,
                                           bq, bk, bv, bkg, bvg,
                                           WcatT, WoT, Wf1T, Wf2T, bcat);
  embed_ln<<<2048,256,0,stream>>>(ids, wemb, pemb, elns, elnb, h, hb);

  for (int l=0; l<12; l++) {
    const size_t oHH = (size_t)l*768*768;
    const size_t oH  = (size_t)l*768;
    const size_t oF  = (size_t)l*3072;
    const bf16* WcatT_l = WcatT + (size_t)l*5*768*768;
    const bf16* WoT_l   = WoT   + (size_t)l*768*768;
    const bf16* Wf1T_l  = Wf1T  + (size_t)l*768*3072;
    const bf16* Wf2T_l  = Wf2T  + (size_t)l*768*3072;
    const float* bcat_l = bcat  + (size_t)l*3840;

    gemm_bt<0,1,0,1,1><<<dim3(16,30),256,0,stream>>>(hb, WcatT_l, bcat_l, nullptr, qkv,
                                                     Vtb, 2048, 3840, 768);
    band_attn<<<dim3(8,12,4),256,0,stream>>>(qkv, Vtb, amask, gmask, att);
    global_attn<<<12,256,0,stream>>>(qkv, h, Wqg+oHH, bqg+oH, amask, att);
    gemm_bt<1,0,0,2,0><<<dim3(16,6,2),256,0,stream>>>(att, WoT_l, bo+oH, pf, nullptr,
                                                      nullptr, 2048, 768, 768);
    add_ln<<<2048,256,0,stream>>>(h, pf, pf+MN, ln1s+oH, ln1b+oH, h2, h2b);
    gemm_bt<0,1,1,1,0><<<dim3(16,24),256,0,stream>>>(h2b, Wf1T_l, bf1+oF, nullptr, f1,
                                                     nullptr, 2048, 3072, 768);
    gemm_bt<1,0,0,2,0><<<dim3(16,6,2),256,0,stream>>>(f1, Wf2T_l, bf2+oH, pf, nullptr,
                                                      nullptr, 2048, 768, 3072);
    add_ln<<<2048,256,0,stream>>>(h2, pf, pf+MN, ln2s+oH, ln2b+oH, h, hb);
  }

  head<<<1,768,0,stream>>>(h, dw, db, ow, ob, (float*)d_out);
}

// Round 6
// 2729.384 us; speedup vs baseline: 2.1012x; 1.0672x over previous
//
#include <hip/hip_runtime.h>
#include <hip/hip_bf16.h>

typedef __hip_bfloat16 bf16;
using bf16x8 = __attribute__((ext_vector_type(8))) short;
using f32x4  = __attribute__((ext_vector_type(4))) float;

#define kNEG 1.0e9f

__device__ __forceinline__ float b2f(bf16 x){ return __bfloat162float(x); }
__device__ __forceinline__ bf16  f2b(float x){ return __float2bfloat16(x); }

#define GLDS16(gp, lp) __builtin_amdgcn_global_load_lds( \
    (const __attribute__((address_space(1))) void*)(gp), \
    (__attribute__((address_space(3))) void*)(lp), 16, 0, 0)

__device__ __forceinline__ void unpack8(uint4 u, float* f){
  f[0]=__uint_as_float(u.x<<16); f[1]=__uint_as_float(u.x&0xffff0000u);
  f[2]=__uint_as_float(u.y<<16); f[3]=__uint_as_float(u.y&0xffff0000u);
  f[4]=__uint_as_float(u.z<<16); f[5]=__uint_as_float(u.z&0xffff0000u);
  f[6]=__uint_as_float(u.w<<16); f[7]=__uint_as_float(u.w&0xffff0000u);
}

// ---------------- embedding + LN ----------------
__global__ __launch_bounds__(256)
void embed_ln(const int* __restrict__ ids, const float* __restrict__ wemb,
              const float* __restrict__ pemb, const float* __restrict__ lns,
              const float* __restrict__ lnb, float* __restrict__ hout,
              bf16* __restrict__ hbout)
{
  const int row = blockIdx.x;
  const int tid = threadIdx.x;
  const int wave = tid >> 6, lane = tid & 63;
  const int id = ids[row];
  float x[3];
  #pragma unroll
  for (int p=0;p<3;p++){
    int i = tid + p*256;
    x[p] = wemb[(size_t)id*768 + i] + pemb[(size_t)row*768 + i];
  }
  float s1 = x[0]+x[1]+x[2];
  float s2 = x[0]*x[0]+x[1]*x[1]+x[2]*x[2];
  #pragma unroll
  for (int m=32;m>=1;m>>=1){ s1 += __shfl_xor(s1,m); s2 += __shfl_xor(s2,m); }
  __shared__ float red[8];
  if (lane==0){ red[wave]=s1; red[4+wave]=s2; }
  __syncthreads();
  s1 = red[0]+red[1]+red[2]+red[3];
  s2 = red[4]+red[5]+red[6]+red[7];
  float mu = s1*(1.0f/768.0f);
  float var = s2*(1.0f/768.0f) - mu*mu;
  float rs = rsqrtf(var + 1e-5f);
  #pragma unroll
  for (int p=0;p<3;p++){
    int i = tid + p*256;
    float y = (x[p]-mu)*rs*lns[i] + lnb[i];
    hout[(size_t)row*768+i] = y;
    hbout[(size_t)row*768+i] = f2b(y);
  }
}

// ---------------- residual add (two deltas) + LN ----------------
__global__ __launch_bounds__(256)
void add_ln(const float* __restrict__ res, const float* __restrict__ d0,
            const float* __restrict__ d1,
            const float* __restrict__ lns, const float* __restrict__ lnb,
            float* __restrict__ hout, bf16* __restrict__ hbout)
{
  const int row = blockIdx.x;
  const int tid = threadIdx.x;
  const int wave = tid >> 6, lane = tid & 63;
  float x[3];
  #pragma unroll
  for (int p=0;p<3;p++){
    int i = tid + p*256;
    size_t idx = (size_t)row*768+i;
    x[p] = res[idx] + d0[idx] + d1[idx];
  }
  float s1 = x[0]+x[1]+x[2];
  float s2 = x[0]*x[0]+x[1]*x[1]+x[2]*x[2];
  #pragma unroll
  for (int m=32;m>=1;m>>=1){ s1 += __shfl_xor(s1,m); s2 += __shfl_xor(s2,m); }
  __shared__ float red[8];
  if (lane==0){ red[wave]=s1; red[4+wave]=s2; }
  __syncthreads();
  s1 = red[0]+red[1]+red[2]+red[3];
  s2 = red[4]+red[5]+red[6]+red[7];
  float mu = s1*(1.0f/768.0f);
  float var = s2*(1.0f/768.0f) - mu*mu;
  float rs = rsqrtf(var + 1e-5f);
  #pragma unroll
  for (int p=0;p<3;p++){
    int i = tid + p*256;
    float y = (x[p]-mu)*rs*lns[i] + lnb[i];
    hout[(size_t)row*768+i] = y;
    hbout[(size_t)row*768+i] = f2b(y);
  }
}

// ---------------- ALL-layer weight transpose -> TILED layout ----------------
// Tiled layout per matrix: [panel p (N/128)][ktile t (K/32)][128 rows][32 k], 8KB tiles.
// Block = 64k x 256n source tile. grid.x: [0,180) Wq..Wvg, [180,216) Wo,
// [216,360) Wf1, [360,504) Wf2, [504,519) bcat ; grid.y = layer
__global__ __launch_bounds__(256)
void prep_all(const float* __restrict__ Wq, const float* __restrict__ Wk,
              const float* __restrict__ Wv, const float* __restrict__ Wkg,
              const float* __restrict__ Wvg, const float* __restrict__ Wo,
              const float* __restrict__ Wf1, const float* __restrict__ Wf2,
              const float* __restrict__ bq, const float* __restrict__ bk,
              const float* __restrict__ bv, const float* __restrict__ bkg,
              const float* __restrict__ bvg,
              bf16* __restrict__ WcatT, bf16* __restrict__ WoT,
              bf16* __restrict__ Wf1T, bf16* __restrict__ Wf2T,
              float* __restrict__ bcat)
{
  const int b = blockIdx.x;
  const int l = blockIdx.y;
  const int tid = threadIdx.x;
  const size_t oHH = (size_t)l*768*768;
  const size_t oHF = (size_t)l*768*3072;
  const size_t oH  = (size_t)l*768;
  if (b >= 504) {
    int i = (b-504)*256 + tid;   // 0..3839
    int which = i / 768, j = i - which*768;
    float v;
    if      (which==0) v = bq[oH+j] * 0.125f;
    else if (which==1) v = bk[oH+j];
    else if (which==2) v = bv[oH+j];
    else if (which==3) v = bkg[oH+j];
    else               v = bvg[oH+j];
    bcat[(size_t)l*3840 + i] = v;
    return;
  }
  const float* src; bf16* dst; int N, KT, p0, tglob, k0, n0; float scale = 1.0f;
  if (b < 180) {
    int wsel = b/36, tile = b - wsel*36;
    int tk = tile/3, tn = tile - tk*3;
    if      (wsel==0){ src=Wq+oHH;  scale=0.125f; }
    else if (wsel==1){ src=Wk+oHH; }
    else if (wsel==2){ src=Wv+oHH; }
    else if (wsel==3){ src=Wkg+oHH; }
    else             { src=Wvg+oHH; }
    dst = WcatT + (size_t)l*5*768*768;
    N=768; KT=24; k0=tk*64; n0=tn*256; p0 = wsel*6 + tn*2; tglob = tk*2;
  } else if (b < 216) {
    int tile = b-180, tk = tile/3, tn = tile - tk*3;
    src = Wo+oHH; dst = WoT + (size_t)l*768*768;
    N=768; KT=24; k0=tk*64; n0=tn*256; p0 = tn*2; tglob = tk*2;
  } else if (b < 360) {
    int tile = b-216, tk = tile/12, tn = tile - tk*12;
    src = Wf1+oHF; dst = Wf1T + (size_t)l*768*3072;
    N=3072; KT=24; k0=tk*64; n0=tn*256; p0 = tn*2; tglob = tk*2;
  } else {
    int tile = b-360, tk = tile/3, tn = tile - tk*3;
    src = Wf2+oHF; dst = Wf2T + (size_t)l*768*3072;
    N=768; KT=96; k0=tk*64; n0=tn*256; p0 = tn*2; tglob = tk*2;
  }

  __shared__ float t[64][260];
  const int wave = tid>>6, lane = tid&63;
  #pragma unroll
  for (int i=0;i<16;i++){
    int r = i*4 + wave;      // wave reads one full 1KB row per iter
    *(float4*)&t[r][lane*4] = *(const float4*)&src[(size_t)(k0+r)*N + n0 + lane*4];
  }
  __syncthreads();
  const int rr = tid>>1, half = tid&1;
  #pragma unroll
  for (int c=0;c<4;c++){
    const int pp = c>>1, tt = c&1;
    union { uint4 u[2]; bf16 h[16]; } pk;
    #pragma unroll
    for (int j=0;j<16;j++)
      pk.h[j] = f2b(t[tt*32 + half*16 + j][pp*128 + rr] * scale);
    bf16* d = dst + ((size_t)(p0+pp)*KT + tglob + tt)*4096 + rr*32 + half*16;
    *(uint4*)d     = pk.u[0];
    *(uint4*)(d+8) = pk.u[1];
  }
}

// ---------------- MFMA GEMM (2-phase prefetch, dbuf LDS, tiled B) ----------------
// C[M][N] = A[M][K] @ BT(tiled)^T + bias. BT layout: [p][t][128][32] 8KB tiles.
// KSPLIT>1: blockIdx.z picks K-slice, partial -> outf + z*M*N (bias on z==0)
// VT: also scatter V-region cols (1536..2304) transposed into vt[(col-1536)][row]
template<int OUTF, int OUTB, int GELU, int KSPLIT, int VT>
__global__ __launch_bounds__(256)
void gemm_bt(const bf16* __restrict__ A, const bf16* __restrict__ Bt,
             const float* __restrict__ bias,
             float* __restrict__ outf, bf16* __restrict__ outb,
             bf16* __restrict__ vt,
             int M, int N, int K)
{
  __shared__ bf16 As[2][128*32];
  __shared__ bf16 Bs[2][128*32];
  const int tid  = threadIdx.x;
  const int lane = tid & 63;
  const int wave = tid >> 6;
  const int wm = wave >> 1, wn = wave & 1;
  const int bm = blockIdx.x, bn = blockIdx.y, bz = (KSPLIT>1) ? blockIdx.z : 0;
  const int fr = lane & 15;
  const int fk = lane >> 4;
  const int Ks = K / KSPLIT;
  const int nt = Ks / 32;
  const int kbeg = bz * Ks;
  const int KT = K >> 5;

  const int srow = tid >> 2;
  const int scol = (tid & 3) << 3;
  const bf16* pa0 = A  + (size_t)(bm*128 + srow)*K      + kbeg + scol;
  const bf16* pa1 = A  + (size_t)(bm*128 + srow + 64)*K + kbeg + scol;
  const bf16* pB  = Bt + ((size_t)bn*KT + (kbeg>>5))*4096;
  const int l0 = srow*32 + scol;           // == 8*tid (lane-linear)
  const int l1 = l0 + 2048;

  f32x4 acc[4][4];
  const f32x4 zero = {0.f,0.f,0.f,0.f};
  #pragma unroll
  for (int i=0;i<4;i++)
    #pragma unroll
    for (int j=0;j<4;j++) acc[i][j] = zero;

  // prologue: stage tile 0 into buf 0
  GLDS16(pa0, &As[0][l0]);
  GLDS16(pa1, &As[0][l1]);
  GLDS16(pB + tid*8,        &Bs[0][tid*8]);
  GLDS16(pB + 2048 + tid*8, &Bs[0][2048 + tid*8]);
  __syncthreads();

  int cur = 0;
  for (int t = 0; t < nt; ++t) {
    if (t+1 < nt) {
      const int ko = (t+1)*32;
      GLDS16(pa0 + ko, &As[cur^1][l0]);
      GLDS16(pa1 + ko, &As[cur^1][l1]);
      GLDS16(pB + (size_t)(t+1)*4096 + tid*8,        &Bs[cur^1][tid*8]);
      GLDS16(pB + (size_t)(t+1)*4096 + 2048 + tid*8, &Bs[cur^1][2048 + tid*8]);
    }
    bf16x8 af[4], bfr[4];
    #pragma unroll
    for (int m=0;m<4;m++)
      af[m] = *reinterpret_cast<const bf16x8*>(&As[cur][(wm*64 + m*16 + fr)*32 + fk*8]);
    #pragma unroll
    for (int n=0;n<4;n++)
      bfr[n] = *reinterpret_cast<const bf16x8*>(&Bs[cur][(wn*64 + n*16 + fr)*32 + fk*8]);
    #pragma unroll
    for (int m=0;m<4;m++)
      #pragma unroll
      for (int n=0;n<4;n++)
        acc[m][n] = __builtin_amdgcn_mfma_f32_16x16x32_bf16(af[m], bfr[n], acc[m][n], 0,0,0);
    __syncthreads();
    cur ^= 1;
  }

  const int row0 = bm*128 + wm*64 + (lane>>4)*4;
  const int col0 = bn*128 + wn*64 + fr;
  float* outfz = OUTF ? (outf + (size_t)bz*M*N) : nullptr;
  #pragma unroll
  for (int n=0;n<4;n++){
    const int col = col0 + n*16;
    const float bv = (bz==0) ? bias[col] : 0.f;
    #pragma unroll
    for (int m=0;m<4;m++){
      const int r0 = row0 + m*16;
      union { ushort4 u; bf16 h[4]; } pk;
      #pragma unroll
      for (int r=0;r<4;r++){
        float x = acc[m][n][r] + bv;
        if (GELU) x = 0.5f*x*(1.0f + erff(x*0.70710678118f));
        size_t idx = (size_t)(r0+r)*N + col;
        pk.h[r] = f2b(x);
        if (OUTF) outfz[idx] = x;
        if (OUTB) outb[idx] = pk.h[r];
      }
      if (VT) {
        if (col >= 1536 && col < 2304)
          *(ushort4*)&vt[(size_t)(col-1536)*2048 + r0] = pk.u;
      }
    }
  }
}

// ---------------- band + global attention (merged launch) ----------------
// grid (c=8, n=12, z=5). z<4: band for 64-row group z. z==4 && c==0: global-token path.
__global__ __launch_bounds__(256)
void band_attn(const bf16* __restrict__ qkv, const bf16* __restrict__ Vt,
               const float* __restrict__ h0, const float* __restrict__ Wqg,
               const float* __restrict__ bqg,
               const int* __restrict__ amask, const int* __restrict__ gmask,
               bf16* __restrict__ attn)
{
  const int c = blockIdx.x, n = blockIdx.y, rg = blockIdx.z;
  const int tid = threadIdx.x, wave = tid>>6, lane = tid&63;

  if (rg == 4) {
    if (c != 0) return;
    // ---- global-token (row 0) full attention, qg fused ----
    __shared__ float sg[2048];
    __shared__ float qh[64];
    __shared__ float redg[8];
    __shared__ float partg[4][64];
    {
      const int d = tid & 63;
      const int w = tid >> 6;
      const float* wp = Wqg + (size_t)(w*192)*768 + n*64 + d;
      float a = 0.f;
      #pragma unroll 8
      for (int k=0;k<192;k++) a += h0[w*192+k] * wp[(size_t)k*768];
      partg[w][d] = a;
    }
    __syncthreads();
    if (tid < 64)
      qh[tid] = (partg[0][tid]+partg[1][tid]+partg[2][tid]+partg[3][tid] + bqg[n*64+tid]) * 0.125f;
    __syncthreads();

    float smax = -3.0e38f;
    for (int p=0;p<8;p++){
      int s = p*256 + tid;
      const uint4* kr = (const uint4*)(qkv + (size_t)s*3840 + 2304 + n*64);
      float acc = 0.f;
      #pragma unroll
      for (int d8=0; d8<8; d8++){
        float f[8]; unpack8(kr[d8], f);
        #pragma unroll
        for (int e=0;e<8;e++) acc += f[e]*qh[d8*8+e];
      }
      if (amask[s] == 0) acc = -kNEG;
      sg[s] = acc;
      smax = fmaxf(smax, acc);
    }
    #pragma unroll
    for (int mk=32; mk>=1; mk>>=1) smax = fmaxf(smax, __shfl_xor(smax, mk));
    if (lane==0) redg[wave] = smax;
    __syncthreads();
    smax = fmaxf(fmaxf(redg[0],redg[1]),fmaxf(redg[2],redg[3]));
    float ssum = 0.f;
    for (int p=0;p<8;p++){
      int s = p*256 + tid;
      float e = __expf(sg[s]-smax);
      sg[s] = e;
      ssum += e;
    }
    #pragma unroll
    for (int mk=32; mk>=1; mk>>=1) ssum += __shfl_xor(ssum, mk);
    if (lane==0) redg[4+wave] = ssum;
    __syncthreads();
    float total = redg[4]+redg[5]+redg[6]+redg[7];
    __syncthreads();

    float o0=0.f,o1=0.f,o2=0.f,o3=0.f;
    const int base = wave*512;
    for (int s = base; s < base+512; s+=4){
      o0 += sg[s]   * b2f(qkv[(size_t)s*3840     + 3072 + n*64 + lane]);
      o1 += sg[s+1] * b2f(qkv[(size_t)(s+1)*3840 + 3072 + n*64 + lane]);
      o2 += sg[s+2] * b2f(qkv[(size_t)(s+2)*3840 + 3072 + n*64 + lane]);
      o3 += sg[s+3] * b2f(qkv[(size_t)(s+3)*3840 + 3072 + n*64 + lane]);
    }
    partg[wave][lane] = (o0+o1)+(o2+o3);
    __syncthreads();
    if (tid < 64) {
      float oo = (partg[0][tid]+partg[1][tid]+partg[2][tid]+partg[3][tid]) / total;
      attn[n*64+tid] = f2b(oo);
    }
    return;
  }

  // ---- band path ----
  const int fr = lane & 15, fk = lane >> 4;
  const int jj = tid >> 2, seg = tid & 3;

  __shared__ __attribute__((aligned(16))) bf16 q_s[64][72];
  __shared__ __attribute__((aligned(16))) bf16 k_s[2][64][72];
  __shared__ __attribute__((aligned(16))) bf16 vt_s[2][64][72];
  __shared__ __attribute__((aligned(16))) bf16 p_s[4][16][72];
  __shared__ int  okk_s[768];
  __shared__ float kv0[2][64];

  {
    const uint4* src = (const uint4*)(qkv + (size_t)(c*256 + rg*64 + jj)*3840 + n*64 + seg*16);
    *(uint4*)&q_s[jj][seg*16]   = src[0];
    *(uint4*)&q_s[jj][seg*16+8] = src[1];
  }
  #pragma unroll
  for (int p=0;p<3;p++){
    int j = tid + p*256;
    int kpos = c*256 + j - 256;
    int ok = 0;
    if (kpos >= 0 && kpos < 2048) ok = (amask[kpos] != 0) && (gmask[kpos] == 0);
    okk_s[j] = ok;
  }
  if (tid < 64)       kv0[0][tid]    = b2f(qkv[768  + n*64 + tid]);
  else if (tid < 128) kv0[1][tid-64] = b2f(qkv[1536 + n*64 + (tid-64)]);

  auto loadK = [&](int kt, uint4& a, uint4& b){
    int kpos = c*256 + kt*64 + jj - 256;
    int kq = kpos < 0 ? 0 : (kpos > 2047 ? 2047 : kpos);
    const uint4* ks = (const uint4*)(qkv + (size_t)kq*3840 + 768 + n*64 + seg*16);
    a = ks[0]; b = ks[1];
  };
  auto loadV = [&](int kt, uint4& a, uint4& b){
    int base = c*256 + kt*64 - 256;
    int sb = (base < 0 || base > 2048-64) ? 0 : base;
    const uint4* vs = (const uint4*)(Vt + (size_t)(n*64 + jj)*2048 + sb + seg*8);
    a = vs[0]; b = vs[4];
  };

  uint4 ka,kb,va,vb;
  loadK(rg,ka,kb); loadV(rg,va,vb);
  *(uint4*)&k_s[0][jj][seg*16]    = ka;
  *(uint4*)&k_s[0][jj][seg*16+8]  = kb;
  *(uint4*)&vt_s[0][jj][seg*8]    = va;
  *(uint4*)&vt_s[0][jj][seg*8+32] = vb;

  float m[4], l[4];
  f32x4 out[4];
  const f32x4 zero = {0.f,0.f,0.f,0.f};
  #pragma unroll
  for (int r=0;r<4;r++){ m[r] = -kNEG; l[r] = 0.f; }
  #pragma unroll
  for (int dt=0;dt<4;dt++) out[dt] = zero;

  const int kt1 = (rg+8 < 11) ? rg+8 : 11;
  int cur = 0;
  for (int kt = rg; kt <= kt1; kt++) {
    const bool pf = (kt < kt1);
    if (pf){ loadK(kt+1,ka,kb); loadV(kt+1,va,vb); }
    __syncthreads();

    f32x4 s[4];
    #pragma unroll
    for (int ct=0;ct<4;ct++) s[ct] = zero;
    #pragma unroll
    for (int ks=0;ks<2;ks++){
      bf16x8 aq = *reinterpret_cast<const bf16x8*>(&q_s[wave*16 + fr][ks*32 + fk*8]);
      #pragma unroll
      for (int ct=0;ct<4;ct++){
        bf16x8 bk = *reinterpret_cast<const bf16x8*>(&k_s[cur][ct*16 + fr][ks*32 + fk*8]);
        s[ct] = __builtin_amdgcn_mfma_f32_16x16x32_bf16(aq, bk, s[ct], 0,0,0);
      }
    }
    const int qbase = rg*64 + wave*16 + fk*4;
    #pragma unroll
    for (int ct=0;ct<4;ct++){
      int j = kt*64 + ct*16 + fr;
      int okj = okk_s[j];
      #pragma unroll
      for (int r=0;r<4;r++){
        unsigned rel = (unsigned)(j - (qbase + r));
        s[ct][r] = (okj && rel <= 512u) ? s[ct][r] : -kNEG;
      }
    }
    float fac[4], psum[4];
    #pragma unroll
    for (int r=0;r<4;r++){
      float mm = fmaxf(fmaxf(s[0][r], s[1][r]), fmaxf(s[2][r], s[3][r]));
      #pragma unroll
      for (int mk=8; mk>=1; mk>>=1) mm = fmaxf(mm, __shfl_xor(mm, mk));
      float mn = fmaxf(m[r], mm);
      fac[r] = __expf(m[r] - mn);
      m[r] = mn;
      psum[r] = 0.f;
    }
    #pragma unroll
    for (int ct=0;ct<4;ct++){
      #pragma unroll
      for (int r=0;r<4;r++){
        float p = __expf(s[ct][r] - m[r]);
        psum[r] += p;
        p_s[wave][fk*4 + r][ct*16 + fr] = f2b(p);
      }
    }
    #pragma unroll
    for (int r=0;r<4;r++){
      float ts = psum[r];
      #pragma unroll
      for (int mk=8; mk>=1; mk>>=1) ts += __shfl_xor(ts, mk);
      l[r] = l[r]*fac[r] + ts;
    }
    #pragma unroll
    for (int dt=0;dt<4;dt++)
      #pragma unroll
      for (int r=0;r<4;r++) out[dt][r] *= fac[r];
    #pragma unroll
    for (int ks=0;ks<2;ks++){
      bf16x8 ap = *reinterpret_cast<const bf16x8*>(&p_s[wave][fr][ks*32 + fk*8]);
      #pragma unroll
      for (int dt=0;dt<4;dt++){
        bf16x8 bv = *reinterpret_cast<const bf16x8*>(&vt_s[cur][dt*16 + fr][ks*32 + fk*8]);
        out[dt] = __builtin_amdgcn_mfma_f32_16x16x32_bf16(ap, bv, out[dt], 0,0,0);
      }
    }

    if (pf){
      *(uint4*)&k_s[cur^1][jj][seg*16]    = ka;
      *(uint4*)&k_s[cur^1][jj][seg*16+8]  = kb;
      *(uint4*)&vt_s[cur^1][jj][seg*8]    = va;
      *(uint4*)&vt_s[cur^1][jj][seg*8+32] = vb;
      cur ^= 1;
    }
  }

  const bool okg = (amask[0] != 0);
  #pragma unroll
  for (int r=0;r<4;r++){
    const int row16 = fk*4 + r;
    float sp = 0.f;
    #pragma unroll
    for (int e=0;e<4;e++){
      int d = fr*4 + e;
      sp += b2f(q_s[wave*16 + row16][d]) * kv0[0][d];
    }
    #pragma unroll
    for (int mk=8; mk>=1; mk>>=1) sp += __shfl_xor(sp, mk);
    float sg2 = okg ? sp : -kNEG;
    float mn = fmaxf(m[r], sg2);
    float fc = __expf(m[r]-mn);
    float pg = __expf(sg2-mn);
    float lf = l[r]*fc + pg;
    const int srow = c*256 + rg*64 + wave*16 + row16;
    if (srow != 0) {     // row 0 is produced by the global-token path in this same launch
      #pragma unroll
      for (int dt=0;dt<4;dt++){
        int d = dt*16 + fr;
        float o = (out[dt][r]*fc + pg*kv0[1][d]) / lf;
        attn[(size_t)srow*768 + n*64 + d] = f2b(o);
      }
    }
  }
}

// ---------------- head: tanh(h0 @ dw + db) @ ow + ob ----------------
__global__ __launch_bounds__(768)
void head(const float* __restrict__ h0, const float* __restrict__ dw,
          const float* __restrict__ db, const float* __restrict__ ow,
          const float* __restrict__ ob, float* __restrict__ out)
{
  __shared__ float y[768];
  const int tid = threadIdx.x;
  float acc = 0.f;
  #pragma unroll 8
  for (int k=0;k<768;k++) acc += h0[k]*dw[(size_t)k*768 + tid];
  y[tid] = tanhf(acc + db[tid]);
  __syncthreads();
  if (tid < 256) {
    float a = 0.f;
    #pragma unroll 8
    for (int k=0;k<768;k++) a += y[k]*ow[(size_t)k*256 + tid];
    out[tid] = a + ob[tid];
  }
}

// ---------------- host ----------------
extern "C" void kernel_launch(void* const* d_in, const int* in_sizes, int n_in,
                              void* d_out, int out_size, void* d_ws, size_t ws_size,
                              hipStream_t stream)
{
  const int*   ids   = (const int*)d_in[0];
  const int*   amask = (const int*)d_in[1];
  const int*   gmask = (const int*)d_in[2];
  const float* wemb  = (const float*)d_in[3];
  const float* pemb  = (const float*)d_in[4];
  const float* elns  = (const float*)d_in[5];
  const float* elnb  = (const float*)d_in[6];
  const float* Wq    = (const float*)d_in[7];
  const float* bq    = (const float*)d_in[8];
  const float* Wk    = (const float*)d_in[9];
  const float* bk    = (const float*)d_in[10];
  const float* Wv    = (const float*)d_in[11];
  const float* bv    = (const float*)d_in[12];
  const float* Wqg   = (const float*)d_in[13];
  const float* bqg   = (const float*)d_in[14];
  const float* Wkg   = (const float*)d_in[15];
  const float* bkg   = (const float*)d_in[16];
  const float* Wvg   = (const float*)d_in[17];
  const float* bvg   = (const float*)d_in[18];
  const float* Wo    = (const float*)d_in[19];
  const float* bo    = (const float*)d_in[20];
  const float* ln1s  = (const float*)d_in[21];
  const float* ln1b  = (const float*)d_in[22];
  const float* Wf1   = (const float*)d_in[23];
  const float* bf1   = (const float*)d_in[24];
  const float* Wf2   = (const float*)d_in[25];
  const float* bf2   = (const float*)d_in[26];
  const float* ln2s  = (const float*)d_in[27];
  const float* ln2b  = (const float*)d_in[28];
  const float* dw    = (const float*)d_in[29];
  const float* db    = (const float*)d_in[30];
  const float* ow    = (const float*)d_in[31];
  const float* ob    = (const float*)d_in[32];

  char* ws = (char*)d_ws;
  size_t off = 0;
  auto alloc = [&](size_t bytes)->char*{
    char* p = ws + off; off += (bytes + 255) & ~(size_t)255; return p;
  };
  float* h     = (float*)alloc((size_t)2048*768*4);
  bf16*  hb    = (bf16*) alloc((size_t)2048*768*2);
  float* h2    = (float*)alloc((size_t)2048*768*4);
  bf16*  h2b   = (bf16*) alloc((size_t)2048*768*2);
  bf16*  qkv   = (bf16*) alloc((size_t)2048*3840*2);   // reused as f32 split-K partials
  bf16*  att   = (bf16*) alloc((size_t)2048*768*2);
  bf16*  f1    = (bf16*) alloc((size_t)2048*3072*2);
  bf16*  Vtb   = (bf16*) alloc((size_t)768*2048*2);    // V^T per layer [head*64+d][s]
  bf16*  WcatT = (bf16*) alloc((size_t)12*5*768*768*2);
  bf16*  WoT   = (bf16*) alloc((size_t)12*768*768*2);
  bf16*  Wf1T  = (bf16*) alloc((size_t)12*768*3072*2);
  bf16*  Wf2T  = (bf16*) alloc((size_t)12*768*3072*2);
  float* bcat  = (float*)alloc((size_t)12*3840*4);
  float* pf    = (float*)qkv;                          // 2 x 2048*768 f32 fits in qkv
  const size_t MN = (size_t)2048*768;

  prep_all<<<dim3(519,12),256,0,stream>>>(Wq, Wk, Wv, Wkg, Wvg, Wo, Wf1, Wf2,
                                          bq, bk, bv, bkg, bvg,
                                          WcatT, WoT, Wf1T, Wf2T, bcat);
  embed_ln<<<2048,256,0,stream>>>(ids, wemb, pemb, elns, elnb, h, hb);

  for (int l=0; l<12; l++) {
    const size_t oHH = (size_t)l*768*768;
    const size_t oH  = (size_t)l*768;
    const size_t oF  = (size_t)l*3072;
    const bf16* WcatT_l = WcatT + (size_t)l*5*768*768;
    const bf16* WoT_l   = WoT   + (size_t)l*768*768;
    const bf16* Wf1T_l  = Wf1T  + (size_t)l*768*3072;
    const bf16* Wf2T_l  = Wf2T  + (size_t)l*768*3072;
    const float* bcat_l = bcat  + (size_t)l*3840;

    gemm_bt<0,1,0,1,1><<<dim3(16,30),256,0,stream>>>(hb, WcatT_l, bcat_l, nullptr, qkv,
                                                     Vtb, 2048, 3840, 768);
    band_attn<<<dim3(8,12,5),256,0,stream>>>(qkv, Vtb, h, Wqg+oHH, bqg+oH,
                                             amask, gmask, att);
    gemm_bt<1,0,0,2,0><<<dim3(16,6,2),256,0,stream>>>(att, WoT_l, bo+oH, pf, nullptr,
                                                      nullptr, 2048, 768, 768);
    add_ln<<<2048,256,0,stream>>>(h, pf, pf+MN, ln1s+oH, ln1b+oH, h2, h2b);
    gemm_bt<0,1,1,1,0><<<dim3(16,24),256,0,stream>>>(h2b, Wf1T_l, bf1+oF, nullptr, f1,
                                                     nullptr, 2048, 3072, 768);
    gemm_bt<1,0,0,2,0><<<dim3(16,6,2),256,0,stream>>>(f1, Wf2T_l, bf2+oH, pf, nullptr,
                                                      nullptr, 2048, 768, 3072);
    add_ln<<<2048,256,0,stream>>>(h2, pf, pf+MN, ln2s+oH, ln2b+oH, h, hb);
  }

  head<<<1,768,0,stream>>>(h, dw, db, ow, ob, (float*)d_out);
}

// Round 7
// 2652.020 us; speedup vs baseline: 2.1625x; 1.0292x over previous
//
#include <hip/hip_runtime.h>
#include <hip/hip_bf16.h>

typedef __hip_bfloat16 bf16;
using bf16x8 = __attribute__((ext_vector_type(8))) short;
using f32x4  = __attribute__((ext_vector_type(4))) float;

#define kNEG 1.0e9f

__device__ __forceinline__ float b2f(bf16 x){ return __bfloat162float(x); }
__device__ __forceinline__ bf16  f2b(float x){ return __float2bfloat16(x); }

#define GLDS16(gp, lp) __builtin_amdgcn_global_load_lds( \
    (const __attribute__((address_space(1))) void*)(gp), \
    (__attribute__((address_space(3))) void*)(lp), 16, 0, 0)

__device__ __forceinline__ void unpack8(uint4 u, float* f){
  f[0]=__uint_as_float(u.x<<16); f[1]=__uint_as_float(u.x&0xffff0000u);
  f[2]=__uint_as_float(u.y<<16); f[3]=__uint_as_float(u.y&0xffff0000u);
  f[4]=__uint_as_float(u.z<<16); f[5]=__uint_as_float(u.z&0xffff0000u);
  f[6]=__uint_as_float(u.w<<16); f[7]=__uint_as_float(u.w&0xffff0000u);
}

// ---------------- embedding + LN ----------------
__global__ __launch_bounds__(256)
void embed_ln(const int* __restrict__ ids, const float* __restrict__ wemb,
              const float* __restrict__ pemb, const float* __restrict__ lns,
              const float* __restrict__ lnb, float* __restrict__ hout,
              bf16* __restrict__ hbout)
{
  const int row = blockIdx.x;
  const int tid = threadIdx.x;
  const int wave = tid >> 6, lane = tid & 63;
  const int id = ids[row];
  float x[3];
  #pragma unroll
  for (int p=0;p<3;p++){
    int i = tid + p*256;
    x[p] = wemb[(size_t)id*768 + i] + pemb[(size_t)row*768 + i];
  }
  float s1 = x[0]+x[1]+x[2];
  float s2 = x[0]*x[0]+x[1]*x[1]+x[2]*x[2];
  #pragma unroll
  for (int m=32;m>=1;m>>=1){ s1 += __shfl_xor(s1,m); s2 += __shfl_xor(s2,m); }
  __shared__ float red[8];
  if (lane==0){ red[wave]=s1; red[4+wave]=s2; }
  __syncthreads();
  s1 = red[0]+red[1]+red[2]+red[3];
  s2 = red[4]+red[5]+red[6]+red[7];
  float mu = s1*(1.0f/768.0f);
  float var = s2*(1.0f/768.0f) - mu*mu;
  float rs = rsqrtf(var + 1e-5f);
  #pragma unroll
  for (int p=0;p<3;p++){
    int i = tid + p*256;
    float y = (x[p]-mu)*rs*lns[i] + lnb[i];
    hout[(size_t)row*768+i] = y;
    hbout[(size_t)row*768+i] = f2b(y);
  }
}

// ---------------- residual add (two deltas) + LN ----------------
__global__ __launch_bounds__(256)
void add_ln(const float* __restrict__ res, const float* __restrict__ d0,
            const float* __restrict__ d1,
            const float* __restrict__ lns, const float* __restrict__ lnb,
            float* __restrict__ hout, bf16* __restrict__ hbout)
{
  const int row = blockIdx.x;
  const int tid = threadIdx.x;
  const int wave = tid >> 6, lane = tid & 63;
  float x[3];
  #pragma unroll
  for (int p=0;p<3;p++){
    int i = tid + p*256;
    size_t idx = (size_t)row*768+i;
    x[p] = res[idx] + d0[idx] + d1[idx];
  }
  float s1 = x[0]+x[1]+x[2];
  float s2 = x[0]*x[0]+x[1]*x[1]+x[2]*x[2];
  #pragma unroll
  for (int m=32;m>=1;m>>=1){ s1 += __shfl_xor(s1,m); s2 += __shfl_xor(s2,m); }
  __shared__ float red[8];
  if (lane==0){ red[wave]=s1; red[4+wave]=s2; }
  __syncthreads();
  s1 = red[0]+red[1]+red[2]+red[3];
  s2 = red[4]+red[5]+red[6]+red[7];
  float mu = s1*(1.0f/768.0f);
  float var = s2*(1.0f/768.0f) - mu*mu;
  float rs = rsqrtf(var + 1e-5f);
  #pragma unroll
  for (int p=0;p<3;p++){
    int i = tid + p*256;
    float y = (x[p]-mu)*rs*lns[i] + lnb[i];
    hout[(size_t)row*768+i] = y;
    hbout[(size_t)row*768+i] = f2b(y);
  }
}

// ---------------- ALL-layer weight transpose -> TILED layout ----------------
// Tiled layout per matrix: [panel p (N/128)][ktile t (K/32)][128 rows][32 k], 8KB tiles.
// Block = 64k x 256n source tile; LDS held as bf16 (33.8KB) for 4 blocks/CU.
__global__ __launch_bounds__(256)
void prep_all(const float* __restrict__ Wq, const float* __restrict__ Wk,
              const float* __restrict__ Wv, const float* __restrict__ Wkg,
              const float* __restrict__ Wvg, const float* __restrict__ Wo,
              const float* __restrict__ Wf1, const float* __restrict__ Wf2,
              const float* __restrict__ bq, const float* __restrict__ bk,
              const float* __restrict__ bv, const float* __restrict__ bkg,
              const float* __restrict__ bvg,
              bf16* __restrict__ WcatT, bf16* __restrict__ WoT,
              bf16* __restrict__ Wf1T, bf16* __restrict__ Wf2T,
              float* __restrict__ bcat)
{
  const int b = blockIdx.x;
  const int l = blockIdx.y;
  const int tid = threadIdx.x;
  const size_t oHH = (size_t)l*768*768;
  const size_t oHF = (size_t)l*768*3072;
  const size_t oH  = (size_t)l*768;
  if (b >= 504) {
    int i = (b-504)*256 + tid;   // 0..3839
    int which = i / 768, j = i - which*768;
    float v;
    if      (which==0) v = bq[oH+j] * 0.125f;
    else if (which==1) v = bk[oH+j];
    else if (which==2) v = bv[oH+j];
    else if (which==3) v = bkg[oH+j];
    else               v = bvg[oH+j];
    bcat[(size_t)l*3840 + i] = v;
    return;
  }
  const float* src; bf16* dst; int N, KT, p0, tglob, k0, n0; float scale = 1.0f;
  if (b < 180) {
    int wsel = b/36, tile = b - wsel*36;
    int tk = tile/3, tn = tile - tk*3;
    if      (wsel==0){ src=Wq+oHH;  scale=0.125f; }
    else if (wsel==1){ src=Wk+oHH; }
    else if (wsel==2){ src=Wv+oHH; }
    else if (wsel==3){ src=Wkg+oHH; }
    else             { src=Wvg+oHH; }
    dst = WcatT + (size_t)l*5*768*768;
    N=768; KT=24; k0=tk*64; n0=tn*256; p0 = wsel*6 + tn*2; tglob = tk*2;
  } else if (b < 216) {
    int tile = b-180, tk = tile/3, tn = tile - tk*3;
    src = Wo+oHH; dst = WoT + (size_t)l*768*768;
    N=768; KT=24; k0=tk*64; n0=tn*256; p0 = tn*2; tglob = tk*2;
  } else if (b < 360) {
    int tile = b-216, tk = tile/12, tn = tile - tk*12;
    src = Wf1+oHF; dst = Wf1T + (size_t)l*768*3072;
    N=3072; KT=24; k0=tk*64; n0=tn*256; p0 = tn*2; tglob = tk*2;
  } else {
    int tile = b-360, tk = tile/3, tn = tile - tk*3;
    src = Wf2+oHF; dst = Wf2T + (size_t)l*768*3072;
    N=768; KT=96; k0=tk*64; n0=tn*256; p0 = tn*2; tglob = tk*2;
  }

  __shared__ bf16 t[64][264];
  const int wave = tid>>6, lane = tid&63;
  #pragma unroll
  for (int i=0;i<16;i++){
    int r = i*4 + wave;      // wave reads one full 1KB row per iter
    float4 v = *(const float4*)&src[(size_t)(k0+r)*N + n0 + lane*4];
    union { ushort4 u; bf16 h[4]; } pk;
    pk.h[0]=f2b(v.x*scale); pk.h[1]=f2b(v.y*scale);
    pk.h[2]=f2b(v.z*scale); pk.h[3]=f2b(v.w*scale);
    *(ushort4*)&t[r][lane*4] = pk.u;
  }
  __syncthreads();
  const int rr = tid>>1, half = tid&1;
  #pragma unroll
  for (int c=0;c<4;c++){
    const int pp = c>>1, tt = c&1;
    union { uint4 u[2]; bf16 h[16]; } pk;
    #pragma unroll
    for (int j=0;j<16;j++)
      pk.h[j] = t[tt*32 + half*16 + j][pp*128 + rr];
    bf16* d = dst + ((size_t)(p0+pp)*KT + tglob + tt)*4096 + rr*32 + half*16;
    *(uint4*)d     = pk.u[0];
    *(uint4*)(d+8) = pk.u[1];
  }
}

// ---------------- MFMA GEMM (depth-2 counted-vmcnt pipeline, dbuf LDS, tiled B) ----------------
// C[M][N] = A[M][K] @ BT(tiled)^T + bias. BT layout: [p][t][128][32] 8KB tiles.
// KSPLIT>1: blockIdx.z picks K-slice, partial -> outf + z*M*N (bias on z==0)
// VT: also scatter V-region cols (1536..2304) transposed into vt[(col-1536)][row]
template<int OUTF, int OUTB, int GELU, int KSPLIT, int VT>
__global__ __launch_bounds__(256)
void gemm_bt(const bf16* __restrict__ A, const bf16* __restrict__ Bt,
             const float* __restrict__ bias,
             float* __restrict__ outf, bf16* __restrict__ outb,
             bf16* __restrict__ vt,
             int M, int N, int K)
{
  __shared__ bf16 As[2][128*32];
  __shared__ bf16 Bs[2][128*32];
  const int tid  = threadIdx.x;
  const int lane = tid & 63;
  const int wave = tid >> 6;
  const int wm = wave >> 1, wn = wave & 1;
  // XCD-chunked block swizzle (nwg % 8 == 0 for all our launches)
  const int gx = gridDim.x, nwg = gx*gridDim.y;
  const int w  = blockIdx.y*gx + blockIdx.x;
  const int cpx = nwg >> 3;
  const int sw = (w & 7)*cpx + (w >> 3);
  const int bm = sw % gx, bn = sw / gx;
  const int bz = (KSPLIT>1) ? blockIdx.z : 0;
  const int fr = lane & 15;
  const int fk = lane >> 4;
  const int Ks = K / KSPLIT;
  const int nt = Ks / 32;
  const int kbeg = bz * Ks;
  const int KT = K >> 5;

  const int srow = tid >> 2;
  const int scol = (tid & 3) << 3;
  const bf16* pa0 = A  + (size_t)(bm*128 + srow)*K      + kbeg + scol;
  const bf16* pa1 = A  + (size_t)(bm*128 + srow + 64)*K + kbeg + scol;
  const bf16* pB  = Bt + ((size_t)bn*KT + (kbeg>>5))*4096;
  const int l0 = srow*32 + scol;           // == 8*tid (lane-linear)
  const int l1 = l0 + 2048;

  f32x4 acc[4][4];
  const f32x4 zero = {0.f,0.f,0.f,0.f};
  #pragma unroll
  for (int i=0;i<4;i++)
    #pragma unroll
    for (int j=0;j<4;j++) acc[i][j] = zero;

  // prologue: stage tiles 0 and 1 (nt >= 12 always)
  GLDS16(pa0,      &As[0][l0]);
  GLDS16(pa1,      &As[0][l1]);
  GLDS16(pB + tid*8,        &Bs[0][tid*8]);
  GLDS16(pB + 2048 + tid*8, &Bs[0][2048 + tid*8]);
  GLDS16(pa0 + 32, &As[1][l0]);
  GLDS16(pa1 + 32, &As[1][l1]);
  GLDS16(pB + 4096 + tid*8,        &Bs[1][tid*8]);
  GLDS16(pB + 4096 + 2048 + tid*8, &Bs[1][2048 + tid*8]);

  for (int t = 0; t < nt; ++t) {
    const int cur = t & 1;
    if (t < nt-1) asm volatile("s_waitcnt vmcnt(4)" ::: "memory");
    else          asm volatile("s_waitcnt vmcnt(0)" ::: "memory");
    __builtin_amdgcn_s_barrier();
    __builtin_amdgcn_sched_barrier(0);

    bf16x8 af[4], bfr[4];
    #pragma unroll
    for (int m=0;m<4;m++)
      af[m] = *reinterpret_cast<const bf16x8*>(&As[cur][(wm*64 + m*16 + fr)*32 + fk*8]);
    #pragma unroll
    for (int n=0;n<4;n++)
      bfr[n] = *reinterpret_cast<const bf16x8*>(&Bs[cur][(wn*64 + n*16 + fr)*32 + fk*8]);
    #pragma unroll
    for (int m=0;m<4;m++)
      #pragma unroll
      for (int n=0;n<4;n++)
        acc[m][n] = __builtin_amdgcn_mfma_f32_16x16x32_bf16(af[m], bfr[n], acc[m][n], 0,0,0);

    __builtin_amdgcn_s_barrier();
    __builtin_amdgcn_sched_barrier(0);
    if (t+2 < nt) {     // stage tile t+2 into buf[cur] (its readers passed the barrier)
      const size_t ko = (size_t)(t+2)*32;
      GLDS16(pa0 + ko, &As[cur][l0]);
      GLDS16(pa1 + ko, &As[cur][l1]);
      GLDS16(pB + (size_t)(t+2)*4096 + tid*8,        &Bs[cur][tid*8]);
      GLDS16(pB + (size_t)(t+2)*4096 + 2048 + tid*8, &Bs[cur][2048 + tid*8]);
    }
  }

  const int row0 = bm*128 + wm*64 + (lane>>4)*4;
  const int col0 = bn*128 + wn*64 + fr;
  float* outfz = OUTF ? (outf + (size_t)bz*M*N) : nullptr;
  #pragma unroll
  for (int n=0;n<4;n++){
    const int col = col0 + n*16;
    const float bv = (bz==0) ? bias[col] : 0.f;
    #pragma unroll
    for (int m=0;m<4;m++){
      const int r0 = row0 + m*16;
      union { ushort4 u; bf16 h[4]; } pk;
      #pragma unroll
      for (int r=0;r<4;r++){
        float x = acc[m][n][r] + bv;
        if (GELU) x = 0.5f*x*(1.0f + erff(x*0.70710678118f));
        size_t idx = (size_t)(r0+r)*N + col;
        pk.h[r] = f2b(x);
        if (OUTF) outfz[idx] = x;
        if (OUTB) outb[idx] = pk.h[r];
      }
      if (VT) {
        if (col >= 1536 && col < 2304)
          *(ushort4*)&vt[(size_t)(col-1536)*2048 + r0] = pk.u;
      }
    }
  }
}

// ---------------- band + global attention (merged launch) ----------------
// grid (c=8, n=12, z=5). z<4: band for 64-row group z. z==4 && c==0: global-token path.
__global__ __launch_bounds__(256)
void band_attn(const bf16* __restrict__ qkv, const bf16* __restrict__ Vt,
               const float* __restrict__ h0, const float* __restrict__ Wqg,
               const float* __restrict__ bqg,
               const int* __restrict__ amask, const int* __restrict__ gmask,
               bf16* __restrict__ attn)
{
  const int c = blockIdx.x, n = blockIdx.y, rg = blockIdx.z;
  const int tid = threadIdx.x, wave = tid>>6, lane = tid&63;

  if (rg == 4) {
    if (c != 0) return;
    __shared__ float sg[2048];
    __shared__ float qh[64];
    __shared__ float redg[8];
    __shared__ float partg[4][64];
    {
      const int d = tid & 63;
      const int w = tid >> 6;
      const float* wp = Wqg + (size_t)(w*192)*768 + n*64 + d;
      float a = 0.f;
      #pragma unroll 8
      for (int k=0;k<192;k++) a += h0[w*192+k] * wp[(size_t)k*768];
      partg[w][d] = a;
    }
    __syncthreads();
    if (tid < 64)
      qh[tid] = (partg[0][tid]+partg[1][tid]+partg[2][tid]+partg[3][tid] + bqg[n*64+tid]) * 0.125f;
    __syncthreads();

    float smax = -3.0e38f;
    for (int p=0;p<8;p++){
      int s = p*256 + tid;
      const uint4* kr = (const uint4*)(qkv + (size_t)s*3840 + 2304 + n*64);
      float acc = 0.f;
      #pragma unroll
      for (int d8=0; d8<8; d8++){
        float f[8]; unpack8(kr[d8], f);
        #pragma unroll
        for (int e=0;e<8;e++) acc += f[e]*qh[d8*8+e];
      }
      if (amask[s] == 0) acc = -kNEG;
      sg[s] = acc;
      smax = fmaxf(smax, acc);
    }
    #pragma unroll
    for (int mk=32; mk>=1; mk>>=1) smax = fmaxf(smax, __shfl_xor(smax, mk));
    if (lane==0) redg[wave] = smax;
    __syncthreads();
    smax = fmaxf(fmaxf(redg[0],redg[1]),fmaxf(redg[2],redg[3]));
    float ssum = 0.f;
    for (int p=0;p<8;p++){
      int s = p*256 + tid;
      float e = __expf(sg[s]-smax);
      sg[s] = e;
      ssum += e;
    }
    #pragma unroll
    for (int mk=32; mk>=1; mk>>=1) ssum += __shfl_xor(ssum, mk);
    if (lane==0) redg[4+wave] = ssum;
    __syncthreads();
    float total = redg[4]+redg[5]+redg[6]+redg[7];
    __syncthreads();

    float o0=0.f,o1=0.f,o2=0.f,o3=0.f;
    const int base = wave*512;
    for (int s = base; s < base+512; s+=4){
      o0 += sg[s]   * b2f(qkv[(size_t)s*3840     + 3072 + n*64 + lane]);
      o1 += sg[s+1] * b2f(qkv[(size_t)(s+1)*3840 + 3072 + n*64 + lane]);
      o2 += sg[s+2] * b2f(qkv[(size_t)(s+2)*3840 + 3072 + n*64 + lane]);
      o3 += sg[s+3] * b2f(qkv[(size_t)(s+3)*3840 + 3072 + n*64 + lane]);
    }
    partg[wave][lane] = (o0+o1)+(o2+o3);
    __syncthreads();
    if (tid < 64) {
      float oo = (partg[0][tid]+partg[1][tid]+partg[2][tid]+partg[3][tid]) / total;
      attn[n*64+tid] = f2b(oo);
    }
    return;
  }

  // ---- band path ----
  const int fr = lane & 15, fk = lane >> 4;
  const int jj = tid >> 2, seg = tid & 3;

  __shared__ __attribute__((aligned(16))) bf16 q_s[64][72];
  __shared__ __attribute__((aligned(16))) bf16 k_s[2][64][72];
  __shared__ __attribute__((aligned(16))) bf16 vt_s[2][64][72];
  __shared__ __attribute__((aligned(16))) bf16 p_s[4][16][72];
  __shared__ int  okk_s[768];
  __shared__ float kv0[2][64];

  {
    const uint4* src = (const uint4*)(qkv + (size_t)(c*256 + rg*64 + jj)*3840 + n*64 + seg*16);
    *(uint4*)&q_s[jj][seg*16]   = src[0];
    *(uint4*)&q_s[jj][seg*16+8] = src[1];
  }
  #pragma unroll
  for (int p=0;p<3;p++){
    int j = tid + p*256;
    int kpos = c*256 + j - 256;
    int ok = 0;
    if (kpos >= 0 && kpos < 2048) ok = (amask[kpos] != 0) && (gmask[kpos] == 0);
    okk_s[j] = ok;
  }
  if (tid < 64)       kv0[0][tid]    = b2f(qkv[768  + n*64 + tid]);
  else if (tid < 128) kv0[1][tid-64] = b2f(qkv[1536 + n*64 + (tid-64)]);

  auto loadK = [&](int kt, uint4& a, uint4& b){
    int kpos = c*256 + kt*64 + jj - 256;
    int kq = kpos < 0 ? 0 : (kpos > 2047 ? 2047 : kpos);
    const uint4* ks = (const uint4*)(qkv + (size_t)kq*3840 + 768 + n*64 + seg*16);
    a = ks[0]; b = ks[1];
  };
  auto loadV = [&](int kt, uint4& a, uint4& b){
    int base = c*256 + kt*64 - 256;
    int sb = (base < 0 || base > 2048-64) ? 0 : base;
    const uint4* vs = (const uint4*)(Vt + (size_t)(n*64 + jj)*2048 + sb + seg*8);
    a = vs[0]; b = vs[4];
  };

  uint4 ka,kb,va,vb;
  loadK(rg,ka,kb); loadV(rg,va,vb);
  *(uint4*)&k_s[0][jj][seg*16]    = ka;
  *(uint4*)&k_s[0][jj][seg*16+8]  = kb;
  *(uint4*)&vt_s[0][jj][seg*8]    = va;
  *(uint4*)&vt_s[0][jj][seg*8+32] = vb;

  float m[4], l[4];
  f32x4 out[4];
  const f32x4 zero = {0.f,0.f,0.f,0.f};
  #pragma unroll
  for (int r=0;r<4;r++){ m[r] = -kNEG; l[r] = 0.f; }
  #pragma unroll
  for (int dt=0;dt<4;dt++) out[dt] = zero;

  const int kt1 = (rg+8 < 11) ? rg+8 : 11;
  int cur = 0;
  for (int kt = rg; kt <= kt1; kt++) {
    const bool pf = (kt < kt1);
    if (pf){ loadK(kt+1,ka,kb); loadV(kt+1,va,vb); }
    __syncthreads();

    f32x4 s[4];
    #pragma unroll
    for (int ct=0;ct<4;ct++) s[ct] = zero;
    #pragma unroll
    for (int ks=0;ks<2;ks++){
      bf16x8 aq = *reinterpret_cast<const bf16x8*>(&q_s[wave*16 + fr][ks*32 + fk*8]);
      #pragma unroll
      for (int ct=0;ct<4;ct++){
        bf16x8 bk = *reinterpret_cast<const bf16x8*>(&k_s[cur][ct*16 + fr][ks*32 + fk*8]);
        s[ct] = __builtin_amdgcn_mfma_f32_16x16x32_bf16(aq, bk, s[ct], 0,0,0);
      }
    }
    const int qbase = rg*64 + wave*16 + fk*4;
    #pragma unroll
    for (int ct=0;ct<4;ct++){
      int j = kt*64 + ct*16 + fr;
      int okj = okk_s[j];
      #pragma unroll
      for (int r=0;r<4;r++){
        unsigned rel = (unsigned)(j - (qbase + r));
        s[ct][r] = (okj && rel <= 512u) ? s[ct][r] : -kNEG;
      }
    }
    float fac[4], psum[4];
    #pragma unroll
    for (int r=0;r<4;r++){
      float mm = fmaxf(fmaxf(s[0][r], s[1][r]), fmaxf(s[2][r], s[3][r]));
      #pragma unroll
      for (int mk=8; mk>=1; mk>>=1) mm = fmaxf(mm, __shfl_xor(mm, mk));
      float mn = fmaxf(m[r], mm);
      fac[r] = __expf(m[r] - mn);
      m[r] = mn;
      psum[r] = 0.f;
    }
    #pragma unroll
    for (int ct=0;ct<4;ct++){
      #pragma unroll
      for (int r=0;r<4;r++){
        float p = __expf(s[ct][r] - m[r]);
        psum[r] += p;
        p_s[wave][fk*4 + r][ct*16 + fr] = f2b(p);
      }
    }
    #pragma unroll
    for (int r=0;r<4;r++){
      float ts = psum[r];
      #pragma unroll
      for (int mk=8; mk>=1; mk>>=1) ts += __shfl_xor(ts, mk);
      l[r] = l[r]*fac[r] + ts;
    }
    #pragma unroll
    for (int dt=0;dt<4;dt++)
      #pragma unroll
      for (int r=0;r<4;r++) out[dt][r] *= fac[r];
    #pragma unroll
    for (int ks=0;ks<2;ks++){
      bf16x8 ap = *reinterpret_cast<const bf16x8*>(&p_s[wave][fr][ks*32 + fk*8]);
      #pragma unroll
      for (int dt=0;dt<4;dt++){
        bf16x8 bv = *reinterpret_cast<const bf16x8*>(&vt_s[cur][dt*16 + fr][ks*32 + fk*8]);
        out[dt] = __builtin_amdgcn_mfma_f32_16x16x32_bf16(ap, bv, out[dt], 0,0,0);
      }
    }

    if (pf){
      *(uint4*)&k_s[cur^1][jj][seg*16]    = ka;
      *(uint4*)&k_s[cur^1][jj][seg*16+8]  = kb;
      *(uint4*)&vt_s[cur^1][jj][seg*8]    = va;
      *(uint4*)&vt_s[cur^1][jj][seg*8+32] = vb;
      cur ^= 1;
    }
  }

  const bool okg = (amask[0] != 0);
  #pragma unroll
  for (int r=0;r<4;r++){
    const int row16 = fk*4 + r;
    float sp = 0.f;
    #pragma unroll
    for (int e=0;e<4;e++){
      int d = fr*4 + e;
      sp += b2f(q_s[wave*16 + row16][d]) * kv0[0][d];
    }
    #pragma unroll
    for (int mk=8; mk>=1; mk>>=1) sp += __shfl_xor(sp, mk);
    float sg2 = okg ? sp : -kNEG;
    float mn = fmaxf(m[r], sg2);
    float fc = __expf(m[r]-mn);
    float pg = __expf(sg2-mn);
    float lf = l[r]*fc + pg;
    const int srow = c*256 + rg*64 + wave*16 + row16;
    if (srow != 0) {
      #pragma unroll
      for (int dt=0;dt<4;dt++){
        int d = dt*16 + fr;
        float o = (out[dt][r]*fc + pg*kv0[1][d]) / lf;
        attn[(size_t)srow*768 + n*64 + d] = f2b(o);
      }
    }
  }
}

// ---------------- head: tanh(h0 @ dw + db) @ ow + ob ----------------
__global__ __launch_bounds__(768)
void head(const float* __restrict__ h0, const float* __restrict__ dw,
          const float* __restrict__ db, const float* __restrict__ ow,
          const float* __restrict__ ob, float* __restrict__ out)
{
  __shared__ float y[768];
  const int tid = threadIdx.x;
  float acc = 0.f;
  #pragma unroll 8
  for (int k=0;k<768;k++) acc += h0[k]*dw[(size_t)k*768 + tid];
  y[tid] = tanhf(acc + db[tid]);
  __syncthreads();
  if (tid < 256) {
    float a = 0.f;
    #pragma unroll 8
    for (int k=0;k<768;k++) a += y[k]*ow[(size_t)k*256 + tid];
    out[tid] = a + ob[tid];
  }
}

// ---------------- host ----------------
extern "C" void kernel_launch(void* const* d_in, const int* in_sizes, int n_in,
                              void* d_out, int out_size, void* d_ws, size_t ws_size,
                              hipStream_t stream)
{
  const int*   ids   = (const int*)d_in[0];
  const int*   amask = (const int*)d_in[1];
  const int*   gmask = (const int*)d_in[2];
  const float* wemb  = (const float*)d_in[3];
  const float* pemb  = (const float*)d_in[4];
  const float* elns  = (const float*)d_in[5];
  const float* elnb  = (const float*)d_in[6];
  const float* Wq    = (const float*)d_in[7];
  const float* bq    = (const float*)d_in[8];
  const float* Wk    = (const float*)d_in[9];
  const float* bk    = (const float*)d_in[10];
  const float* Wv    = (const float*)d_in[11];
  const float* bv    = (const float*)d_in[12];
  const float* Wqg   = (const float*)d_in[13];
  const float* bqg   = (const float*)d_in[14];
  const float* Wkg   = (const float*)d_in[15];
  const float* bkg   = (const float*)d_in[16];
  const float* Wvg   = (const float*)d_in[17];
  const float* bvg   = (const float*)d_in[18];
  const float* Wo    = (const float*)d_in[19];
  const float* bo    = (const float*)d_in[20];
  const float* ln1s  = (const float*)d_in[21];
  const float* ln1b  = (const float*)d_in[22];
  const float* Wf1   = (const float*)d_in[23];
  const float* bf1   = (const float*)d_in[24];
  const float* Wf2   = (const float*)d_in[25];
  const float* bf2   = (const float*)d_in[26];
  const float* ln2s  = (const float*)d_in[27];
  const float* ln2b  = (const float*)d_in[28];
  const float* dw    = (const float*)d_in[29];
  const float* db    = (const float*)d_in[30];
  const float* ow    = (const float*)d_in[31];
  const float* ob    = (const float*)d_in[32];

  char* ws = (char*)d_ws;
  size_t off = 0;
  auto alloc = [&](size_t bytes)->char*{
    char* p = ws + off; off += (bytes + 255) & ~(size_t)255; return p;
  };
  float* h     = (float*)alloc((size_t)2048*768*4);
  bf16*  hb    = (bf16*) alloc((size_t)2048*768*2);
  float* h2    = (float*)alloc((size_t)2048*768*4);
  bf16*  h2b   = (bf16*) alloc((size_t)2048*768*2);
  bf16*  qkv   = (bf16*) alloc((size_t)2048*3840*2);   // reused as f32 split-K partials
  bf16*  att   = (bf16*) alloc((size_t)2048*768*2);
  bf16*  f1    = (bf16*) alloc((size_t)2048*3072*2);
  bf16*  Vtb   = (bf16*) alloc((size_t)768*2048*2);    // V^T per layer [head*64+d][s]
  bf16*  WcatT = (bf16*) alloc((size_t)12*5*768*768*2);
  bf16*  WoT   = (bf16*) alloc((size_t)12*768*768*2);
  bf16*  Wf1T  = (bf16*) alloc((size_t)12*768*3072*2);
  bf16*  Wf2T  = (bf16*) alloc((size_t)12*768*3072*2);
  float* bcat  = (float*)alloc((size_t)12*3840*4);
  float* pf    = (float*)qkv;                          // 2 x 2048*768 f32 fits in qkv
  const size_t MN = (size_t)2048*768;

  prep_all<<<dim3(519,12),256,0,stream>>>(Wq, Wk, Wv, Wkg, Wvg, Wo, Wf1, Wf2,
                                          bq, bk, bv, bkg, bvg,
                                          WcatT, WoT, Wf1T, Wf2T, bcat);
  embed_ln<<<2048,256,0,stream>>>(ids, wemb, pemb, elns, elnb, h, hb);

  for (int l=0; l<12; l++) {
    const size_t oHH = (size_t)l*768*768;
    const size_t oH  = (size_t)l*768;
    const size_t oF  = (size_t)l*3072;
    const bf16* WcatT_l = WcatT + (size_t)l*5*768*768;
    const bf16* WoT_l   = WoT   + (size_t)l*768*768;
    const bf16* Wf1T_l  = Wf1T  + (size_t)l*768*3072;
    const bf16* Wf2T_l  = Wf2T  + (size_t)l*768*3072;
    const float* bcat_l = bcat  + (size_t)l*3840;

    gemm_bt<0,1,0,1,1><<<dim3(16,30),256,0,stream>>>(hb, WcatT_l, bcat_l, nullptr, qkv,
                                                     Vtb, 2048, 3840, 768);
    band_attn<<<dim3(8,12,5),256,0,stream>>>(qkv, Vtb, h, Wqg+oHH, bqg+oH,
                                             amask, gmask, att);
    gemm_bt<1,0,0,2,0><<<dim3(16,6,2),256,0,stream>>>(att, WoT_l, bo+oH, pf, nullptr,
                                                      nullptr, 2048, 768, 768);
    add_ln<<<2048,256,0,stream>>>(h, pf, pf+MN, ln1s+oH, ln1b+oH, h2, h2b);
    gemm_bt<0,1,1,1,0><<<dim3(16,24),256,0,stream>>>(h2b, Wf1T_l, bf1+oF, nullptr, f1,
                                                     nullptr, 2048, 3072, 768);
    gemm_bt<1,0,0,2,0><<<dim3(16,6,2),256,0,stream>>>(f1, Wf2T_l, bf2+oH, pf, nullptr,
                                                      nullptr, 2048, 768, 3072);
    add_ln<<<2048,256,0,stream>>>(h2, pf, pf+MN, ln2s+oH, ln2b+oH, h, hb);
  }

  head<<<1,768,0,stream>>>(h, dw, db, ow, ob, (float*)d_out);
}

// Round 8
// 2373.876 us; speedup vs baseline: 2.4159x; 1.1172x over previous
//
#include <hip/hip_runtime.h>
#include <hip/hip_bf16.h>

typedef __hip_bfloat16 bf16;
using bf16x8 = __attribute__((ext_vector_type(8))) short;
using f32x4  = __attribute__((ext_vector_type(4))) float;

#define kNEG 1.0e9f

__device__ __forceinline__ float b2f(bf16 x){ return __bfloat162float(x); }
__device__ __forceinline__ bf16  f2b(float x){ return __float2bfloat16(x); }

#define GLDS16(gp, lp) __builtin_amdgcn_global_load_lds( \
    (const __attribute__((address_space(1))) void*)(gp), \
    (__attribute__((address_space(3))) void*)(lp), 16, 0, 0)

__device__ __forceinline__ void unpack8(uint4 u, float* f){
  f[0]=__uint_as_float(u.x<<16); f[1]=__uint_as_float(u.x&0xffff0000u);
  f[2]=__uint_as_float(u.y<<16); f[3]=__uint_as_float(u.y&0xffff0000u);
  f[4]=__uint_as_float(u.z<<16); f[5]=__uint_as_float(u.z&0xffff0000u);
  f[6]=__uint_as_float(u.w<<16); f[7]=__uint_as_float(u.w&0xffff0000u);
}

// ---------------- embedding + LN ----------------
__global__ __launch_bounds__(256)
void embed_ln(const int* __restrict__ ids, const float* __restrict__ wemb,
              const float* __restrict__ pemb, const float* __restrict__ lns,
              const float* __restrict__ lnb, float* __restrict__ hout,
              bf16* __restrict__ hbout)
{
  const int row = blockIdx.x;
  const int tid = threadIdx.x;
  const int wave = tid >> 6, lane = tid & 63;
  const int id = ids[row];
  float x[3];
  #pragma unroll
  for (int p=0;p<3;p++){
    int i = tid + p*256;
    x[p] = wemb[(size_t)id*768 + i] + pemb[(size_t)row*768 + i];
  }
  float s1 = x[0]+x[1]+x[2];
  float s2 = x[0]*x[0]+x[1]*x[1]+x[2]*x[2];
  #pragma unroll
  for (int m=32;m>=1;m>>=1){ s1 += __shfl_xor(s1,m); s2 += __shfl_xor(s2,m); }
  __shared__ float red[8];
  if (lane==0){ red[wave]=s1; red[4+wave]=s2; }
  __syncthreads();
  s1 = red[0]+red[1]+red[2]+red[3];
  s2 = red[4]+red[5]+red[6]+red[7];
  float mu = s1*(1.0f/768.0f);
  float var = s2*(1.0f/768.0f) - mu*mu;
  float rs = rsqrtf(var + 1e-5f);
  #pragma unroll
  for (int p=0;p<3;p++){
    int i = tid + p*256;
    float y = (x[p]-mu)*rs*lns[i] + lnb[i];
    hout[(size_t)row*768+i] = y;
    hbout[(size_t)row*768+i] = f2b(y);
  }
}

// ---------------- residual add (two deltas) + LN ----------------
__global__ __launch_bounds__(256)
void add_ln(const float* __restrict__ res, const float* __restrict__ d0,
            const float* __restrict__ d1,
            const float* __restrict__ lns, const float* __restrict__ lnb,
            float* __restrict__ hout, bf16* __restrict__ hbout)
{
  const int row = blockIdx.x;
  const int tid = threadIdx.x;
  const int wave = tid >> 6, lane = tid & 63;
  float x[3];
  #pragma unroll
  for (int p=0;p<3;p++){
    int i = tid + p*256;
    size_t idx = (size_t)row*768+i;
    x[p] = res[idx] + d0[idx] + d1[idx];
  }
  float s1 = x[0]+x[1]+x[2];
  float s2 = x[0]*x[0]+x[1]*x[1]+x[2]*x[2];
  #pragma unroll
  for (int m=32;m>=1;m>>=1){ s1 += __shfl_xor(s1,m); s2 += __shfl_xor(s2,m); }
  __shared__ float red[8];
  if (lane==0){ red[wave]=s1; red[4+wave]=s2; }
  __syncthreads();
  s1 = red[0]+red[1]+red[2]+red[3];
  s2 = red[4]+red[5]+red[6]+red[7];
  float mu = s1*(1.0f/768.0f);
  float var = s2*(1.0f/768.0f) - mu*mu;
  float rs = rsqrtf(var + 1e-5f);
  #pragma unroll
  for (int p=0;p<3;p++){
    int i = tid + p*256;
    float y = (x[p]-mu)*rs*lns[i] + lnb[i];
    hout[(size_t)row*768+i] = y;
    hbout[(size_t)row*768+i] = f2b(y);
  }
}

// ---------------- ALL-layer weight transpose -> swizzled BK-64 TILED layout ----------------
// Per matrix: [panel p (N/128)][ktile64 t (K/64)][128 rows][64 k] with k8-group XOR (row&7).
// Block = 64k x 256n source tile.
__global__ __launch_bounds__(256)
void prep_all(const float* __restrict__ Wq, const float* __restrict__ Wk,
              const float* __restrict__ Wv, const float* __restrict__ Wkg,
              const float* __restrict__ Wvg, const float* __restrict__ Wo,
              const float* __restrict__ Wf1, const float* __restrict__ Wf2,
              const float* __restrict__ bq, const float* __restrict__ bk,
              const float* __restrict__ bv, const float* __restrict__ bkg,
              const float* __restrict__ bvg,
              bf16* __restrict__ WcatT, bf16* __restrict__ WoT,
              bf16* __restrict__ Wf1T, bf16* __restrict__ Wf2T,
              float* __restrict__ bcat)
{
  const int b = blockIdx.x;
  const int l = blockIdx.y;
  const int tid = threadIdx.x;
  const size_t oHH = (size_t)l*768*768;
  const size_t oHF = (size_t)l*768*3072;
  const size_t oH  = (size_t)l*768;
  if (b >= 504) {
    int i = (b-504)*256 + tid;   // 0..3839
    int which = i / 768, j = i - which*768;
    float v;
    if      (which==0) v = bq[oH+j] * 0.125f;
    else if (which==1) v = bk[oH+j];
    else if (which==2) v = bv[oH+j];
    else if (which==3) v = bkg[oH+j];
    else               v = bvg[oH+j];
    bcat[(size_t)l*3840 + i] = v;
    return;
  }
  const float* src; bf16* dst; int N, KT64, p0, tk, k0, n0; float scale = 1.0f;
  if (b < 180) {
    int wsel = b/36, tile = b - wsel*36;
    int tkk = tile/3, tn = tile - tkk*3;
    if      (wsel==0){ src=Wq+oHH;  scale=0.125f; }
    else if (wsel==1){ src=Wk+oHH; }
    else if (wsel==2){ src=Wv+oHH; }
    else if (wsel==3){ src=Wkg+oHH; }
    else             { src=Wvg+oHH; }
    dst = WcatT + (size_t)l*5*768*768;
    N=768; KT64=12; k0=tkk*64; n0=tn*256; p0 = wsel*6 + tn*2; tk = tkk;
  } else if (b < 216) {
    int tile = b-180, tkk = tile/3, tn = tile - tkk*3;
    src = Wo+oHH; dst = WoT + (size_t)l*768*768;
    N=768; KT64=12; k0=tkk*64; n0=tn*256; p0 = tn*2; tk = tkk;
  } else if (b < 360) {
    int tile = b-216, tkk = tile/12, tn = tile - tkk*12;
    src = Wf1+oHF; dst = Wf1T + (size_t)l*768*3072;
    N=3072; KT64=12; k0=tkk*64; n0=tn*256; p0 = tn*2; tk = tkk;
  } else {
    int tile = b-360, tkk = tile/3, tn = tile - tkk*3;
    src = Wf2+oHF; dst = Wf2T + (size_t)l*768*3072;
    N=768; KT64=48; k0=tkk*64; n0=tn*256; p0 = tn*2; tk = tkk;
  }

  __shared__ bf16 t[64][264];
  const int wave = tid>>6, lane = tid&63;
  // batch all 16 global loads into registers (keeps 16 loads in flight per wave)
  float4 v[16];
  #pragma unroll
  for (int i=0;i<16;i++){
    int r = i*4 + wave;
    v[i] = *(const float4*)&src[(size_t)(k0+r)*N + n0 + lane*4];
  }
  #pragma unroll
  for (int i=0;i<16;i++){
    int r = i*4 + wave;
    union { ushort4 u; bf16 h[4]; } pk;
    pk.h[0]=f2b(v[i].x*scale); pk.h[1]=f2b(v[i].y*scale);
    pk.h[2]=f2b(v[i].z*scale); pk.h[3]=f2b(v[i].w*scale);
    *(ushort4*)&t[r][lane*4] = pk.u;
  }
  __syncthreads();
  const int rr = tid>>1, half = tid&1;
  const int r7 = rr & 7;
  #pragma unroll
  for (int c=0;c<4;c++){
    const int pp = c>>1, tt = c&1;
    union { uint4 u[2]; bf16 h[16]; } pk;
    #pragma unroll
    for (int j=0;j<16;j++)
      pk.h[j] = t[tt*32 + half*16 + j][pp*128 + rr];
    bf16* base = dst + ((size_t)(p0+pp)*KT64 + tk)*8192 + rr*64;
    const int g0 = tt*4 + half*2;
    *(uint4*)(base + (((g0  ) ^ r7)<<3)) = pk.u[0];
    *(uint4*)(base + (((g0+1) ^ r7)<<3)) = pk.u[1];
  }
}

// ---------------- MFMA GEMM (BK=64, depth-2 counted-vmcnt, XOR-swizzled LDS) ----------------
// C[M][N] = A[M][K] @ BT(tiled,pre-swizzled)^T + bias.
// KSPLIT>1: blockIdx.z picks K-slice, partial -> outf + z*M*N (bias on z==0)
// VT: also scatter V-region cols (1536..2304) transposed into vt[(col-1536)][row]
template<int OUTF, int OUTB, int GELU, int KSPLIT, int VT>
__global__ __launch_bounds__(256)
void gemm_bt(const bf16* __restrict__ A, const bf16* __restrict__ Bt,
             const float* __restrict__ bias,
             float* __restrict__ outf, bf16* __restrict__ outb,
             bf16* __restrict__ vt,
             int M, int N, int K)
{
  __shared__ bf16 As[2][128*64];
  __shared__ bf16 Bs[2][128*64];
  const int tid  = threadIdx.x;
  const int lane = tid & 63;
  const int wave = tid >> 6;
  const int wm = wave >> 1, wn = wave & 1;
  // XCD-chunked block swizzle (nwg % 8 == 0 for all our launches)
  const int gx = gridDim.x, nwg = gx*gridDim.y;
  const int w  = blockIdx.y*gx + blockIdx.x;
  const int cpx = nwg >> 3;
  const int sw = (w & 7)*cpx + (w >> 3);
  const int bm = sw % gx, bn = sw / gx;
  const int bz = (KSPLIT>1) ? blockIdx.z : 0;
  const int fr = lane & 15;
  const int fk = lane >> 4;
  const int x7 = fr & 7;
  const int Ks = K / KSPLIT;
  const int nt = Ks >> 6;
  const int kbeg = bz * Ks;
  const int KT64 = K >> 6;

  // A staging: 4 slots/thread; slot s=i*256+tid: row=s>>3, k8-group=s&7 (linear LDS dest,
  // inverse-swizzled global source)
  const bf16* pa[4];
  int ldsA[4];
  #pragma unroll
  for (int i=0;i<4;i++){
    int s = i*256 + tid;
    int row = s >> 3, k8l = s & 7;
    pa[i] = A + (size_t)(bm*128 + row)*K + kbeg + ((k8l ^ (row&7))<<3);
    ldsA[i] = s*8;
  }
  const bf16* pB = Bt + ((size_t)bn*KT64 + (kbeg>>6))*8192;  // pre-swizzled, pure linear

  f32x4 acc[4][4];
  const f32x4 zero = {0.f,0.f,0.f,0.f};
  #pragma unroll
  for (int i=0;i<4;i++)
    #pragma unroll
    for (int j=0;j<4;j++) acc[i][j] = zero;

  // prologue: stage tiles 0 and 1
  #pragma unroll
  for (int i=0;i<4;i++) GLDS16(pa[i], &As[0][ldsA[i]]);
  #pragma unroll
  for (int i=0;i<4;i++){ int o=(i*256+tid)*8; GLDS16(pB+o, &Bs[0][o]); }
  if (nt > 1) {
    #pragma unroll
    for (int i=0;i<4;i++) GLDS16(pa[i]+64, &As[1][ldsA[i]]);
    #pragma unroll
    for (int i=0;i<4;i++){ int o=(i*256+tid)*8; GLDS16(pB+8192+o, &Bs[1][o]); }
  }

  for (int t = 0; t < nt; ++t) {
    const int cur = t & 1;
    if (t < nt-1) asm volatile("s_waitcnt vmcnt(8)" ::: "memory");
    else          asm volatile("s_waitcnt vmcnt(0)" ::: "memory");
    __builtin_amdgcn_s_barrier();
    __builtin_amdgcn_sched_barrier(0);

    bf16x8 af[2][4], bfr[2][4];
    #pragma unroll
    for (int kk=0;kk<2;kk++){
      #pragma unroll
      for (int m=0;m<4;m++)
        af[kk][m] = *reinterpret_cast<const bf16x8*>(
            &As[cur][(wm*64 + m*16 + fr)*64 + ((((kk<<2)+fk) ^ x7)<<3)]);
      #pragma unroll
      for (int n=0;n<4;n++)
        bfr[kk][n] = *reinterpret_cast<const bf16x8*>(
            &Bs[cur][(wn*64 + n*16 + fr)*64 + ((((kk<<2)+fk) ^ x7)<<3)]);
    }
    #pragma unroll
    for (int kk=0;kk<2;kk++)
      #pragma unroll
      for (int m=0;m<4;m++)
        #pragma unroll
        for (int n=0;n<4;n++)
          acc[m][n] = __builtin_amdgcn_mfma_f32_16x16x32_bf16(af[kk][m], bfr[kk][n], acc[m][n], 0,0,0);

    __builtin_amdgcn_s_barrier();
    __builtin_amdgcn_sched_barrier(0);
    if (t+2 < nt) {
      #pragma unroll
      for (int i=0;i<4;i++) GLDS16(pa[i] + (size_t)(t+2)*64, &As[cur][ldsA[i]]);
      #pragma unroll
      for (int i=0;i<4;i++){ int o=(i*256+tid)*8;
        GLDS16(pB + (size_t)(t+2)*8192 + o, &Bs[cur][o]); }
    }
  }

  const int row0 = bm*128 + wm*64 + (lane>>4)*4;
  const int col0 = bn*128 + wn*64 + fr;
  float* outfz = OUTF ? (outf + (size_t)bz*M*N) : nullptr;
  #pragma unroll
  for (int n=0;n<4;n++){
    const int col = col0 + n*16;
    const float bv = (bz==0) ? bias[col] : 0.f;
    #pragma unroll
    for (int m=0;m<4;m++){
      const int r0 = row0 + m*16;
      union { ushort4 u; bf16 h[4]; } pk;
      #pragma unroll
      for (int r=0;r<4;r++){
        float x = acc[m][n][r] + bv;
        if (GELU) x = 0.5f*x*(1.0f + erff(x*0.70710678118f));
        size_t idx = (size_t)(r0+r)*N + col;
        pk.h[r] = f2b(x);
        if (OUTF) outfz[idx] = x;
        if (OUTB) outb[idx] = pk.h[r];
      }
      if (VT) {
        if (col >= 1536 && col < 2304)
          *(ushort4*)&vt[(size_t)(col-1536)*2048 + r0] = pk.u;
      }
    }
  }
}

// ---------------- band + global attention (merged launch) ----------------
// grid (c=8, n=12, z=5). z<4: band for 64-row group z. z==4 && c==0: global-token path.
__global__ __launch_bounds__(256)
void band_attn(const bf16* __restrict__ qkv, const bf16* __restrict__ Vt,
               const float* __restrict__ h0, const float* __restrict__ Wqg,
               const float* __restrict__ bqg,
               const int* __restrict__ amask, const int* __restrict__ gmask,
               bf16* __restrict__ attn)
{
  const int c = blockIdx.x, n = blockIdx.y, rg = blockIdx.z;
  const int tid = threadIdx.x, wave = tid>>6, lane = tid&63;

  if (rg == 4) {
    if (c != 0) return;
    __shared__ float sg[2048];
    __shared__ float qh[64];
    __shared__ float redg[8];
    __shared__ float partg[4][64];
    {
      const int d = tid & 63;
      const int w = tid >> 6;
      const float* wp = Wqg + (size_t)(w*192)*768 + n*64 + d;
      float a = 0.f;
      #pragma unroll 8
      for (int k=0;k<192;k++) a += h0[w*192+k] * wp[(size_t)k*768];
      partg[w][d] = a;
    }
    __syncthreads();
    if (tid < 64)
      qh[tid] = (partg[0][tid]+partg[1][tid]+partg[2][tid]+partg[3][tid] + bqg[n*64+tid]) * 0.125f;
    __syncthreads();

    float smax = -3.0e38f;
    for (int p=0;p<8;p++){
      int s = p*256 + tid;
      const uint4* kr = (const uint4*)(qkv + (size_t)s*3840 + 2304 + n*64);
      float acc = 0.f;
      #pragma unroll
      for (int d8=0; d8<8; d8++){
        float f[8]; unpack8(kr[d8], f);
        #pragma unroll
        for (int e=0;e<8;e++) acc += f[e]*qh[d8*8+e];
      }
      if (amask[s] == 0) acc = -kNEG;
      sg[s] = acc;
      smax = fmaxf(smax, acc);
    }
    #pragma unroll
    for (int mk=32; mk>=1; mk>>=1) smax = fmaxf(smax, __shfl_xor(smax, mk));
    if (lane==0) redg[wave] = smax;
    __syncthreads();
    smax = fmaxf(fmaxf(redg[0],redg[1]),fmaxf(redg[2],redg[3]));
    float ssum = 0.f;
    for (int p=0;p<8;p++){
      int s = p*256 + tid;
      float e = __expf(sg[s]-smax);
      sg[s] = e;
      ssum += e;
    }
    #pragma unroll
    for (int mk=32; mk>=1; mk>>=1) ssum += __shfl_xor(ssum, mk);
    if (lane==0) redg[4+wave] = ssum;
    __syncthreads();
    float total = redg[4]+redg[5]+redg[6]+redg[7];
    __syncthreads();

    float o0=0.f,o1=0.f,o2=0.f,o3=0.f;
    const int base = wave*512;
    for (int s = base; s < base+512; s+=4){
      o0 += sg[s]   * b2f(qkv[(size_t)s*3840     + 3072 + n*64 + lane]);
      o1 += sg[s+1] * b2f(qkv[(size_t)(s+1)*3840 + 3072 + n*64 + lane]);
      o2 += sg[s+2] * b2f(qkv[(size_t)(s+2)*3840 + 3072 + n*64 + lane]);
      o3 += sg[s+3] * b2f(qkv[(size_t)(s+3)*3840 + 3072 + n*64 + lane]);
    }
    partg[wave][lane] = (o0+o1)+(o2+o3);
    __syncthreads();
    if (tid < 64) {
      float oo = (partg[0][tid]+partg[1][tid]+partg[2][tid]+partg[3][tid]) / total;
      attn[n*64+tid] = f2b(oo);
    }
    return;
  }

  // ---- band path ----
  const int fr = lane & 15, fk = lane >> 4;
  const int jj = tid >> 2, seg = tid & 3;

  __shared__ __attribute__((aligned(16))) bf16 q_s[64][72];
  __shared__ __attribute__((aligned(16))) bf16 k_s[2][64][72];
  __shared__ __attribute__((aligned(16))) bf16 vt_s[2][64][72];
  __shared__ __attribute__((aligned(16))) bf16 p_s[4][16][72];
  __shared__ int  okk_s[768];
  __shared__ float kv0[2][64];

  {
    const uint4* src = (const uint4*)(qkv + (size_t)(c*256 + rg*64 + jj)*3840 + n*64 + seg*16);
    *(uint4*)&q_s[jj][seg*16]   = src[0];
    *(uint4*)&q_s[jj][seg*16+8] = src[1];
  }
  #pragma unroll
  for (int p=0;p<3;p++){
    int j = tid + p*256;
    int kpos = c*256 + j - 256;
    int ok = 0;
    if (kpos >= 0 && kpos < 2048) ok = (amask[kpos] != 0) && (gmask[kpos] == 0);
    okk_s[j] = ok;
  }
  if (tid < 64)       kv0[0][tid]    = b2f(qkv[768  + n*64 + tid]);
  else if (tid < 128) kv0[1][tid-64] = b2f(qkv[1536 + n*64 + (tid-64)]);

  auto loadK = [&](int kt, uint4& a, uint4& b){
    int kpos = c*256 + kt*64 + jj - 256;
    int kq = kpos < 0 ? 0 : (kpos > 2047 ? 2047 : kpos);
    const uint4* ks = (const uint4*)(qkv + (size_t)kq*3840 + 768 + n*64 + seg*16);
    a = ks[0]; b = ks[1];
  };
  auto loadV = [&](int kt, uint4& a, uint4& b){
    int base = c*256 + kt*64 - 256;
    int sb = (base < 0 || base > 2048-64) ? 0 : base;
    const uint4* vs = (const uint4*)(Vt + (size_t)(n*64 + jj)*2048 + sb + seg*8);
    a = vs[0]; b = vs[4];
  };

  uint4 ka,kb,va,vb;
  loadK(rg,ka,kb); loadV(rg,va,vb);
  *(uint4*)&k_s[0][jj][seg*16]    = ka;
  *(uint4*)&k_s[0][jj][seg*16+8]  = kb;
  *(uint4*)&vt_s[0][jj][seg*8]    = va;
  *(uint4*)&vt_s[0][jj][seg*8+32] = vb;

  float m[4], l[4];
  f32x4 out[4];
  const f32x4 zero = {0.f,0.f,0.f,0.f};
  #pragma unroll
  for (int r=0;r<4;r++){ m[r] = -kNEG; l[r] = 0.f; }
  #pragma unroll
  for (int dt=0;dt<4;dt++) out[dt] = zero;

  const int kt1 = (rg+8 < 11) ? rg+8 : 11;
  int cur = 0;
  for (int kt = rg; kt <= kt1; kt++) {
    const bool pf = (kt < kt1);
    if (pf){ loadK(kt+1,ka,kb); loadV(kt+1,va,vb); }
    __syncthreads();

    f32x4 s[4];
    #pragma unroll
    for (int ct=0;ct<4;ct++) s[ct] = zero;
    #pragma unroll
    for (int ks=0;ks<2;ks++){
      bf16x8 aq = *reinterpret_cast<const bf16x8*>(&q_s[wave*16 + fr][ks*32 + fk*8]);
      #pragma unroll
      for (int ct=0;ct<4;ct++){
        bf16x8 bk = *reinterpret_cast<const bf16x8*>(&k_s[cur][ct*16 + fr][ks*32 + fk*8]);
        s[ct] = __builtin_amdgcn_mfma_f32_16x16x32_bf16(aq, bk, s[ct], 0,0,0);
      }
    }
    const int qbase = rg*64 + wave*16 + fk*4;
    #pragma unroll
    for (int ct=0;ct<4;ct++){
      int j = kt*64 + ct*16 + fr;
      int okj = okk_s[j];
      #pragma unroll
      for (int r=0;r<4;r++){
        unsigned rel = (unsigned)(j - (qbase + r));
        s[ct][r] = (okj && rel <= 512u) ? s[ct][r] : -kNEG;
      }
    }
    float fac[4], psum[4];
    #pragma unroll
    for (int r=0;r<4;r++){
      float mm = fmaxf(fmaxf(s[0][r], s[1][r]), fmaxf(s[2][r], s[3][r]));
      #pragma unroll
      for (int mk=8; mk>=1; mk>>=1) mm = fmaxf(mm, __shfl_xor(mm, mk));
      float mn = fmaxf(m[r], mm);
      fac[r] = __expf(m[r] - mn);
      m[r] = mn;
      psum[r] = 0.f;
    }
    #pragma unroll
    for (int ct=0;ct<4;ct++){
      #pragma unroll
      for (int r=0;r<4;r++){
        float p = __expf(s[ct][r] - m[r]);
        psum[r] += p;
        p_s[wave][fk*4 + r][ct*16 + fr] = f2b(p);
      }
    }
    #pragma unroll
    for (int r=0;r<4;r++){
      float ts = psum[r];
      #pragma unroll
      for (int mk=8; mk>=1; mk>>=1) ts += __shfl_xor(ts, mk);
      l[r] = l[r]*fac[r] + ts;
    }
    #pragma unroll
    for (int dt=0;dt<4;dt++)
      #pragma unroll
      for (int r=0;r<4;r++) out[dt][r] *= fac[r];
    #pragma unroll
    for (int ks=0;ks<2;ks++){
      bf16x8 ap = *reinterpret_cast<const bf16x8*>(&p_s[wave][fr][ks*32 + fk*8]);
      #pragma unroll
      for (int dt=0;dt<4;dt++){
        bf16x8 bv = *reinterpret_cast<const bf16x8*>(&vt_s[cur][dt*16 + fr][ks*32 + fk*8]);
        out[dt] = __builtin_amdgcn_mfma_f32_16x16x32_bf16(ap, bv, out[dt], 0,0,0);
      }
    }

    if (pf){
      *(uint4*)&k_s[cur^1][jj][seg*16]    = ka;
      *(uint4*)&k_s[cur^1][jj][seg*16+8]  = kb;
      *(uint4*)&vt_s[cur^1][jj][seg*8]    = va;
      *(uint4*)&vt_s[cur^1][jj][seg*8+32] = vb;
      cur ^= 1;
    }
  }

  const bool okg = (amask[0] != 0);
  #pragma unroll
  for (int r=0;r<4;r++){
    const int row16 = fk*4 + r;
    float sp = 0.f;
    #pragma unroll
    for (int e=0;e<4;e++){
      int d = fr*4 + e;
      sp += b2f(q_s[wave*16 + row16][d]) * kv0[0][d];
    }
    #pragma unroll
    for (int mk=8; mk>=1; mk>>=1) sp += __shfl_xor(sp, mk);
    float sg2 = okg ? sp : -kNEG;
    float mn = fmaxf(m[r], sg2);
    float fc = __expf(m[r]-mn);
    float pg = __expf(sg2-mn);
    float lf = l[r]*fc + pg;
    const int srow = c*256 + rg*64 + wave*16 + row16;
    if (srow != 0) {
      #pragma unroll
      for (int dt=0;dt<4;dt++){
        int d = dt*16 + fr;
        float o = (out[dt][r]*fc + pg*kv0[1][d]) / lf;
        attn[(size_t)srow*768 + n*64 + d] = f2b(o);
      }
    }
  }
}

// ---------------- head: tanh(h0 @ dw + db) @ ow + ob ----------------
__global__ __launch_bounds__(768)
void head(const float* __restrict__ h0, const float* __restrict__ dw,
          const float* __restrict__ db, const float* __restrict__ ow,
          const float* __restrict__ ob, float* __restrict__ out)
{
  __shared__ float y[768];
  const int tid = threadIdx.x;
  float acc = 0.f;
  #pragma unroll 8
  for (int k=0;k<768;k++) acc += h0[k]*dw[(size_t)k*768 + tid];
  y[tid] = tanhf(acc + db[tid]);
  __syncthreads();
  if (tid < 256) {
    float a = 0.f;
    #pragma unroll 8
    for (int k=0;k<768;k++) a += y[k]*ow[(size_t)k*256 + tid];
    out[tid] = a + ob[tid];
  }
}

// ---------------- host ----------------
extern "C" void kernel_launch(void* const* d_in, const int* in_sizes, int n_in,
                              void* d_out, int out_size, void* d_ws, size_t ws_size,
                              hipStream_t stream)
{
  const int*   ids   = (const int*)d_in[0];
  const int*   amask = (const int*)d_in[1];
  const int*   gmask = (const int*)d_in[2];
  const float* wemb  = (const float*)d_in[3];
  const float* pemb  = (const float*)d_in[4];
  const float* elns  = (const float*)d_in[5];
  const float* elnb  = (const float*)d_in[6];
  const float* Wq    = (const float*)d_in[7];
  const float* bq    = (const float*)d_in[8];
  const float* Wk    = (const float*)d_in[9];
  const float* bk    = (const float*)d_in[10];
  const float* Wv    = (const float*)d_in[11];
  const float* bv    = (const float*)d_in[12];
  const float* Wqg   = (const float*)d_in[13];
  const float* bqg   = (const float*)d_in[14];
  const float* Wkg   = (const float*)d_in[15];
  const float* bkg   = (const float*)d_in[16];
  const float* Wvg   = (const float*)d_in[17];
  const float* bvg   = (const float*)d_in[18];
  const float* Wo    = (const float*)d_in[19];
  const float* bo    = (const float*)d_in[20];
  const float* ln1s  = (const float*)d_in[21];
  const float* ln1b  = (const float*)d_in[22];
  const float* Wf1   = (const float*)d_in[23];
  const float* bf1   = (const float*)d_in[24];
  const float* Wf2   = (const float*)d_in[25];
  const float* bf2   = (const float*)d_in[26];
  const float* ln2s  = (const float*)d_in[27];
  const float* ln2b  = (const float*)d_in[28];
  const float* dw    = (const float*)d_in[29];
  const float* db    = (const float*)d_in[30];
  const float* ow    = (const float*)d_in[31];
  const float* ob    = (const float*)d_in[32];

  char* ws = (char*)d_ws;
  size_t off = 0;
  auto alloc = [&](size_t bytes)->char*{
    char* p = ws + off; off += (bytes + 255) & ~(size_t)255; return p;
  };
  float* h     = (float*)alloc((size_t)2048*768*4);
  bf16*  hb    = (bf16*) alloc((size_t)2048*768*2);
  float* h2    = (float*)alloc((size_t)2048*768*4);
  bf16*  h2b   = (bf16*) alloc((size_t)2048*768*2);
  bf16*  qkv   = (bf16*) alloc((size_t)2048*3840*2);   // reused as f32 split-K partials
  bf16*  att   = (bf16*) alloc((size_t)2048*768*2);
  bf16*  f1    = (bf16*) alloc((size_t)2048*3072*2);
  bf16*  Vtb   = (bf16*) alloc((size_t)768*2048*2);    // V^T per layer [head*64+d][s]
  bf16*  WcatT = (bf16*) alloc((size_t)12*5*768*768*2);
  bf16*  WoT   = (bf16*) alloc((size_t)12*768*768*2);
  bf16*  Wf1T  = (bf16*) alloc((size_t)12*768*3072*2);
  bf16*  Wf2T  = (bf16*) alloc((size_t)12*768*3072*2);
  float* bcat  = (float*)alloc((size_t)12*3840*4);
  float* pf    = (float*)qkv;                          // 2 x 2048*768 f32 fits in qkv
  const size_t MN = (size_t)2048*768;

  prep_all<<<dim3(519,12),256,0,stream>>>(Wq, Wk, Wv, Wkg, Wvg, Wo, Wf1, Wf2,
                                          bq, bk, bv, bkg, bvg,
                                          WcatT, WoT, Wf1T, Wf2T, bcat);
  embed_ln<<<2048,256,0,stream>>>(ids, wemb, pemb, elns, elnb, h, hb);

  for (int l=0; l<12; l++) {
    const size_t oHH = (size_t)l*768*768;
    const size_t oH  = (size_t)l*768;
    const size_t oF  = (size_t)l*3072;
    const bf16* WcatT_l = WcatT + (size_t)l*5*768*768;
    const bf16* WoT_l   = WoT   + (size_t)l*768*768;
    const bf16* Wf1T_l  = Wf1T  + (size_t)l*768*3072;
    const bf16* Wf2T_l  = Wf2T  + (size_t)l*768*3072;
    const float* bcat_l = bcat  + (size_t)l*3840;

    gemm_bt<0,1,0,1,1><<<dim3(16,30),256,0,stream>>>(hb, WcatT_l, bcat_l, nullptr, qkv,
                                                     Vtb, 2048, 3840, 768);
    band_attn<<<dim3(8,12,5),256,0,stream>>>(qkv, Vtb, h, Wqg+oHH, bqg+oH,
                                             amask, gmask, att);
    gemm_bt<1,0,0,2,0><<<dim3(16,6,2),256,0,stream>>>(att, WoT_l, bo+oH, pf, nullptr,
                                                      nullptr, 2048, 768, 768);
    add_ln<<<2048,256,0,stream>>>(h, pf, pf+MN, ln1s+oH, ln1b+oH, h2, h2b);
    gemm_bt<0,1,1,1,0><<<dim3(16,24),256,0,stream>>>(h2b, Wf1T_l, bf1+oF, nullptr, f1,
                                                     nullptr, 2048, 3072, 768);
    gemm_bt<1,0,0,2,0><<<dim3(16,6,2),256,0,stream>>>(f1, Wf2T_l, bf2+oH, pf, nullptr,
                                                      nullptr, 2048, 768, 3072);
    add_ln<<<2048,256,0,stream>>>(h2, pf, pf+MN, ln2s+oH, ln2b+oH, h, hb);
  }

  head<<<1,768,0,stream>>>(h, dw, db, ow, ob, (float*)d_out);
}